// Round 6
// baseline (3898.909 us; speedup 1.0000x reference)
//
#include <hip/hip_runtime.h>
#include <hip/hip_bf16.h>
#include <math.h>

#define EPSV 1e-8f

__device__ __forceinline__ float dsmall(float d){ return d > EPSV ? d : EPSV; }
__device__ __forceinline__ float sigf(float x){ return 1.f/(1.f+expf(-x)); }

// ---------------------------------------------------------------------------
// Transpose: W (R x C) -> WT (C x R)
// ---------------------------------------------------------------------------
__global__ __launch_bounds__(1024) void k_transpose(const float* __restrict__ W,
                                                    float* __restrict__ WT, int R, int C){
  __shared__ float t[32][33];
  int rb = blockIdx.y*32, cb = blockIdx.x*32;
  int r = rb + threadIdx.y, c = cb + threadIdx.x;
  if (r < R && c < C) t[threadIdx.y][threadIdx.x] = W[(size_t)r*C + c];
  __syncthreads();
  int rr = cb + threadIdx.y, cc = rb + threadIdx.x;
  if (rr < C && cc < R) WT[(size_t)rr*R + cc] = t[threadIdx.x][threadIdx.y];
}

// ---------------------------------------------------------------------------
// Generic z-batched tiled GEMM-like kernel. 64x64 tile, 256 thr, 4x4/thread.
// MODE 0: C=A(MxK)@B(NxK)^T + bias[n]
// MODE 1: C=(A*wscale^2)(MxK)@B(NxK)^T / dsmall(U[m]*V[n])
// MODE 2: C=A(MxK)@B(KxN) / dsmall(U[m])
// MODE 3: C=max_k A(MxK)*B(KxN)
// MODE 4: C=A(KxM)^T@B(KxN) / dsmall(U[m])
// MODE 5: C=max_k A(KxM)^T*B(KxN)
// ---------------------------------------------------------------------------
template<int MODE>
__global__ __launch_bounds__(256) void k_gemm(
    const float* __restrict__ A0, int lda, long long sAo, long long sAi,
    const float* __restrict__ B0, int ldb, long long sBo, long long sBi,
    float* __restrict__ C0, int ldc, long long sCo, long long sCi,
    const float* __restrict__ W0, long long sWo, long long sWi,
    const float* __restrict__ U0, long long sUo, long long sUi,
    const float* __restrict__ V0, long long sVo, long long sVi,
    const float* __restrict__ bias,
    int M, int N, int K, int zdiv)
{
  const int z = blockIdx.z, zo = z / zdiv, zi = z % zdiv;
  const float* A = A0 + zo*sAo + zi*sAi;
  const float* B = B0 + zo*sBo + zi*sBi;
  float* C = C0 + zo*sCo + zi*sCi;
  const float* Wv = W0 ? (W0 + zo*sWo + zi*sWi) : nullptr;
  const float* U  = U0 ? (U0 + zo*sUo + zi*sUi) : nullptr;
  const float* V  = V0 ? (V0 + zo*sVo + zi*sVi) : nullptr;

  __shared__ float As[16][68];
  __shared__ float Bs[16][68];
  const int mb = blockIdx.y*64, nb = blockIdx.x*64;
  const int tid = threadIdx.x;
  const int tx = tid & 15, ty = tid >> 4;
  const bool ISMAX = (MODE==3 || MODE==5);

  float acc[4][4];
  #pragma unroll
  for (int i=0;i<4;i++)
    #pragma unroll
    for (int j=0;j<4;j++) acc[i][j] = ISMAX ? -INFINITY : 0.f;

  for (int kt = 0; kt < K; kt += 16) {
    // ---- stage A ----
    if (MODE <= 3) {              // A is M x K row-major
      int ka = tid & 15, ma = tid >> 4;
      #pragma unroll
      for (int q=0;q<4;q++){
        int m = ma + q*16;
        float v = 0.f;
        if (mb+m < M && kt+ka < K){
          v = A[(size_t)(mb+m)*lda + kt+ka];
          if (MODE==1 && Wv){ float w = Wv[kt+ka]; v *= w*w; }
        }
        As[ka][m] = v;
      }
    } else {                      // A is K x M row-major (aTb)
      int ma = tid & 63, ka = tid >> 6;
      #pragma unroll
      for (int q=0;q<4;q++){
        int k = ka + q*4;
        float v = 0.f;
        if (kt+k < K && mb+ma < M) v = A[(size_t)(kt+k)*lda + mb+ma];
        As[k][ma] = v;
      }
    }
    // ---- stage B ----
    if (MODE <= 1) {              // B is N x K row-major (B^T gemm)
      int kb = tid & 15, nbi = tid >> 4;
      #pragma unroll
      for (int q=0;q<4;q++){
        int n = nbi + q*16;
        float v = 0.f;
        if (nb+n < N && kt+kb < K) v = B[(size_t)(nb+n)*ldb + kt+kb];
        Bs[kb][n] = v;
      }
    } else {                      // B is K x N row-major
      int nbi = tid & 63, kb = tid >> 6;
      #pragma unroll
      for (int q=0;q<4;q++){
        int k = kb + q*4;
        float v = 0.f;
        if (kt+k < K && nb+nbi < N) v = B[(size_t)(kt+k)*ldb + nb+nbi];
        Bs[k][nbi] = v;
      }
    }
    __syncthreads();
    #pragma unroll
    for (int k=0;k<16;k++){
      float a[4], bv[4];
      #pragma unroll
      for (int i=0;i<4;i++) a[i] = As[k][ty*4+i];
      #pragma unroll
      for (int j=0;j<4;j++) bv[j] = Bs[k][tx*4+j];
      #pragma unroll
      for (int i=0;i<4;i++)
        #pragma unroll
        for (int j=0;j<4;j++){
          if (ISMAX) acc[i][j] = fmaxf(acc[i][j], a[i]*bv[j]);
          else       acc[i][j] += a[i]*bv[j];
        }
    }
    __syncthreads();
  }
  // ---- epilogue ----
  #pragma unroll
  for (int i=0;i<4;i++){
    int m = mb + ty*4 + i;
    if (m >= M) continue;
    #pragma unroll
    for (int j=0;j<4;j++){
      int n = nb + tx*4 + j;
      if (n >= N) continue;
      float v = acc[i][j];
      if (MODE==0){ if (bias) v += bias[n]; }
      else if (MODE==1){ v = v / dsmall(U[m]*V[n]); }
      else if (MODE==2 || MODE==4){ v = v / dsmall(U[m]); }
      C[(size_t)m*ldc + n] = v;
    }
  }
}

// ---------------------------------------------------------------------------
// LSTM scan v6: as v5 (8 WGs/dir, weights in VGPRs, per-half-wave exchange)
// plus: (1) inline-asm "+v" pin of the weight slice -- R5's VGPR_Count=116
// proved the compiler rematerialized the 32 global loads inside the step
// loop (L2-latency-bound); the opaque asm forces true register residency.
// (2) PRE prefetch issued BEFORE the poll/fetch so HBM latency hides under
// the spin + matmul.
// ---------------------------------------------------------------------------
__global__ __launch_bounds__(256, 1) void k_scan6(
    const float* __restrict__ PREf, const float* __restrict__ PREb,
    const float* __restrict__ WTf, const float* __restrict__ WTb,
    float* __restrict__ Hbuf, int* __restrict__ flg,
    float* __restrict__ HSo, float* __restrict__ HTo)
{
  const int xcd = blockIdx.x & 7;
  if (xcd > 1) return;
  const int d  = xcd;
  const int wg = blockIdx.x >> 3;
  const float* PRE = d ? PREb : PREf;
  const float* WT  = d ? WTb  : WTf;
  float* Hb = Hbuf + (size_t)d*2*2048;
  int* fl = flg + d*8*32;

  __shared__ float hl[256][8];       // 8 KB   hl[k][s]; chunk c = rows [c*32,c*32+32)
  __shared__ float red[4][32][40];   // 20 KB  red[kp][s*4+cc][gq] (bank-disjoint)

  const int tid = threadIdx.x;
  const int kc = tid >> 5;   // k-chunk 0..7 (32 k each)
  const int gq = tid & 31;   // gate-col quad
  const int as = tid >> 5;   // activation: seq 0..7
  const int aj = tid & 31;   // activation: h-col within slice

  // stage weight slice into REGISTERS (static across all 256 steps)
  float4 wv[32];
  {
    const float* wbase = WT + (gq>>3)*256 + wg*32 + (gq&7)*4;
    #pragma unroll
    for (int kk=0; kk<32; ++kk)
      wv[kk] = *(const float4*)&wbase[(size_t)(kc*32+kk)*1024];
  }
  // PIN in VGPRs: opaque to the optimizer -> no rematerialization in the loop
  #pragma unroll
  for (int kk=0; kk<32; ++kk)
    asm volatile("" : "+v"(wv[kk].x), "+v"(wv[kk].y), "+v"(wv[kk].z), "+v"(wv[kk].w));

  for (int e = tid; e < 2048; e += 256) ((float*)hl)[e] = 0.f;
  float cst = 0.f;
  __syncthreads();

  for (int tt = 0; tt < 256; ++tt) {
    const int t = d ? 255 - tt : tt;
    const int wp = tt & 1;          // parity this iteration stores (h_state(tt+1))
    const int sp = (tt + 1) & 1;    // parity holding h_state(tt) (stored at tt-1)

    // prefetch PRE for activation FIRST (HBM latency hides under spin+matmul)
    const size_t pbase = ((size_t)(as*256 + t))*1024 + wg*32 + aj;
    const float pre0 = PRE[pbase];       const float pre1 = PRE[pbase + 256];
    const float pre2 = PRE[pbase + 512]; const float pre3 = PRE[pbase + 768];

    // ---- per-half-wave fetch of remote chunk kc of h_state(tt) ----
    if (tt > 0 && kc != wg) {
      const int* flp = &fl[kc*32];
      while (__hip_atomic_load(flp, __ATOMIC_RELAXED, __HIP_MEMORY_SCOPE_AGENT) < tt)
        __builtin_amdgcn_s_sleep(1);
      const unsigned long long* srcu =
          (const unsigned long long*)&Hb[sp*2048 + kc*256 + gq*8];
      unsigned long long u0 = __hip_atomic_load(srcu+0, __ATOMIC_RELAXED, __HIP_MEMORY_SCOPE_AGENT);
      unsigned long long u1 = __hip_atomic_load(srcu+1, __ATOMIC_RELAXED, __HIP_MEMORY_SCOPE_AGENT);
      unsigned long long u2 = __hip_atomic_load(srcu+2, __ATOMIC_RELAXED, __HIP_MEMORY_SCOPE_AGENT);
      unsigned long long u3 = __hip_atomic_load(srcu+3, __ATOMIC_RELAXED, __HIP_MEMORY_SCOPE_AGENT);
      unsigned long long* dst = (unsigned long long*)&((float*)hl)[kc*256 + gq*8];
      dst[0] = u0; dst[1] = u1; dst[2] = u2; dst[3] = u3;
    }

    // ---- gate matmul: acc[s][cc] over 32 k of chunk kc, weights in regs ----
    float acc[8][4];
    #pragma unroll
    for (int s=0;s<8;s++){ acc[s][0]=0.f; acc[s][1]=0.f; acc[s][2]=0.f; acc[s][3]=0.f; }
    #pragma unroll
    for (int kk = 0; kk < 32; ++kk) {
      const int k = kc*32 + kk;
      float4 ha = *(const float4*)&hl[k][0];
      float4 hb = *(const float4*)&hl[k][4];
      float4 w  = wv[kk];
      acc[0][0] += ha.x*w.x; acc[0][1] += ha.x*w.y; acc[0][2] += ha.x*w.z; acc[0][3] += ha.x*w.w;
      acc[1][0] += ha.y*w.x; acc[1][1] += ha.y*w.y; acc[1][2] += ha.y*w.z; acc[1][3] += ha.y*w.w;
      acc[2][0] += ha.z*w.x; acc[2][1] += ha.z*w.y; acc[2][2] += ha.z*w.z; acc[2][3] += ha.z*w.w;
      acc[3][0] += ha.w*w.x; acc[3][1] += ha.w*w.y; acc[3][2] += ha.w*w.z; acc[3][3] += ha.w*w.w;
      acc[4][0] += hb.x*w.x; acc[4][1] += hb.x*w.y; acc[4][2] += hb.x*w.z; acc[4][3] += hb.x*w.w;
      acc[5][0] += hb.y*w.x; acc[5][1] += hb.y*w.y; acc[5][2] += hb.y*w.z; acc[5][3] += hb.y*w.w;
      acc[6][0] += hb.z*w.x; acc[6][1] += hb.z*w.y; acc[6][2] += hb.z*w.z; acc[6][3] += hb.z*w.w;
      acc[7][0] += hb.w*w.x; acc[7][1] += hb.w*w.y; acc[7][2] += hb.w*w.z; acc[7][3] += hb.w*w.w;
    }
    // reduce kc-pairs (lanes l <-> l^32), stash to LDS (lane-stride-1 writes)
    #pragma unroll
    for (int s=0;s<8;s++)
      #pragma unroll
      for (int c2=0;c2<4;c2++)
        acc[s][c2] += __shfl_xor(acc[s][c2], 32, 64);
    if ((tid & 32) == 0) {
      const int kp = kc >> 1;   // 0..3
      #pragma unroll
      for (int s=0;s<8;s++)
        #pragma unroll
        for (int c2=0;c2<4;c2++)
          red[kp][s*4+c2][gq] = acc[s][c2];
    }
    __syncthreads();   // B1: red ready

    // ---- activation + h/c update (all 256 threads) ----
    float hreg;
    {
      float g[4];
      #pragma unroll
      for (int gt=0; gt<4; ++gt) {
        const int c = gt*32 + aj;
        const int gqq = c >> 2, cc = c & 3;
        const int ii = as*4 + cc;
        g[gt] = red[0][ii][gqq] + red[1][ii][gqq] + red[2][ii][gqq] + red[3][ii][gqq];
      }
      g[0] += pre0; g[1] += pre1; g[2] += pre2; g[3] += pre3;
      const float ig = sigf(g[0]), fg = sigf(g[1]), gg = tanhf(g[2]), og = sigf(g[3]);
      cst = fg*cst + ig*gg;
      hreg = og*tanhf(cst);
      // own chunk -> LDS directly (visible WG-wide after B2)
      hl[wg*32 + aj][as] = hreg;
      // publish to peers (L2)
      __hip_atomic_store(&Hb[wp*2048 + (wg*32 + aj)*8 + as], hreg,
                         __ATOMIC_RELAXED, __HIP_MEMORY_SCOPE_AGENT);
    }
    __syncthreads();   // B2: drains Hb stores (vmcnt(0)) + own-hl ds_writes

    // ---- post own flag (own 128B line); peers poll per-half-wave ----
    if (tid == 0)
      __hip_atomic_store(&fl[wg*32], tt+1, __ATOMIC_RELEASE, __HIP_MEMORY_SCOPE_AGENT);

    // ---- HSo/HTo stores OFF the critical path (drained by next B2) ----
    if (HSo) HSo[((size_t)(as*256 + t))*512 + d*256 + wg*32 + aj] = hreg;
    if (HTo && tt == 255) HTo[((size_t)(as*2 + d))*256 + wg*32 + aj] = hreg;
  }
}

// ---------------------------------------------------------------------------
// Row L2 norms of the 4096 (seq,dir,i) hidden rows.
// ---------------------------------------------------------------------------
__global__ __launch_bounds__(256) void k_rownorm(const float* __restrict__ HS_,
                                                 float* __restrict__ NORM_){
  int r = blockIdx.x*4 + (threadIdx.x >> 6);
  int lane = threadIdx.x & 63;
  int seq = r >> 9, d = (r >> 8) & 1, i = r & 255;
  const float* row = HS_ + ((size_t)(seq*256 + i))*512 + d*256;
  float s = 0.f;
  #pragma unroll
  for (int q=0;q<4;q++){ float v = row[lane + 64*q]; s += v*v; }
  for (int off=32; off; off>>=1) s += __shfl_xor(s, off, 64);
  if (lane == 0) NORM_[r] = sqrtf(s);
}

// ---------------------------------------------------------------------------
// Row sum+max reduction (cols elements per row, 4 rows/block)
// ---------------------------------------------------------------------------
__global__ __launch_bounds__(256) void k_rowred(const float* __restrict__ in,
                                                float* __restrict__ osum,
                                                float* __restrict__ omax, int cols){
  int r = blockIdx.x*4 + (threadIdx.x >> 6);
  int lane = threadIdx.x & 63;
  const float* row = in + (size_t)r*cols;
  float s = 0.f, m = -INFINITY;
  for (int cidx=lane; cidx<cols; cidx+=64){ float v=row[cidx]; s += v; m = fmaxf(m,v); }
  for (int off=32; off; off>>=1){ s += __shfl_xor(s,off,64); m = fmaxf(m, __shfl_xor(m,off,64)); }
  if (lane == 0){ if (osum) osum[r] = s; if (omax) omax[r] = m; }
}

// Column sum+max reduction over nrows, 256 cols, one block per z.
__global__ __launch_bounds__(256) void k_colred(const float* __restrict__ in0, long long zstride,
                                                int nrows, int ld,
                                                float* __restrict__ osum, float* __restrict__ omax){
  const float* in = in0 + (size_t)blockIdx.z*zstride;
  int j = threadIdx.x;
  float s = 0.f, m = -INFINITY;
  for (int r=0;r<nrows;r++){ float v = in[(size_t)r*ld + j]; s += v; m = fmaxf(m,v); }
  if (osum) osum[blockIdx.z*256 + j] = s;
  if (omax) omax[blockIdx.z*256 + j] = m;
}

// ---------------------------------------------------------------------------
// Weighted norms for pairwise matching: out[side][d][b][l][i]
// ---------------------------------------------------------------------------
__global__ __launch_bounds__(256) void k_wnorm(const float* __restrict__ HS_,
                                               const float* __restrict__ w3, const float* __restrict__ w4,
                                               float* __restrict__ WN1_, float* __restrict__ WN2_){
  int rid = blockIdx.x*4 + (threadIdx.x >> 6);
  int lane = threadIdx.x & 63;
  int side = rid / 20480; int rem = rid % 20480;
  int d = rem / 10240; int rem2 = rem % 10240;
  int b = rem2 / 2560; int l = (rem2 / 256) % 10; int i = rem2 & 255;
  int seq = side ? 4+b : b;
  const float* row = HS_ + ((size_t)(seq*256 + i))*512 + d*256;
  const float* w = (d ? w4 : w3) + l*256;
  float s = 0.f;
  #pragma unroll
  for (int q=0;q<4;q++){ float wv = w[lane+64*q]; float v = row[lane+64*q]; s += wv*wv*v*v; }
  for (int off=32; off; off>>=1) s += __shfl_xor(s, off, 64);
  if (lane == 0) (side ? WN2_ : WN1_)[rem] = sqrtf(s);
}

// ---------------------------------------------------------------------------
// Assemble mv rows (62 channels) incl. the 40 mp_match channels.
// Block per (side,b,i); 4 waves = 4 (vec,w) pairs.
// ---------------------------------------------------------------------------
__global__ __launch_bounds__(256) void k_mv(
    const float* __restrict__ HS_, const float* __restrict__ MEANH_, const float* __restrict__ MEANP_,
    const float* __restrict__ XH_, const float* __restrict__ XP_,
    const float* __restrict__ RS_, const float* __restrict__ RMAX_,
    const float* __restrict__ CS_, const float* __restrict__ CMAX_,
    const float* __restrict__ MMR_, const float* __restrict__ MMC_,
    const float* __restrict__ w5, const float* __restrict__ w6,
    const float* __restrict__ w7, const float* __restrict__ w8,
    float* __restrict__ MV_)
{
  const int blk = blockIdx.x;
  const int side = blk >> 10, b = (blk >> 8) & 3, i = blk & 255;
  const int wv = threadIdx.x >> 6, lane = threadIdx.x & 63;
  float* mvrow = MV_ + (size_t)blk*62;

  if (threadIdx.x == 0){
    const float* rmax = side ? CMAX_ : RMAX_;
    const float* rsum = side ? CS_   : RS_;
    mvrow[0] = rmax[b*256 + i];              // att_fw max
    mvrow[1] = rsum[b*256 + i] * (1.f/256.f);// att_fw mean
  }
  if (threadIdx.x < 20){
    int dd = threadIdx.x / 10, l = threadIdx.x % 10;
    const float* mm = side ? MMC_ : MMR_;
    mvrow[2 + dd*10 + l] = mm[dd*10240 + (b*10 + l)*256 + i];
  }
  const int d = wv & 1;                      // pairs 0,2 fw; 1,3 bw
  const int seq = side ? 4+b : b;
  const float* arow = HS_ + ((size_t)(seq*256 + i))*512 + d*256;
  const float* Mside = side ? MEANP_ : MEANH_;
  const float* Xside = side ? XP_ : XH_;
  const float* brow = (wv < 2 ? Mside : Xside) + (size_t)d*262144 + (size_t)b*65536 + (size_t)i*256;
  const float* wp = (wv==0) ? w5 : (wv==1) ? w6 : (wv==2) ? w7 : w8;

  float av[4], bv[4];
  #pragma unroll
  for (int q=0;q<4;q++){ av[q] = arow[lane+64*q]; bv[q] = brow[lane+64*q]; }
  for (int l=0;l<10;l++){
    const float* wrow = wp + l*256;
    float s1=0.f, s2=0.f, s3=0.f;
    #pragma unroll
    for (int q=0;q<4;q++){
      float w = wrow[lane+64*q]; float w2v = w*w;
      s1 += w2v*av[q]*bv[q]; s2 += w2v*av[q]*av[q]; s3 += w2v*bv[q]*bv[q];
    }
    for (int off=32; off; off>>=1){
      s1 += __shfl_xor(s1,off,64); s2 += __shfl_xor(s2,off,64); s3 += __shfl_xor(s3,off,64);
    }
    if (lane == 0) mvrow[22 + wv*10 + l] = s1 / fmaxf(sqrtf(s2)*sqrtf(s3), EPSV);
  }
}

// ---------------------------------------------------------------------------
// Mean over time of left/right: XM[b][side*300+d]
// ---------------------------------------------------------------------------
__global__ void k_means(const float* __restrict__ L, const float* __restrict__ R,
                        float* __restrict__ XM){
  int b = blockIdx.x & 3, sideR = blockIdx.x >> 2;
  const float* src = sideR ? R : L;
  int dch = threadIdx.x;
  if (dch >= 300) return;
  float s = 0.f;
  for (int t=0;t<256;t++) s += src[((size_t)(b*256 + t))*300 + dch];
  XM[b*600 + sideR*300 + dch] = s*(1.f/256.f);
}

// ---------------------------------------------------------------------------
// Head: fc1 (tanh), fc2
// ---------------------------------------------------------------------------
__global__ __launch_bounds__(512) void k_fc1(const float* __restrict__ HT_,
                                             const float* __restrict__ XM,
                                             const float* __restrict__ W1T,
                                             const float* __restrict__ b1,
                                             float* __restrict__ X2){
  __shared__ float x[1626];
  int b = blockIdx.x, t = threadIdx.x;
  if (t < 256){
    x[t]       = HT_[(b*2+0)*256 + t];
    x[256+t]   = HT_[(b*2+1)*256 + t];
    x[512+t]   = HT_[((4+b)*2+0)*256 + t];
    x[768+t]   = HT_[((4+b)*2+1)*256 + t];
  }
  if (t == 0){ x[1024] = 0.5f; x[1025] = 0.5f; }
  if (t < 300){ x[1026+t] = XM[b*600 + t]; x[1326+t] = XM[b*600 + 300 + t]; }
  __syncthreads();
  float acc = b1[t];
  for (int k=0;k<1626;k++) acc += x[k]*W1T[(size_t)k*512 + t];
  X2[b*512 + t] = tanhf(acc);
}

__global__ void k_fc2(const float* __restrict__ X2, const float* __restrict__ W2,
                      const float* __restrict__ b2, float* __restrict__ out){
  int b = blockIdx.x, o = threadIdx.x;
  if (o >= 22) return;
  float acc = b2[o];
  const float* xr = X2 + b*512;
  const float* wr = W2 + (size_t)o*512;
  for (int k=0;k<512;k++) acc += xr[k]*wr[k];
  out[b*22 + o] = acc;
}

// ---------------------------------------------------------------------------
extern "C" void kernel_launch(void* const* d_in, const int* in_sizes, int n_in,
                              void* d_out, int out_size, void* d_ws, size_t ws_size,
                              hipStream_t stream) {
  const float* left  = (const float*)d_in[0];
  const float* right = (const float*)d_in[1];
  const float* cWihF = (const float*)d_in[2];
  const float* cWhhF = (const float*)d_in[3];
  const float* cbF   = (const float*)d_in[4];
  const float* cWihB = (const float*)d_in[5];
  const float* cWhhB = (const float*)d_in[6];
  const float* cbB   = (const float*)d_in[7];
  const float* aWihF = (const float*)d_in[8];
  const float* aWhhF = (const float*)d_in[9];
  const float* abF   = (const float*)d_in[10];
  const float* aWihB = (const float*)d_in[11];
  const float* aWhhB = (const float*)d_in[12];
  const float* abB   = (const float*)d_in[13];
  const float* w3 = (const float*)d_in[14];
  const float* w4 = (const float*)d_in[15];
  const float* w5 = (const float*)d_in[16];
  const float* w6 = (const float*)d_in[17];
  const float* w7 = (const float*)d_in[18];
  const float* w8 = (const float*)d_in[19];
  const float* fc1W = (const float*)d_in[20];
  const float* fc1b = (const float*)d_in[21];
  const float* fc2W = (const float*)d_in[22];
  const float* fc2b = (const float*)d_in[23];
  float* out = (float*)d_out;
  float* ws = (float*)d_ws;

  // workspace layout (floats)
  float* WT    = ws;                 // 4 * 262144  (ctx_f, ctx_b, agg_f, agg_b)
  float* PREf  = ws + 1048576;       // 2097152
  float* PREb  = ws + 3145728;       // 2097152
  float* HS    = ws + 5242880;       // 1048576  (8,256,512)
  float* NORM  = ws + 6291456;       // 4096     [(seq*2+d)*256+i]
  float* ATT   = ws + 6295552;       // 524288   [d][b][i][j]
  float* RS    = ws + 6819840;       // 2048     [(d*4+b)*256+i]
  float* RMAX  = ws + 6821888;       // 2048
  float* CS    = ws + 6823936;       // 2048
  float* CMAX  = ws + 6825984;       // 2048
  float* MEANH = ws + 6828032;       // 524288   [d][b][i][h]
  float* MEANP = ws + 7352320;       // 524288   [d][b][j][h]
  float* XH    = ws + 7876608;       // 524288
  float* XP    = ws + 8400896;       // 524288
  float* WN1   = ws + 8925184;       // 20480    [d][b][l][i]
  float* WN2   = ws + 8945664;       // 20480
  float* MM    = ws + 8966144;       // 2621440  [b][l][i][j] (per dir, reused)
  float* MMR   = ws + 11587584;      // 20480    [d][b][l][i]
  float* MMC   = ws + 11608064;      // 20480
  float* MV    = ws + 11628544;      // 126976   (2048,62)
  float* HT    = ws + 11755520;      // 4096     [(seq*2+d)*256+j]
  float* XM    = ws + 11759616;      // 2400
  float* X2    = ws + 11762016;      // 2048
  float* W1T   = ws + 11764064;      // 832512

  // scan exchange buffers live in the (idle-during-scans) MM region
  float* HXB = MM;                   // 8192 floats: [dir][parity][256][8]
  int*   FLG = (int*)(MM + 8192);    // 512 ints:   [dir*8+wg]*32

  // 1. transposes
  k_transpose<<<dim3(8,32),  dim3(32,32), 0, stream>>>(cWhhF, WT + 0,      1024, 256);
  k_transpose<<<dim3(8,32),  dim3(32,32), 0, stream>>>(cWhhB, WT + 262144, 1024, 256);
  k_transpose<<<dim3(8,32),  dim3(32,32), 0, stream>>>(aWhhF, WT + 524288, 1024, 256);
  k_transpose<<<dim3(8,32),  dim3(32,32), 0, stream>>>(aWhhB, WT + 786432, 1024, 256);
  k_transpose<<<dim3(51,16), dim3(32,32), 0, stream>>>(fc1W, W1T, 512, 1626);

  // 2. ctx input projections (x @ Wih^T + b)
  k_gemm<0><<<dim3(16,16,1),256,0,stream>>>(left, 300,0,0,  cWihF,300,0,0,  PREf,           1024,0,0,
      nullptr,0,0, nullptr,0,0, nullptr,0,0, cbF, 1024,1024,300, 1);
  k_gemm<0><<<dim3(16,16,1),256,0,stream>>>(right,300,0,0,  cWihF,300,0,0,  PREf+1048576,   1024,0,0,
      nullptr,0,0, nullptr,0,0, nullptr,0,0, cbF, 1024,1024,300, 1);
  k_gemm<0><<<dim3(16,16,1),256,0,stream>>>(left, 300,0,0,  cWihB,300,0,0,  PREb,           1024,0,0,
      nullptr,0,0, nullptr,0,0, nullptr,0,0, cbB, 1024,1024,300, 1);
  k_gemm<0><<<dim3(16,16,1),256,0,stream>>>(right,300,0,0,  cWihB,300,0,0,  PREb+1048576,   1024,0,0,
      nullptr,0,0, nullptr,0,0, nullptr,0,0, cbB, 1024,1024,300, 1);

  // 3. ctx scan (8 WGs/dir, weights pinned in VGPRs, per-half-wave exchange)
  hipMemsetAsync(FLG, 0, 512*sizeof(int), stream);
  k_scan6<<<64,256,0,stream>>>(PREf, PREb, WT, WT+262144, HXB, FLG, HS, nullptr);

  // 4. row norms
  k_rownorm<<<1024,256,0,stream>>>(HS, NORM);

  // 5. att (cosine matrix), z = d*4+b
  k_gemm<1><<<dim3(4,4,8),256,0,stream>>>(HS,512,256,131072,  HS+524288,512,256,131072,
      ATT,256,262144,65536,  nullptr,0,0,  NORM,256,512,  NORM+2048,256,512,
      nullptr, 256,256,256, 4);

  // 6-7. att reductions
  k_rowred<<<512,256,0,stream>>>(ATT, RS, RMAX, 256);
  k_colred<<<dim3(1,1,8),256,0,stream>>>(ATT, 65536, 256, 256, CS, CMAX);

  // 8. attentive means and maxes
  k_gemm<2><<<dim3(4,4,8),256,0,stream>>>(ATT,256,262144,65536,  HS+524288,512,256,131072,
      MEANH,256,262144,65536,  nullptr,0,0,  RS,1024,256,  nullptr,0,0, nullptr, 256,256,256, 4);
  k_gemm<4><<<dim3(4,4,8),256,0,stream>>>(ATT,256,262144,65536,  HS,512,256,131072,
      MEANP,256,262144,65536,  nullptr,0,0,  CS,1024,256,  nullptr,0,0, nullptr, 256,256,256, 4);
  k_gemm<3><<<dim3(4,4,8),256,0,stream>>>(ATT,256,262144,65536,  HS+524288,512,256,131072,
      XH,256,262144,65536,  nullptr,0,0,  nullptr,0,0,  nullptr,0,0, nullptr, 256,256,256, 4);
  k_gemm<5><<<dim3(4,4,8),256,0,stream>>>(ATT,256,262144,65536,  HS,512,256,131072,
      XP,256,262144,65536,  nullptr,0,0,  nullptr,0,0,  nullptr,0,0, nullptr, 256,256,256, 4);

  // 9. weighted norms
  k_wnorm<<<10240,256,0,stream>>>(HS, w3, w4, WN1, WN2);

  // 10-13. pairwise mm (fw then bw, buffer reused), z = b*10+l
  k_gemm<1><<<dim3(4,4,40),256,0,stream>>>(HS,512,131072,0,  HS+524288,512,131072,0,
      MM,256,655360,65536,  w3,0,256,  WN1,2560,256,  WN2,2560,256,
      nullptr, 256,256,256, 10);
  k_rowred<<<2560,256,0,stream>>>(MM, nullptr, MMR, 256);
  k_colred<<<dim3(1,1,40),256,0,stream>>>(MM, 65536, 256, 256, nullptr, MMC);
  k_gemm<1><<<dim3(4,4,40),256,0,stream>>>(HS+256,512,131072,0,  HS+524288+256,512,131072,0,
      MM,256,655360,65536,  w4,0,256,  WN1+10240,2560,256,  WN2+10240,2560,256,
      nullptr, 256,256,256, 10);
  k_rowred<<<2560,256,0,stream>>>(MM, nullptr, MMR+10240, 256);
  k_colred<<<dim3(1,1,40),256,0,stream>>>(MM, 65536, 256, 256, nullptr, MMC+10240);

  // 14. assemble mv (2048 rows x 62)
  k_mv<<<2048,256,0,stream>>>(HS, MEANH, MEANP, XH, XP, RS, RMAX, CS, CMAX,
                              MMR, MMC, w5, w6, w7, w8, MV);

  // 15. agg projections
  k_gemm<0><<<dim3(16,32,1),256,0,stream>>>(MV,62,0,0,  aWihF,62,0,0,  PREf,1024,0,0,
      nullptr,0,0, nullptr,0,0, nullptr,0,0, abF, 2048,1024,62, 1);
  k_gemm<0><<<dim3(16,32,1),256,0,stream>>>(MV,62,0,0,  aWihB,62,0,0,  PREb,1024,0,0,
      nullptr,0,0, nullptr,0,0, nullptr,0,0, abB, 2048,1024,62, 1);

  // 16. agg scan (keep only final h)
  hipMemsetAsync(FLG, 0, 512*sizeof(int), stream);
  k_scan6<<<64,256,0,stream>>>(PREf, PREb, WT+524288, WT+786432, HXB, FLG, nullptr, HT);

  // 17-19. head
  k_means<<<8,320,0,stream>>>(left, right, XM);
  k_fc1<<<4,512,0,stream>>>(HT, XM, W1T, fc1b, X2);
  k_fc2<<<4,64,0,stream>>>(X2, fc2W, fc2b, out);
}

// Round 7
// 3234.100 us; speedup vs baseline: 1.2056x; 1.2056x over previous
//
#include <hip/hip_runtime.h>
#include <hip/hip_bf16.h>
#include <math.h>

#define EPSV 1e-8f

__device__ __forceinline__ float dsmall(float d){ return d > EPSV ? d : EPSV; }
__device__ __forceinline__ float sigf(float x){ return 1.f/(1.f+expf(-x)); }

// ---------------------------------------------------------------------------
// Transpose: W (R x C) -> WT (C x R)
// ---------------------------------------------------------------------------
__global__ __launch_bounds__(1024) void k_transpose(const float* __restrict__ W,
                                                    float* __restrict__ WT, int R, int C){
  __shared__ float t[32][33];
  int rb = blockIdx.y*32, cb = blockIdx.x*32;
  int r = rb + threadIdx.y, c = cb + threadIdx.x;
  if (r < R && c < C) t[threadIdx.y][threadIdx.x] = W[(size_t)r*C + c];
  __syncthreads();
  int rr = cb + threadIdx.y, cc = rb + threadIdx.x;
  if (rr < C && cc < R) WT[(size_t)rr*R + cc] = t[threadIdx.x][threadIdx.y];
}

// ---------------------------------------------------------------------------
// Generic z-batched tiled GEMM-like kernel. 64x64 tile, 256 thr, 4x4/thread.
// MODE 0: C=A(MxK)@B(NxK)^T + bias[n]
// MODE 1: C=(A*wscale^2)(MxK)@B(NxK)^T / dsmall(U[m]*V[n])
// MODE 2: C=A(MxK)@B(KxN) / dsmall(U[m])
// MODE 3: C=max_k A(MxK)*B(KxN)
// MODE 4: C=A(KxM)^T@B(KxN) / dsmall(U[m])
// MODE 5: C=max_k A(KxM)^T*B(KxN)
// ---------------------------------------------------------------------------
template<int MODE>
__global__ __launch_bounds__(256) void k_gemm(
    const float* __restrict__ A0, int lda, long long sAo, long long sAi,
    const float* __restrict__ B0, int ldb, long long sBo, long long sBi,
    float* __restrict__ C0, int ldc, long long sCo, long long sCi,
    const float* __restrict__ W0, long long sWo, long long sWi,
    const float* __restrict__ U0, long long sUo, long long sUi,
    const float* __restrict__ V0, long long sVo, long long sVi,
    const float* __restrict__ bias,
    int M, int N, int K, int zdiv)
{
  const int z = blockIdx.z, zo = z / zdiv, zi = z % zdiv;
  const float* A = A0 + zo*sAo + zi*sAi;
  const float* B = B0 + zo*sBo + zi*sBi;
  float* C = C0 + zo*sCo + zi*sCi;
  const float* Wv = W0 ? (W0 + zo*sWo + zi*sWi) : nullptr;
  const float* U  = U0 ? (U0 + zo*sUo + zi*sUi) : nullptr;
  const float* V  = V0 ? (V0 + zo*sVo + zi*sVi) : nullptr;

  __shared__ float As[16][68];
  __shared__ float Bs[16][68];
  const int mb = blockIdx.y*64, nb = blockIdx.x*64;
  const int tid = threadIdx.x;
  const int tx = tid & 15, ty = tid >> 4;
  const bool ISMAX = (MODE==3 || MODE==5);

  float acc[4][4];
  #pragma unroll
  for (int i=0;i<4;i++)
    #pragma unroll
    for (int j=0;j<4;j++) acc[i][j] = ISMAX ? -INFINITY : 0.f;

  for (int kt = 0; kt < K; kt += 16) {
    // ---- stage A ----
    if (MODE <= 3) {              // A is M x K row-major
      int ka = tid & 15, ma = tid >> 4;
      #pragma unroll
      for (int q=0;q<4;q++){
        int m = ma + q*16;
        float v = 0.f;
        if (mb+m < M && kt+ka < K){
          v = A[(size_t)(mb+m)*lda + kt+ka];
          if (MODE==1 && Wv){ float w = Wv[kt+ka]; v *= w*w; }
        }
        As[ka][m] = v;
      }
    } else {                      // A is K x M row-major (aTb)
      int ma = tid & 63, ka = tid >> 6;
      #pragma unroll
      for (int q=0;q<4;q++){
        int k = ka + q*4;
        float v = 0.f;
        if (kt+k < K && mb+ma < M) v = A[(size_t)(kt+k)*lda + mb+ma];
        As[k][ma] = v;
      }
    }
    // ---- stage B ----
    if (MODE <= 1) {              // B is N x K row-major (B^T gemm)
      int kb = tid & 15, nbi = tid >> 4;
      #pragma unroll
      for (int q=0;q<4;q++){
        int n = nbi + q*16;
        float v = 0.f;
        if (nb+n < N && kt+kb < K) v = B[(size_t)(nb+n)*ldb + kt+kb];
        Bs[kb][n] = v;
      }
    } else {                      // B is K x N row-major
      int nbi = tid & 63, kb = tid >> 6;
      #pragma unroll
      for (int q=0;q<4;q++){
        int k = kb + q*4;
        float v = 0.f;
        if (kt+k < K && nb+nbi < N) v = B[(size_t)(kt+k)*ldb + nb+nbi];
        Bs[k][nbi] = v;
      }
    }
    __syncthreads();
    #pragma unroll
    for (int k=0;k<16;k++){
      float a[4], bv[4];
      #pragma unroll
      for (int i=0;i<4;i++) a[i] = As[k][ty*4+i];
      #pragma unroll
      for (int j=0;j<4;j++) bv[j] = Bs[k][tx*4+j];
      #pragma unroll
      for (int i=0;i<4;i++)
        #pragma unroll
        for (int j=0;j<4;j++){
          if (ISMAX) acc[i][j] = fmaxf(acc[i][j], a[i]*bv[j]);
          else       acc[i][j] += a[i]*bv[j];
        }
    }
    __syncthreads();
  }
  // ---- epilogue ----
  #pragma unroll
  for (int i=0;i<4;i++){
    int m = mb + ty*4 + i;
    if (m >= M) continue;
    #pragma unroll
    for (int j=0;j<4;j++){
      int n = nb + tx*4 + j;
      if (n >= N) continue;
      float v = acc[i][j];
      if (MODE==0){ if (bias) v += bias[n]; }
      else if (MODE==1){ v = v / dsmall(U[m]*V[n]); }
      else if (MODE==2 || MODE==4){ v = v / dsmall(U[m]); }
      C[(size_t)m*ldc + n] = v;
    }
  }
}

// ---------------------------------------------------------------------------
// LSTM scan v7 = R5's lean sync + LDS-resident weights (R2/R4-proven path;
// R5/R6 showed the compiler won't keep a 128-VGPR weight slice resident --
// it remats from L2 (R5) or spills to scratch (R6)).
// 8 WGs/dir, 8 seqs batched, grid=64 (xcd=bx&7 in {0,1} = dir; wg=bx>>3).
// Thread (kc=tid>>5, gq=tid&31): 8 seqs x 4 gate-cols x 32 k per step,
// weights from Wl (contiguous ds_read_b128, ~1024cy/step overlapped w/ FMA).
// Exchange: group kc consumes ONLY h-chunk kc -> per-half-wave poll of
// flag[kc] + 1KB fetch into its own hl rows (no extra barrier).
// 2-parity Hbuf, reuse distance 2: flag[c]=tt certifies WG c's parity-(tt-2)
// reads done -> no clobber.
// ---------------------------------------------------------------------------
__global__ __launch_bounds__(256, 1) void k_scan7(
    const float* __restrict__ PREf, const float* __restrict__ PREb,
    const float* __restrict__ WTf, const float* __restrict__ WTb,
    float* __restrict__ Hbuf, int* __restrict__ flg,
    float* __restrict__ HSo, float* __restrict__ HTo)
{
  const int xcd = blockIdx.x & 7;
  if (xcd > 1) return;
  const int d  = xcd;
  const int wg = blockIdx.x >> 3;
  const float* PRE = d ? PREb : PREf;
  const float* WT  = d ? WTb  : WTf;
  float* Hb = Hbuf + (size_t)d*2*2048;
  int* fl = flg + d*8*32;

  __shared__ float Wl[256][128];     // 128 KB  Wl[k][gt*32+j]
  __shared__ float hl[256][8];       // 8 KB    hl[k][s]; chunk c = rows [c*32,c*32+32)
  __shared__ float red[4][32][40];   // 20 KB   red[kp][s*4+cc][gq] (bank-disjoint)

  const int tid = threadIdx.x;
  const int kc = tid >> 5;   // k-chunk 0..7 (32 k each)
  const int gq = tid & 31;   // gate-col quad
  const int as = tid >> 5;   // activation: seq 0..7
  const int aj = tid & 31;   // activation: h-col within slice

  // stage weight slice into LDS (once; static across all 256 steps)
  for (int e = tid; e < 256*128; e += 256) {
    int k = e >> 7, c = e & 127;
    Wl[k][c] = WT[(size_t)k*1024 + (c>>5)*256 + wg*32 + (c&31)];
  }
  for (int e = tid; e < 2048; e += 256) ((float*)hl)[e] = 0.f;
  float cst = 0.f;
  __syncthreads();

  for (int tt = 0; tt < 256; ++tt) {
    const int t = d ? 255 - tt : tt;
    const int wp = tt & 1;          // parity this iteration stores (h_state(tt+1))
    const int sp = (tt + 1) & 1;    // parity holding h_state(tt) (stored at tt-1)

    // prefetch PRE for activation FIRST (HBM latency hides under spin+matmul)
    const size_t pbase = ((size_t)(as*256 + t))*1024 + wg*32 + aj;
    const float pre0 = PRE[pbase];       const float pre1 = PRE[pbase + 256];
    const float pre2 = PRE[pbase + 512]; const float pre3 = PRE[pbase + 768];

    // ---- per-half-wave fetch of remote chunk kc of h_state(tt) ----
    if (tt > 0 && kc != wg) {
      const int* flp = &fl[kc*32];
      while (__hip_atomic_load(flp, __ATOMIC_RELAXED, __HIP_MEMORY_SCOPE_AGENT) < tt)
        __builtin_amdgcn_s_sleep(1);
      const unsigned long long* srcu =
          (const unsigned long long*)&Hb[sp*2048 + kc*256 + gq*8];
      unsigned long long u0 = __hip_atomic_load(srcu+0, __ATOMIC_RELAXED, __HIP_MEMORY_SCOPE_AGENT);
      unsigned long long u1 = __hip_atomic_load(srcu+1, __ATOMIC_RELAXED, __HIP_MEMORY_SCOPE_AGENT);
      unsigned long long u2 = __hip_atomic_load(srcu+2, __ATOMIC_RELAXED, __HIP_MEMORY_SCOPE_AGENT);
      unsigned long long u3 = __hip_atomic_load(srcu+3, __ATOMIC_RELAXED, __HIP_MEMORY_SCOPE_AGENT);
      unsigned long long* dst = (unsigned long long*)&((float*)hl)[kc*256 + gq*8];
      dst[0] = u0; dst[1] = u1; dst[2] = u2; dst[3] = u3;
    }

    // ---- gate matmul: acc[s][cc] over 32 k of chunk kc, weights from LDS ----
    float acc[8][4];
    #pragma unroll
    for (int s=0;s<8;s++){ acc[s][0]=0.f; acc[s][1]=0.f; acc[s][2]=0.f; acc[s][3]=0.f; }
    #pragma unroll 8
    for (int kk = 0; kk < 32; ++kk) {
      const int k = kc*32 + kk;
      float4 w  = *(const float4*)&Wl[k][gq*4];
      float4 ha = *(const float4*)&hl[k][0];
      float4 hb = *(const float4*)&hl[k][4];
      acc[0][0] += ha.x*w.x; acc[0][1] += ha.x*w.y; acc[0][2] += ha.x*w.z; acc[0][3] += ha.x*w.w;
      acc[1][0] += ha.y*w.x; acc[1][1] += ha.y*w.y; acc[1][2] += ha.y*w.z; acc[1][3] += ha.y*w.w;
      acc[2][0] += ha.z*w.x; acc[2][1] += ha.z*w.y; acc[2][2] += ha.z*w.z; acc[2][3] += ha.z*w.w;
      acc[3][0] += ha.w*w.x; acc[3][1] += ha.w*w.y; acc[3][2] += ha.w*w.z; acc[3][3] += ha.w*w.w;
      acc[4][0] += hb.x*w.x; acc[4][1] += hb.x*w.y; acc[4][2] += hb.x*w.z; acc[4][3] += hb.x*w.w;
      acc[5][0] += hb.y*w.x; acc[5][1] += hb.y*w.y; acc[5][2] += hb.y*w.z; acc[5][3] += hb.y*w.w;
      acc[6][0] += hb.z*w.x; acc[6][1] += hb.z*w.y; acc[6][2] += hb.z*w.z; acc[6][3] += hb.z*w.w;
      acc[7][0] += hb.w*w.x; acc[7][1] += hb.w*w.y; acc[7][2] += hb.w*w.z; acc[7][3] += hb.w*w.w;
    }
    // reduce kc-pairs (lanes l <-> l^32), stash to LDS (lane-stride-1 writes)
    #pragma unroll
    for (int s=0;s<8;s++)
      #pragma unroll
      for (int c2=0;c2<4;c2++)
        acc[s][c2] += __shfl_xor(acc[s][c2], 32, 64);
    if ((tid & 32) == 0) {
      const int kp = kc >> 1;   // 0..3
      #pragma unroll
      for (int s=0;s<8;s++)
        #pragma unroll
        for (int c2=0;c2<4;c2++)
          red[kp][s*4+c2][gq] = acc[s][c2];
    }
    __syncthreads();   // B1: red ready

    // ---- activation + h/c update (all 256 threads) ----
    float hreg;
    {
      float g[4];
      #pragma unroll
      for (int gt=0; gt<4; ++gt) {
        const int c = gt*32 + aj;
        const int gqq = c >> 2, cc = c & 3;
        const int ii = as*4 + cc;
        g[gt] = red[0][ii][gqq] + red[1][ii][gqq] + red[2][ii][gqq] + red[3][ii][gqq];
      }
      g[0] += pre0; g[1] += pre1; g[2] += pre2; g[3] += pre3;
      const float ig = sigf(g[0]), fg = sigf(g[1]), gg = tanhf(g[2]), og = sigf(g[3]);
      cst = fg*cst + ig*gg;
      hreg = og*tanhf(cst);
      // own chunk -> LDS directly (visible WG-wide after B2)
      hl[wg*32 + aj][as] = hreg;
      // publish to peers (L2)
      __hip_atomic_store(&Hb[wp*2048 + (wg*32 + aj)*8 + as], hreg,
                         __ATOMIC_RELAXED, __HIP_MEMORY_SCOPE_AGENT);
    }
    __syncthreads();   // B2: drains Hb stores (vmcnt(0)) + own-hl ds_writes

    // ---- post own flag (own 128B line); peers poll per-half-wave ----
    if (tid == 0)
      __hip_atomic_store(&fl[wg*32], tt+1, __ATOMIC_RELEASE, __HIP_MEMORY_SCOPE_AGENT);

    // ---- HSo/HTo stores OFF the critical path (drained by next B2) ----
    if (HSo) HSo[((size_t)(as*256 + t))*512 + d*256 + wg*32 + aj] = hreg;
    if (HTo && tt == 255) HTo[((size_t)(as*2 + d))*256 + wg*32 + aj] = hreg;
  }
}

// ---------------------------------------------------------------------------
// Row L2 norms of the 4096 (seq,dir,i) hidden rows.
// ---------------------------------------------------------------------------
__global__ __launch_bounds__(256) void k_rownorm(const float* __restrict__ HS_,
                                                 float* __restrict__ NORM_){
  int r = blockIdx.x*4 + (threadIdx.x >> 6);
  int lane = threadIdx.x & 63;
  int seq = r >> 9, d = (r >> 8) & 1, i = r & 255;
  const float* row = HS_ + ((size_t)(seq*256 + i))*512 + d*256;
  float s = 0.f;
  #pragma unroll
  for (int q=0;q<4;q++){ float v = row[lane + 64*q]; s += v*v; }
  for (int off=32; off; off>>=1) s += __shfl_xor(s, off, 64);
  if (lane == 0) NORM_[r] = sqrtf(s);
}

// ---------------------------------------------------------------------------
// Row sum+max reduction (cols elements per row, 4 rows/block)
// ---------------------------------------------------------------------------
__global__ __launch_bounds__(256) void k_rowred(const float* __restrict__ in,
                                                float* __restrict__ osum,
                                                float* __restrict__ omax, int cols){
  int r = blockIdx.x*4 + (threadIdx.x >> 6);
  int lane = threadIdx.x & 63;
  const float* row = in + (size_t)r*cols;
  float s = 0.f, m = -INFINITY;
  for (int cidx=lane; cidx<cols; cidx+=64){ float v=row[cidx]; s += v; m = fmaxf(m,v); }
  for (int off=32; off; off>>=1){ s += __shfl_xor(s,off,64); m = fmaxf(m, __shfl_xor(m,off,64)); }
  if (lane == 0){ if (osum) osum[r] = s; if (omax) omax[r] = m; }
}

// Column sum+max reduction over nrows, 256 cols, one block per z.
__global__ __launch_bounds__(256) void k_colred(const float* __restrict__ in0, long long zstride,
                                                int nrows, int ld,
                                                float* __restrict__ osum, float* __restrict__ omax){
  const float* in = in0 + (size_t)blockIdx.z*zstride;
  int j = threadIdx.x;
  float s = 0.f, m = -INFINITY;
  for (int r=0;r<nrows;r++){ float v = in[(size_t)r*ld + j]; s += v; m = fmaxf(m,v); }
  if (osum) osum[blockIdx.z*256 + j] = s;
  if (omax) omax[blockIdx.z*256 + j] = m;
}

// ---------------------------------------------------------------------------
// Weighted norms for pairwise matching: out[side][d][b][l][i]
// ---------------------------------------------------------------------------
__global__ __launch_bounds__(256) void k_wnorm(const float* __restrict__ HS_,
                                               const float* __restrict__ w3, const float* __restrict__ w4,
                                               float* __restrict__ WN1_, float* __restrict__ WN2_){
  int rid = blockIdx.x*4 + (threadIdx.x >> 6);
  int lane = threadIdx.x & 63;
  int side = rid / 20480; int rem = rid % 20480;
  int d = rem / 10240; int rem2 = rem % 10240;
  int b = rem2 / 2560; int l = (rem2 / 256) % 10; int i = rem2 & 255;
  int seq = side ? 4+b : b;
  const float* row = HS_ + ((size_t)(seq*256 + i))*512 + d*256;
  const float* w = (d ? w4 : w3) + l*256;
  float s = 0.f;
  #pragma unroll
  for (int q=0;q<4;q++){ float wv = w[lane+64*q]; float v = row[lane+64*q]; s += wv*wv*v*v; }
  for (int off=32; off; off>>=1) s += __shfl_xor(s, off, 64);
  if (lane == 0) (side ? WN2_ : WN1_)[rem] = sqrtf(s);
}

// ---------------------------------------------------------------------------
// Assemble mv rows (62 channels) incl. the 40 mp_match channels.
// Block per (side,b,i); 4 waves = 4 (vec,w) pairs.
// ---------------------------------------------------------------------------
__global__ __launch_bounds__(256) void k_mv(
    const float* __restrict__ HS_, const float* __restrict__ MEANH_, const float* __restrict__ MEANP_,
    const float* __restrict__ XH_, const float* __restrict__ XP_,
    const float* __restrict__ RS_, const float* __restrict__ RMAX_,
    const float* __restrict__ CS_, const float* __restrict__ CMAX_,
    const float* __restrict__ MMR_, const float* __restrict__ MMC_,
    const float* __restrict__ w5, const float* __restrict__ w6,
    const float* __restrict__ w7, const float* __restrict__ w8,
    float* __restrict__ MV_)
{
  const int blk = blockIdx.x;
  const int side = blk >> 10, b = (blk >> 8) & 3, i = blk & 255;
  const int wv = threadIdx.x >> 6, lane = threadIdx.x & 63;
  float* mvrow = MV_ + (size_t)blk*62;

  if (threadIdx.x == 0){
    const float* rmax = side ? CMAX_ : RMAX_;
    const float* rsum = side ? CS_   : RS_;
    mvrow[0] = rmax[b*256 + i];              // att_fw max
    mvrow[1] = rsum[b*256 + i] * (1.f/256.f);// att_fw mean
  }
  if (threadIdx.x < 20){
    int dd = threadIdx.x / 10, l = threadIdx.x % 10;
    const float* mm = side ? MMC_ : MMR_;
    mvrow[2 + dd*10 + l] = mm[dd*10240 + (b*10 + l)*256 + i];
  }
  const int d = wv & 1;                      // pairs 0,2 fw; 1,3 bw
  const int seq = side ? 4+b : b;
  const float* arow = HS_ + ((size_t)(seq*256 + i))*512 + d*256;
  const float* Mside = side ? MEANP_ : MEANH_;
  const float* Xside = side ? XP_ : XH_;
  const float* brow = (wv < 2 ? Mside : Xside) + (size_t)d*262144 + (size_t)b*65536 + (size_t)i*256;
  const float* wp = (wv==0) ? w5 : (wv==1) ? w6 : (wv==2) ? w7 : w8;

  float av[4], bv[4];
  #pragma unroll
  for (int q=0;q<4;q++){ av[q] = arow[lane+64*q]; bv[q] = brow[lane+64*q]; }
  for (int l=0;l<10;l++){
    const float* wrow = wp + l*256;
    float s1=0.f, s2=0.f, s3=0.f;
    #pragma unroll
    for (int q=0;q<4;q++){
      float w = wrow[lane+64*q]; float w2v = w*w;
      s1 += w2v*av[q]*bv[q]; s2 += w2v*av[q]*av[q]; s3 += w2v*bv[q]*bv[q];
    }
    for (int off=32; off; off>>=1){
      s1 += __shfl_xor(s1,off,64); s2 += __shfl_xor(s2,off,64); s3 += __shfl_xor(s3,off,64);
    }
    if (lane == 0) mvrow[22 + wv*10 + l] = s1 / fmaxf(sqrtf(s2)*sqrtf(s3), EPSV);
  }
}

// ---------------------------------------------------------------------------
// Mean over time of left/right: XM[b][side*300+d]
// ---------------------------------------------------------------------------
__global__ void k_means(const float* __restrict__ L, const float* __restrict__ R,
                        float* __restrict__ XM){
  int b = blockIdx.x & 3, sideR = blockIdx.x >> 2;
  const float* src = sideR ? R : L;
  int dch = threadIdx.x;
  if (dch >= 300) return;
  float s = 0.f;
  for (int t=0;t<256;t++) s += src[((size_t)(b*256 + t))*300 + dch];
  XM[b*600 + sideR*300 + dch] = s*(1.f/256.f);
}

// ---------------------------------------------------------------------------
// Head: fc1 (tanh), fc2
// ---------------------------------------------------------------------------
__global__ __launch_bounds__(512) void k_fc1(const float* __restrict__ HT_,
                                             const float* __restrict__ XM,
                                             const float* __restrict__ W1T,
                                             const float* __restrict__ b1,
                                             float* __restrict__ X2){
  __shared__ float x[1626];
  int b = blockIdx.x, t = threadIdx.x;
  if (t < 256){
    x[t]       = HT_[(b*2+0)*256 + t];
    x[256+t]   = HT_[(b*2+1)*256 + t];
    x[512+t]   = HT_[((4+b)*2+0)*256 + t];
    x[768+t]   = HT_[((4+b)*2+1)*256 + t];
  }
  if (t == 0){ x[1024] = 0.5f; x[1025] = 0.5f; }
  if (t < 300){ x[1026+t] = XM[b*600 + t]; x[1326+t] = XM[b*600 + 300 + t]; }
  __syncthreads();
  float acc = b1[t];
  for (int k=0;k<1626;k++) acc += x[k]*W1T[(size_t)k*512 + t];
  X2[b*512 + t] = tanhf(acc);
}

__global__ void k_fc2(const float* __restrict__ X2, const float* __restrict__ W2,
                      const float* __restrict__ b2, float* __restrict__ out){
  int b = blockIdx.x, o = threadIdx.x;
  if (o >= 22) return;
  float acc = b2[o];
  const float* xr = X2 + b*512;
  const float* wr = W2 + (size_t)o*512;
  for (int k=0;k<512;k++) acc += xr[k]*wr[k];
  out[b*22 + o] = acc;
}

// ---------------------------------------------------------------------------
extern "C" void kernel_launch(void* const* d_in, const int* in_sizes, int n_in,
                              void* d_out, int out_size, void* d_ws, size_t ws_size,
                              hipStream_t stream) {
  const float* left  = (const float*)d_in[0];
  const float* right = (const float*)d_in[1];
  const float* cWihF = (const float*)d_in[2];
  const float* cWhhF = (const float*)d_in[3];
  const float* cbF   = (const float*)d_in[4];
  const float* cWihB = (const float*)d_in[5];
  const float* cWhhB = (const float*)d_in[6];
  const float* cbB   = (const float*)d_in[7];
  const float* aWihF = (const float*)d_in[8];
  const float* aWhhF = (const float*)d_in[9];
  const float* abF   = (const float*)d_in[10];
  const float* aWihB = (const float*)d_in[11];
  const float* aWhhB = (const float*)d_in[12];
  const float* abB   = (const float*)d_in[13];
  const float* w3 = (const float*)d_in[14];
  const float* w4 = (const float*)d_in[15];
  const float* w5 = (const float*)d_in[16];
  const float* w6 = (const float*)d_in[17];
  const float* w7 = (const float*)d_in[18];
  const float* w8 = (const float*)d_in[19];
  const float* fc1W = (const float*)d_in[20];
  const float* fc1b = (const float*)d_in[21];
  const float* fc2W = (const float*)d_in[22];
  const float* fc2b = (const float*)d_in[23];
  float* out = (float*)d_out;
  float* ws = (float*)d_ws;

  // workspace layout (floats)
  float* WT    = ws;                 // 4 * 262144  (ctx_f, ctx_b, agg_f, agg_b)
  float* PREf  = ws + 1048576;       // 2097152
  float* PREb  = ws + 3145728;       // 2097152
  float* HS    = ws + 5242880;       // 1048576  (8,256,512)
  float* NORM  = ws + 6291456;       // 4096     [(seq*2+d)*256+i]
  float* ATT   = ws + 6295552;       // 524288   [d][b][i][j]
  float* RS    = ws + 6819840;       // 2048     [(d*4+b)*256+i]
  float* RMAX  = ws + 6821888;       // 2048
  float* CS    = ws + 6823936;       // 2048
  float* CMAX  = ws + 6825984;       // 2048
  float* MEANH = ws + 6828032;       // 524288   [d][b][i][h]
  float* MEANP = ws + 7352320;       // 524288   [d][b][j][h]
  float* XH    = ws + 7876608;       // 524288
  float* XP    = ws + 8400896;       // 524288
  float* WN1   = ws + 8925184;       // 20480    [d][b][l][i]
  float* WN2   = ws + 8945664;       // 20480
  float* MM    = ws + 8966144;       // 2621440  [b][l][i][j] (per dir, reused)
  float* MMR   = ws + 11587584;      // 20480    [d][b][l][i]
  float* MMC   = ws + 11608064;      // 20480
  float* MV    = ws + 11628544;      // 126976   (2048,62)
  float* HT    = ws + 11755520;      // 4096     [(seq*2+d)*256+j]
  float* XM    = ws + 11759616;      // 2400
  float* X2    = ws + 11762016;      // 2048
  float* W1T   = ws + 11764064;      // 832512

  // scan exchange buffers live in the (idle-during-scans) MM region
  float* HXB = MM;                   // 8192 floats: [dir][parity][256][8]
  int*   FLG = (int*)(MM + 8192);    // 512 ints:   [dir*8+wg]*32

  // 1. transposes
  k_transpose<<<dim3(8,32),  dim3(32,32), 0, stream>>>(cWhhF, WT + 0,      1024, 256);
  k_transpose<<<dim3(8,32),  dim3(32,32), 0, stream>>>(cWhhB, WT + 262144, 1024, 256);
  k_transpose<<<dim3(8,32),  dim3(32,32), 0, stream>>>(aWhhF, WT + 524288, 1024, 256);
  k_transpose<<<dim3(8,32),  dim3(32,32), 0, stream>>>(aWhhB, WT + 786432, 1024, 256);
  k_transpose<<<dim3(51,16), dim3(32,32), 0, stream>>>(fc1W, W1T, 512, 1626);

  // 2. ctx input projections (x @ Wih^T + b)
  k_gemm<0><<<dim3(16,16,1),256,0,stream>>>(left, 300,0,0,  cWihF,300,0,0,  PREf,           1024,0,0,
      nullptr,0,0, nullptr,0,0, nullptr,0,0, cbF, 1024,1024,300, 1);
  k_gemm<0><<<dim3(16,16,1),256,0,stream>>>(right,300,0,0,  cWihF,300,0,0,  PREf+1048576,   1024,0,0,
      nullptr,0,0, nullptr,0,0, nullptr,0,0, cbF, 1024,1024,300, 1);
  k_gemm<0><<<dim3(16,16,1),256,0,stream>>>(left, 300,0,0,  cWihB,300,0,0,  PREb,           1024,0,0,
      nullptr,0,0, nullptr,0,0, nullptr,0,0, cbB, 1024,1024,300, 1);
  k_gemm<0><<<dim3(16,16,1),256,0,stream>>>(right,300,0,0,  cWihB,300,0,0,  PREb+1048576,   1024,0,0,
      nullptr,0,0, nullptr,0,0, nullptr,0,0, cbB, 1024,1024,300, 1);

  // 3. ctx scan (8 WGs/dir, LDS weights, per-half-wave exchange)
  hipMemsetAsync(FLG, 0, 512*sizeof(int), stream);
  k_scan7<<<64,256,0,stream>>>(PREf, PREb, WT, WT+262144, HXB, FLG, HS, nullptr);

  // 4. row norms
  k_rownorm<<<1024,256,0,stream>>>(HS, NORM);

  // 5. att (cosine matrix), z = d*4+b
  k_gemm<1><<<dim3(4,4,8),256,0,stream>>>(HS,512,256,131072,  HS+524288,512,256,131072,
      ATT,256,262144,65536,  nullptr,0,0,  NORM,256,512,  NORM+2048,256,512,
      nullptr, 256,256,256, 4);

  // 6-7. att reductions
  k_rowred<<<512,256,0,stream>>>(ATT, RS, RMAX, 256);
  k_colred<<<dim3(1,1,8),256,0,stream>>>(ATT, 65536, 256, 256, CS, CMAX);

  // 8. attentive means and maxes
  k_gemm<2><<<dim3(4,4,8),256,0,stream>>>(ATT,256,262144,65536,  HS+524288,512,256,131072,
      MEANH,256,262144,65536,  nullptr,0,0,  RS,1024,256,  nullptr,0,0, nullptr, 256,256,256, 4);
  k_gemm<4><<<dim3(4,4,8),256,0,stream>>>(ATT,256,262144,65536,  HS,512,256,131072,
      MEANP,256,262144,65536,  nullptr,0,0,  CS,1024,256,  nullptr,0,0, nullptr, 256,256,256, 4);
  k_gemm<3><<<dim3(4,4,8),256,0,stream>>>(ATT,256,262144,65536,  HS+524288,512,256,131072,
      XH,256,262144,65536,  nullptr,0,0,  nullptr,0,0,  nullptr,0,0, nullptr, 256,256,256, 4);
  k_gemm<5><<<dim3(4,4,8),256,0,stream>>>(ATT,256,262144,65536,  HS,512,256,131072,
      XP,256,262144,65536,  nullptr,0,0,  nullptr,0,0,  nullptr,0,0, nullptr, 256,256,256, 4);

  // 9. weighted norms
  k_wnorm<<<10240,256,0,stream>>>(HS, w3, w4, WN1, WN2);

  // 10-13. pairwise mm (fw then bw, buffer reused), z = b*10+l
  k_gemm<1><<<dim3(4,4,40),256,0,stream>>>(HS,512,131072,0,  HS+524288,512,131072,0,
      MM,256,655360,65536,  w3,0,256,  WN1,2560,256,  WN2,2560,256,
      nullptr, 256,256,256, 10);
  k_rowred<<<2560,256,0,stream>>>(MM, nullptr, MMR, 256);
  k_colred<<<dim3(1,1,40),256,0,stream>>>(MM, 65536, 256, 256, nullptr, MMC);
  k_gemm<1><<<dim3(4,4,40),256,0,stream>>>(HS+256,512,131072,0,  HS+524288+256,512,131072,0,
      MM,256,655360,65536,  w4,0,256,  WN1+10240,2560,256,  WN2+10240,2560,256,
      nullptr, 256,256,256, 10);
  k_rowred<<<2560,256,0,stream>>>(MM, nullptr, MMR+10240, 256);
  k_colred<<<dim3(1,1,40),256,0,stream>>>(MM, 65536, 256, 256, nullptr, MMC+10240);

  // 14. assemble mv (2048 rows x 62)
  k_mv<<<2048,256,0,stream>>>(HS, MEANH, MEANP, XH, XP, RS, RMAX, CS, CMAX,
                              MMR, MMC, w5, w6, w7, w8, MV);

  // 15. agg projections
  k_gemm<0><<<dim3(16,32,1),256,0,stream>>>(MV,62,0,0,  aWihF,62,0,0,  PREf,1024,0,0,
      nullptr,0,0, nullptr,0,0, nullptr,0,0, abF, 2048,1024,62, 1);
  k_gemm<0><<<dim3(16,32,1),256,0,stream>>>(MV,62,0,0,  aWihB,62,0,0,  PREb,1024,0,0,
      nullptr,0,0, nullptr,0,0, nullptr,0,0, abB, 2048,1024,62, 1);

  // 16. agg scan (keep only final h)
  hipMemsetAsync(FLG, 0, 512*sizeof(int), stream);
  k_scan7<<<64,256,0,stream>>>(PREf, PREb, WT+524288, WT+786432, HXB, FLG, nullptr, HT);

  // 17-19. head
  k_means<<<8,320,0,stream>>>(left, right, XM);
  k_fc1<<<4,512,0,stream>>>(HT, XM, W1T, fc1b, X2);
  k_fc2<<<4,64,0,stream>>>(X2, fc2W, fc2b, out);
}

// Round 8
// 2839.865 us; speedup vs baseline: 1.3729x; 1.1388x over previous
//
#include <hip/hip_runtime.h>
#include <hip/hip_bf16.h>
#include <math.h>

#define EPSV 1e-8f

__device__ __forceinline__ float dsmall(float d){ return d > EPSV ? d : EPSV; }
__device__ __forceinline__ float sigf(float x){ return 1.f/(1.f+expf(-x)); }

// ---------------------------------------------------------------------------
// Transpose: W (R x C) -> WT (C x R)
// ---------------------------------------------------------------------------
__global__ __launch_bounds__(1024) void k_transpose(const float* __restrict__ W,
                                                    float* __restrict__ WT, int R, int C){
  __shared__ float t[32][33];
  int rb = blockIdx.y*32, cb = blockIdx.x*32;
  int r = rb + threadIdx.y, c = cb + threadIdx.x;
  if (r < R && c < C) t[threadIdx.y][threadIdx.x] = W[(size_t)r*C + c];
  __syncthreads();
  int rr = cb + threadIdx.y, cc = rb + threadIdx.x;
  if (rr < C && cc < R) WT[(size_t)rr*R + cc] = t[threadIdx.x][threadIdx.y];
}

// ---------------------------------------------------------------------------
// Generic z-batched tiled GEMM-like kernel. 64x64 tile, 256 thr, 4x4/thread.
// MODE 0: C=A(MxK)@B(NxK)^T + bias[n]
// MODE 1: C=(A*wscale^2)(MxK)@B(NxK)^T / dsmall(U[m]*V[n])
// MODE 2: C=A(MxK)@B(KxN) / dsmall(U[m])
// MODE 3: C=max_k A(MxK)*B(KxN)
// MODE 4: C=A(KxM)^T@B(KxN) / dsmall(U[m])
// MODE 5: C=max_k A(KxM)^T*B(KxN)
// ---------------------------------------------------------------------------
template<int MODE>
__global__ __launch_bounds__(256) void k_gemm(
    const float* __restrict__ A0, int lda, long long sAo, long long sAi,
    const float* __restrict__ B0, int ldb, long long sBo, long long sBi,
    float* __restrict__ C0, int ldc, long long sCo, long long sCi,
    const float* __restrict__ W0, long long sWo, long long sWi,
    const float* __restrict__ U0, long long sUo, long long sUi,
    const float* __restrict__ V0, long long sVo, long long sVi,
    const float* __restrict__ bias,
    int M, int N, int K, int zdiv)
{
  const int z = blockIdx.z, zo = z / zdiv, zi = z % zdiv;
  const float* A = A0 + zo*sAo + zi*sAi;
  const float* B = B0 + zo*sBo + zi*sBi;
  float* C = C0 + zo*sCo + zi*sCi;
  const float* Wv = W0 ? (W0 + zo*sWo + zi*sWi) : nullptr;
  const float* U  = U0 ? (U0 + zo*sUo + zi*sUi) : nullptr;
  const float* V  = V0 ? (V0 + zo*sVo + zi*sVi) : nullptr;

  __shared__ float As[16][68];
  __shared__ float Bs[16][68];
  const int mb = blockIdx.y*64, nb = blockIdx.x*64;
  const int tid = threadIdx.x;
  const int tx = tid & 15, ty = tid >> 4;
  const bool ISMAX = (MODE==3 || MODE==5);

  float acc[4][4];
  #pragma unroll
  for (int i=0;i<4;i++)
    #pragma unroll
    for (int j=0;j<4;j++) acc[i][j] = ISMAX ? -INFINITY : 0.f;

  for (int kt = 0; kt < K; kt += 16) {
    // ---- stage A ----
    if (MODE <= 3) {              // A is M x K row-major
      int ka = tid & 15, ma = tid >> 4;
      #pragma unroll
      for (int q=0;q<4;q++){
        int m = ma + q*16;
        float v = 0.f;
        if (mb+m < M && kt+ka < K){
          v = A[(size_t)(mb+m)*lda + kt+ka];
          if (MODE==1 && Wv){ float w = Wv[kt+ka]; v *= w*w; }
        }
        As[ka][m] = v;
      }
    } else {                      // A is K x M row-major (aTb)
      int ma = tid & 63, ka = tid >> 6;
      #pragma unroll
      for (int q=0;q<4;q++){
        int k = ka + q*4;
        float v = 0.f;
        if (kt+k < K && mb+ma < M) v = A[(size_t)(kt+k)*lda + mb+ma];
        As[k][ma] = v;
      }
    }
    // ---- stage B ----
    if (MODE <= 1) {              // B is N x K row-major (B^T gemm)
      int kb = tid & 15, nbi = tid >> 4;
      #pragma unroll
      for (int q=0;q<4;q++){
        int n = nbi + q*16;
        float v = 0.f;
        if (nb+n < N && kt+kb < K) v = B[(size_t)(nb+n)*ldb + kt+kb];
        Bs[kb][n] = v;
      }
    } else {                      // B is K x N row-major
      int nbi = tid & 63, kb = tid >> 6;
      #pragma unroll
      for (int q=0;q<4;q++){
        int k = kb + q*4;
        float v = 0.f;
        if (kt+k < K && nb+nbi < N) v = B[(size_t)(kt+k)*ldb + nb+nbi];
        Bs[k][nbi] = v;
      }
    }
    __syncthreads();
    #pragma unroll
    for (int k=0;k<16;k++){
      float a[4], bv[4];
      #pragma unroll
      for (int i=0;i<4;i++) a[i] = As[k][ty*4+i];
      #pragma unroll
      for (int j=0;j<4;j++) bv[j] = Bs[k][tx*4+j];
      #pragma unroll
      for (int i=0;i<4;i++)
        #pragma unroll
        for (int j=0;j<4;j++){
          if (ISMAX) acc[i][j] = fmaxf(acc[i][j], a[i]*bv[j]);
          else       acc[i][j] += a[i]*bv[j];
        }
    }
    __syncthreads();
  }
  // ---- epilogue ----
  #pragma unroll
  for (int i=0;i<4;i++){
    int m = mb + ty*4 + i;
    if (m >= M) continue;
    #pragma unroll
    for (int j=0;j<4;j++){
      int n = nb + tx*4 + j;
      if (n >= N) continue;
      float v = acc[i][j];
      if (MODE==0){ if (bias) v += bias[n]; }
      else if (MODE==1){ v = v / dsmall(U[m]*V[n]); }
      else if (MODE==2 || MODE==4){ v = v / dsmall(U[m]); }
      C[(size_t)m*ldc + n] = v;
    }
  }
}

// ---------------------------------------------------------------------------
// LSTM scan v8 = v7 with the flag post RELAXED instead of RELEASE.
// Theory: agent-scope RELEASE on gfx950 lowers to buffer_wbl2 (full dirty-L2
// writeback) + store -- a multi-us op paid per step per WG, explaining the
// ~3.5us/step sync floor invariant across all six prior sync variants.
// Correctness without release: Hb stores are relaxed agent-scope atomics
// (write-through, no L2 allocate); B2's __syncthreads drains vmcnt(0), so
// the h-data is complete at the coherence point BEFORE the relaxed flag
// store issues (in-order vector issue per wave). Consumer: poll load
// completes (s_waitcnt before branch) before data loads issue. No fence
// needed anywhere in the loop.
// ---------------------------------------------------------------------------
__global__ __launch_bounds__(256, 1) void k_scan8(
    const float* __restrict__ PREf, const float* __restrict__ PREb,
    const float* __restrict__ WTf, const float* __restrict__ WTb,
    float* __restrict__ Hbuf, int* __restrict__ flg,
    float* __restrict__ HSo, float* __restrict__ HTo)
{
  const int xcd = blockIdx.x & 7;
  if (xcd > 1) return;
  const int d  = xcd;
  const int wg = blockIdx.x >> 3;
  const float* PRE = d ? PREb : PREf;
  const float* WT  = d ? WTb  : WTf;
  float* Hb = Hbuf + (size_t)d*2*2048;
  int* fl = flg + d*8*32;

  __shared__ float Wl[256][128];     // 128 KB  Wl[k][gt*32+j]
  __shared__ float hl[256][8];       // 8 KB    hl[k][s]; chunk c = rows [c*32,c*32+32)
  __shared__ float red[4][32][40];   // 20 KB   red[kp][s*4+cc][gq] (bank-disjoint)

  const int tid = threadIdx.x;
  const int kc = tid >> 5;   // k-chunk 0..7 (32 k each)
  const int gq = tid & 31;   // gate-col quad
  const int as = tid >> 5;   // activation: seq 0..7
  const int aj = tid & 31;   // activation: h-col within slice

  // stage weight slice into LDS (once; static across all 256 steps)
  for (int e = tid; e < 256*128; e += 256) {
    int k = e >> 7, c = e & 127;
    Wl[k][c] = WT[(size_t)k*1024 + (c>>5)*256 + wg*32 + (c&31)];
  }
  for (int e = tid; e < 2048; e += 256) ((float*)hl)[e] = 0.f;
  float cst = 0.f;
  __syncthreads();

  for (int tt = 0; tt < 256; ++tt) {
    const int t = d ? 255 - tt : tt;
    const int wp = tt & 1;          // parity this iteration stores (h_state(tt+1))
    const int sp = (tt + 1) & 1;    // parity holding h_state(tt) (stored at tt-1)

    // prefetch PRE for activation FIRST (HBM latency hides under spin+matmul)
    const size_t pbase = ((size_t)(as*256 + t))*1024 + wg*32 + aj;
    const float pre0 = PRE[pbase];       const float pre1 = PRE[pbase + 256];
    const float pre2 = PRE[pbase + 512]; const float pre3 = PRE[pbase + 768];

    // ---- per-half-wave fetch of remote chunk kc of h_state(tt) ----
    if (tt > 0 && kc != wg) {
      const int* flp = &fl[kc*32];
      while (__hip_atomic_load(flp, __ATOMIC_RELAXED, __HIP_MEMORY_SCOPE_AGENT) < tt)
        __builtin_amdgcn_s_sleep(1);
      const unsigned long long* srcu =
          (const unsigned long long*)&Hb[sp*2048 + kc*256 + gq*8];
      unsigned long long u0 = __hip_atomic_load(srcu+0, __ATOMIC_RELAXED, __HIP_MEMORY_SCOPE_AGENT);
      unsigned long long u1 = __hip_atomic_load(srcu+1, __ATOMIC_RELAXED, __HIP_MEMORY_SCOPE_AGENT);
      unsigned long long u2 = __hip_atomic_load(srcu+2, __ATOMIC_RELAXED, __HIP_MEMORY_SCOPE_AGENT);
      unsigned long long u3 = __hip_atomic_load(srcu+3, __ATOMIC_RELAXED, __HIP_MEMORY_SCOPE_AGENT);
      unsigned long long* dst = (unsigned long long*)&((float*)hl)[kc*256 + gq*8];
      dst[0] = u0; dst[1] = u1; dst[2] = u2; dst[3] = u3;
    }

    // ---- gate matmul: acc[s][cc] over 32 k of chunk kc, weights from LDS ----
    float acc[8][4];
    #pragma unroll
    for (int s=0;s<8;s++){ acc[s][0]=0.f; acc[s][1]=0.f; acc[s][2]=0.f; acc[s][3]=0.f; }
    #pragma unroll 8
    for (int kk = 0; kk < 32; ++kk) {
      const int k = kc*32 + kk;
      float4 w  = *(const float4*)&Wl[k][gq*4];
      float4 ha = *(const float4*)&hl[k][0];
      float4 hb = *(const float4*)&hl[k][4];
      acc[0][0] += ha.x*w.x; acc[0][1] += ha.x*w.y; acc[0][2] += ha.x*w.z; acc[0][3] += ha.x*w.w;
      acc[1][0] += ha.y*w.x; acc[1][1] += ha.y*w.y; acc[1][2] += ha.y*w.z; acc[1][3] += ha.y*w.w;
      acc[2][0] += ha.z*w.x; acc[2][1] += ha.z*w.y; acc[2][2] += ha.z*w.z; acc[2][3] += ha.z*w.w;
      acc[3][0] += ha.w*w.x; acc[3][1] += ha.w*w.y; acc[3][2] += ha.w*w.z; acc[3][3] += ha.w*w.w;
      acc[4][0] += hb.x*w.x; acc[4][1] += hb.x*w.y; acc[4][2] += hb.x*w.z; acc[4][3] += hb.x*w.w;
      acc[5][0] += hb.y*w.x; acc[5][1] += hb.y*w.y; acc[5][2] += hb.y*w.z; acc[5][3] += hb.y*w.w;
      acc[6][0] += hb.z*w.x; acc[6][1] += hb.z*w.y; acc[6][2] += hb.z*w.z; acc[6][3] += hb.z*w.w;
      acc[7][0] += hb.w*w.x; acc[7][1] += hb.w*w.y; acc[7][2] += hb.w*w.z; acc[7][3] += hb.w*w.w;
    }
    // reduce kc-pairs (lanes l <-> l^32), stash to LDS (lane-stride-1 writes)
    #pragma unroll
    for (int s=0;s<8;s++)
      #pragma unroll
      for (int c2=0;c2<4;c2++)
        acc[s][c2] += __shfl_xor(acc[s][c2], 32, 64);
    if ((tid & 32) == 0) {
      const int kp = kc >> 1;   // 0..3
      #pragma unroll
      for (int s=0;s<8;s++)
        #pragma unroll
        for (int c2=0;c2<4;c2++)
          red[kp][s*4+c2][gq] = acc[s][c2];
    }
    __syncthreads();   // B1: red ready

    // ---- activation + h/c update (all 256 threads) ----
    float hreg;
    {
      float g[4];
      #pragma unroll
      for (int gt=0; gt<4; ++gt) {
        const int c = gt*32 + aj;
        const int gqq = c >> 2, cc = c & 3;
        const int ii = as*4 + cc;
        g[gt] = red[0][ii][gqq] + red[1][ii][gqq] + red[2][ii][gqq] + red[3][ii][gqq];
      }
      g[0] += pre0; g[1] += pre1; g[2] += pre2; g[3] += pre3;
      const float ig = sigf(g[0]), fg = sigf(g[1]), gg = tanhf(g[2]), og = sigf(g[3]);
      cst = fg*cst + ig*gg;
      hreg = og*tanhf(cst);
      // own chunk -> LDS directly (visible WG-wide after B2)
      hl[wg*32 + aj][as] = hreg;
      // publish to peers (write-through to coherence point)
      __hip_atomic_store(&Hb[wp*2048 + (wg*32 + aj)*8 + as], hreg,
                         __ATOMIC_RELAXED, __HIP_MEMORY_SCOPE_AGENT);
    }
    __syncthreads();   // B2: drains Hb stores (vmcnt(0)) + own-hl ds_writes

    // ---- post own flag RELAXED (no buffer_wbl2); data already drained ----
    if (tid == 0)
      __hip_atomic_store(&fl[wg*32], tt+1, __ATOMIC_RELAXED, __HIP_MEMORY_SCOPE_AGENT);

    // ---- HSo/HTo stores OFF the critical path (drained by next B2) ----
    if (HSo) HSo[((size_t)(as*256 + t))*512 + d*256 + wg*32 + aj] = hreg;
    if (HTo && tt == 255) HTo[((size_t)(as*2 + d))*256 + wg*32 + aj] = hreg;
  }
}

// ---------------------------------------------------------------------------
// Row L2 norms of the 4096 (seq,dir,i) hidden rows.
// ---------------------------------------------------------------------------
__global__ __launch_bounds__(256) void k_rownorm(const float* __restrict__ HS_,
                                                 float* __restrict__ NORM_){
  int r = blockIdx.x*4 + (threadIdx.x >> 6);
  int lane = threadIdx.x & 63;
  int seq = r >> 9, d = (r >> 8) & 1, i = r & 255;
  const float* row = HS_ + ((size_t)(seq*256 + i))*512 + d*256;
  float s = 0.f;
  #pragma unroll
  for (int q=0;q<4;q++){ float v = row[lane + 64*q]; s += v*v; }
  for (int off=32; off; off>>=1) s += __shfl_xor(s, off, 64);
  if (lane == 0) NORM_[r] = sqrtf(s);
}

// ---------------------------------------------------------------------------
// Row sum+max reduction (cols elements per row, 4 rows/block)
// ---------------------------------------------------------------------------
__global__ __launch_bounds__(256) void k_rowred(const float* __restrict__ in,
                                                float* __restrict__ osum,
                                                float* __restrict__ omax, int cols){
  int r = blockIdx.x*4 + (threadIdx.x >> 6);
  int lane = threadIdx.x & 63;
  const float* row = in + (size_t)r*cols;
  float s = 0.f, m = -INFINITY;
  for (int cidx=lane; cidx<cols; cidx+=64){ float v=row[cidx]; s += v; m = fmaxf(m,v); }
  for (int off=32; off; off>>=1){ s += __shfl_xor(s,off,64); m = fmaxf(m, __shfl_xor(m,off,64)); }
  if (lane == 0){ if (osum) osum[r] = s; if (omax) omax[r] = m; }
}

// Column sum+max reduction over nrows, 256 cols, one block per z.
__global__ __launch_bounds__(256) void k_colred(const float* __restrict__ in0, long long zstride,
                                                int nrows, int ld,
                                                float* __restrict__ osum, float* __restrict__ omax){
  const float* in = in0 + (size_t)blockIdx.z*zstride;
  int j = threadIdx.x;
  float s = 0.f, m = -INFINITY;
  for (int r=0;r<nrows;r++){ float v = in[(size_t)r*ld + j]; s += v; m = fmaxf(m,v); }
  if (osum) osum[blockIdx.z*256 + j] = s;
  if (omax) omax[blockIdx.z*256 + j] = m;
}

// ---------------------------------------------------------------------------
// Weighted norms for pairwise matching: out[side][d][b][l][i]
// ---------------------------------------------------------------------------
__global__ __launch_bounds__(256) void k_wnorm(const float* __restrict__ HS_,
                                               const float* __restrict__ w3, const float* __restrict__ w4,
                                               float* __restrict__ WN1_, float* __restrict__ WN2_){
  int rid = blockIdx.x*4 + (threadIdx.x >> 6);
  int lane = threadIdx.x & 63;
  int side = rid / 20480; int rem = rid % 20480;
  int d = rem / 10240; int rem2 = rem % 10240;
  int b = rem2 / 2560; int l = (rem2 / 256) % 10; int i = rem2 & 255;
  int seq = side ? 4+b : b;
  const float* row = HS_ + ((size_t)(seq*256 + i))*512 + d*256;
  const float* w = (d ? w4 : w3) + l*256;
  float s = 0.f;
  #pragma unroll
  for (int q=0;q<4;q++){ float wv = w[lane+64*q]; float v = row[lane+64*q]; s += wv*wv*v*v; }
  for (int off=32; off; off>>=1) s += __shfl_xor(s, off, 64);
  if (lane == 0) (side ? WN2_ : WN1_)[rem] = sqrtf(s);
}

// ---------------------------------------------------------------------------
// Assemble mv rows (62 channels) incl. the 40 mp_match channels.
// Block per (side,b,i); 4 waves = 4 (vec,w) pairs.
// ---------------------------------------------------------------------------
__global__ __launch_bounds__(256) void k_mv(
    const float* __restrict__ HS_, const float* __restrict__ MEANH_, const float* __restrict__ MEANP_,
    const float* __restrict__ XH_, const float* __restrict__ XP_,
    const float* __restrict__ RS_, const float* __restrict__ RMAX_,
    const float* __restrict__ CS_, const float* __restrict__ CMAX_,
    const float* __restrict__ MMR_, const float* __restrict__ MMC_,
    const float* __restrict__ w5, const float* __restrict__ w6,
    const float* __restrict__ w7, const float* __restrict__ w8,
    float* __restrict__ MV_)
{
  const int blk = blockIdx.x;
  const int side = blk >> 10, b = (blk >> 8) & 3, i = blk & 255;
  const int wv = threadIdx.x >> 6, lane = threadIdx.x & 63;
  float* mvrow = MV_ + (size_t)blk*62;

  if (threadIdx.x == 0){
    const float* rmax = side ? CMAX_ : RMAX_;
    const float* rsum = side ? CS_   : RS_;
    mvrow[0] = rmax[b*256 + i];              // att_fw max
    mvrow[1] = rsum[b*256 + i] * (1.f/256.f);// att_fw mean
  }
  if (threadIdx.x < 20){
    int dd = threadIdx.x / 10, l = threadIdx.x % 10;
    const float* mm = side ? MMC_ : MMR_;
    mvrow[2 + dd*10 + l] = mm[dd*10240 + (b*10 + l)*256 + i];
  }
  const int d = wv & 1;                      // pairs 0,2 fw; 1,3 bw
  const int seq = side ? 4+b : b;
  const float* arow = HS_ + ((size_t)(seq*256 + i))*512 + d*256;
  const float* Mside = side ? MEANP_ : MEANH_;
  const float* Xside = side ? XP_ : XH_;
  const float* brow = (wv < 2 ? Mside : Xside) + (size_t)d*262144 + (size_t)b*65536 + (size_t)i*256;
  const float* wp = (wv==0) ? w5 : (wv==1) ? w6 : (wv==2) ? w7 : w8;

  float av[4], bv[4];
  #pragma unroll
  for (int q=0;q<4;q++){ av[q] = arow[lane+64*q]; bv[q] = brow[lane+64*q]; }
  for (int l=0;l<10;l++){
    const float* wrow = wp + l*256;
    float s1=0.f, s2=0.f, s3=0.f;
    #pragma unroll
    for (int q=0;q<4;q++){
      float w = wrow[lane+64*q]; float w2v = w*w;
      s1 += w2v*av[q]*bv[q]; s2 += w2v*av[q]*av[q]; s3 += w2v*bv[q]*bv[q];
    }
    for (int off=32; off; off>>=1){
      s1 += __shfl_xor(s1,off,64); s2 += __shfl_xor(s2,off,64); s3 += __shfl_xor(s3,off,64);
    }
    if (lane == 0) mvrow[22 + wv*10 + l] = s1 / fmaxf(sqrtf(s2)*sqrtf(s3), EPSV);
  }
}

// ---------------------------------------------------------------------------
// Mean over time of left/right: XM[b][side*300+d]
// ---------------------------------------------------------------------------
__global__ void k_means(const float* __restrict__ L, const float* __restrict__ R,
                        float* __restrict__ XM){
  int b = blockIdx.x & 3, sideR = blockIdx.x >> 2;
  const float* src = sideR ? R : L;
  int dch = threadIdx.x;
  if (dch >= 300) return;
  float s = 0.f;
  for (int t=0;t<256;t++) s += src[((size_t)(b*256 + t))*300 + dch];
  XM[b*600 + sideR*300 + dch] = s*(1.f/256.f);
}

// ---------------------------------------------------------------------------
// Head: fc1 (tanh), fc2
// ---------------------------------------------------------------------------
__global__ __launch_bounds__(512) void k_fc1(const float* __restrict__ HT_,
                                             const float* __restrict__ XM,
                                             const float* __restrict__ W1T,
                                             const float* __restrict__ b1,
                                             float* __restrict__ X2){
  __shared__ float x[1626];
  int b = blockIdx.x, t = threadIdx.x;
  if (t < 256){
    x[t]       = HT_[(b*2+0)*256 + t];
    x[256+t]   = HT_[(b*2+1)*256 + t];
    x[512+t]   = HT_[((4+b)*2+0)*256 + t];
    x[768+t]   = HT_[((4+b)*2+1)*256 + t];
  }
  if (t == 0){ x[1024] = 0.5f; x[1025] = 0.5f; }
  if (t < 300){ x[1026+t] = XM[b*600 + t]; x[1326+t] = XM[b*600 + 300 + t]; }
  __syncthreads();
  float acc = b1[t];
  for (int k=0;k<1626;k++) acc += x[k]*W1T[(size_t)k*512 + t];
  X2[b*512 + t] = tanhf(acc);
}

__global__ void k_fc2(const float* __restrict__ X2, const float* __restrict__ W2,
                      const float* __restrict__ b2, float* __restrict__ out){
  int b = blockIdx.x, o = threadIdx.x;
  if (o >= 22) return;
  float acc = b2[o];
  const float* xr = X2 + b*512;
  const float* wr = W2 + (size_t)o*512;
  for (int k=0;k<512;k++) acc += xr[k]*wr[k];
  out[b*22 + o] = acc;
}

// ---------------------------------------------------------------------------
extern "C" void kernel_launch(void* const* d_in, const int* in_sizes, int n_in,
                              void* d_out, int out_size, void* d_ws, size_t ws_size,
                              hipStream_t stream) {
  const float* left  = (const float*)d_in[0];
  const float* right = (const float*)d_in[1];
  const float* cWihF = (const float*)d_in[2];
  const float* cWhhF = (const float*)d_in[3];
  const float* cbF   = (const float*)d_in[4];
  const float* cWihB = (const float*)d_in[5];
  const float* cWhhB = (const float*)d_in[6];
  const float* cbB   = (const float*)d_in[7];
  const float* aWihF = (const float*)d_in[8];
  const float* aWhhF = (const float*)d_in[9];
  const float* abF   = (const float*)d_in[10];
  const float* aWihB = (const float*)d_in[11];
  const float* aWhhB = (const float*)d_in[12];
  const float* abB   = (const float*)d_in[13];
  const float* w3 = (const float*)d_in[14];
  const float* w4 = (const float*)d_in[15];
  const float* w5 = (const float*)d_in[16];
  const float* w6 = (const float*)d_in[17];
  const float* w7 = (const float*)d_in[18];
  const float* w8 = (const float*)d_in[19];
  const float* fc1W = (const float*)d_in[20];
  const float* fc1b = (const float*)d_in[21];
  const float* fc2W = (const float*)d_in[22];
  const float* fc2b = (const float*)d_in[23];
  float* out = (float*)d_out;
  float* ws = (float*)d_ws;

  // workspace layout (floats)
  float* WT    = ws;                 // 4 * 262144  (ctx_f, ctx_b, agg_f, agg_b)
  float* PREf  = ws + 1048576;       // 2097152
  float* PREb  = ws + 3145728;       // 2097152
  float* HS    = ws + 5242880;       // 1048576  (8,256,512)
  float* NORM  = ws + 6291456;       // 4096     [(seq*2+d)*256+i]
  float* ATT   = ws + 6295552;       // 524288   [d][b][i][j]
  float* RS    = ws + 6819840;       // 2048     [(d*4+b)*256+i]
  float* RMAX  = ws + 6821888;       // 2048
  float* CS    = ws + 6823936;       // 2048
  float* CMAX  = ws + 6825984;       // 2048
  float* MEANH = ws + 6828032;       // 524288   [d][b][i][h]
  float* MEANP = ws + 7352320;       // 524288   [d][b][j][h]
  float* XH    = ws + 7876608;       // 524288
  float* XP    = ws + 8400896;       // 524288
  float* WN1   = ws + 8925184;       // 20480    [d][b][l][i]
  float* WN2   = ws + 8945664;       // 20480
  float* MM    = ws + 8966144;       // 2621440  [b][l][i][j] (per dir, reused)
  float* MMR   = ws + 11587584;      // 20480    [d][b][l][i]
  float* MMC   = ws + 11608064;      // 20480
  float* MV    = ws + 11628544;      // 126976   (2048,62)
  float* HT    = ws + 11755520;      // 4096     [(seq*2+d)*256+j]
  float* XM    = ws + 11759616;      // 2400
  float* X2    = ws + 11762016;      // 2048
  float* W1T   = ws + 11764064;      // 832512

  // scan exchange buffers live in the (idle-during-scans) MM region
  float* HXB = MM;                   // 8192 floats: [dir][parity][256][8]
  int*   FLG = (int*)(MM + 8192);    // 512 ints:   [dir*8+wg]*32

  // 1. transposes
  k_transpose<<<dim3(8,32),  dim3(32,32), 0, stream>>>(cWhhF, WT + 0,      1024, 256);
  k_transpose<<<dim3(8,32),  dim3(32,32), 0, stream>>>(cWhhB, WT + 262144, 1024, 256);
  k_transpose<<<dim3(8,32),  dim3(32,32), 0, stream>>>(aWhhF, WT + 524288, 1024, 256);
  k_transpose<<<dim3(8,32),  dim3(32,32), 0, stream>>>(aWhhB, WT + 786432, 1024, 256);
  k_transpose<<<dim3(51,16), dim3(32,32), 0, stream>>>(fc1W, W1T, 512, 1626);

  // 2. ctx input projections (x @ Wih^T + b)
  k_gemm<0><<<dim3(16,16,1),256,0,stream>>>(left, 300,0,0,  cWihF,300,0,0,  PREf,           1024,0,0,
      nullptr,0,0, nullptr,0,0, nullptr,0,0, cbF, 1024,1024,300, 1);
  k_gemm<0><<<dim3(16,16,1),256,0,stream>>>(right,300,0,0,  cWihF,300,0,0,  PREf+1048576,   1024,0,0,
      nullptr,0,0, nullptr,0,0, nullptr,0,0, cbF, 1024,1024,300, 1);
  k_gemm<0><<<dim3(16,16,1),256,0,stream>>>(left, 300,0,0,  cWihB,300,0,0,  PREb,           1024,0,0,
      nullptr,0,0, nullptr,0,0, nullptr,0,0, cbB, 1024,1024,300, 1);
  k_gemm<0><<<dim3(16,16,1),256,0,stream>>>(right,300,0,0,  cWihB,300,0,0,  PREb+1048576,   1024,0,0,
      nullptr,0,0, nullptr,0,0, nullptr,0,0, cbB, 1024,1024,300, 1);

  // 3. ctx scan (8 WGs/dir, LDS weights, relaxed-flag exchange)
  hipMemsetAsync(FLG, 0, 512*sizeof(int), stream);
  k_scan8<<<64,256,0,stream>>>(PREf, PREb, WT, WT+262144, HXB, FLG, HS, nullptr);

  // 4. row norms
  k_rownorm<<<1024,256,0,stream>>>(HS, NORM);

  // 5. att (cosine matrix), z = d*4+b
  k_gemm<1><<<dim3(4,4,8),256,0,stream>>>(HS,512,256,131072,  HS+524288,512,256,131072,
      ATT,256,262144,65536,  nullptr,0,0,  NORM,256,512,  NORM+2048,256,512,
      nullptr, 256,256,256, 4);

  // 6-7. att reductions
  k_rowred<<<512,256,0,stream>>>(ATT, RS, RMAX, 256);
  k_colred<<<dim3(1,1,8),256,0,stream>>>(ATT, 65536, 256, 256, CS, CMAX);

  // 8. attentive means and maxes
  k_gemm<2><<<dim3(4,4,8),256,0,stream>>>(ATT,256,262144,65536,  HS+524288,512,256,131072,
      MEANH,256,262144,65536,  nullptr,0,0,  RS,1024,256,  nullptr,0,0, nullptr, 256,256,256, 4);
  k_gemm<4><<<dim3(4,4,8),256,0,stream>>>(ATT,256,262144,65536,  HS,512,256,131072,
      MEANP,256,262144,65536,  nullptr,0,0,  CS,1024,256,  nullptr,0,0, nullptr, 256,256,256, 4);
  k_gemm<3><<<dim3(4,4,8),256,0,stream>>>(ATT,256,262144,65536,  HS+524288,512,256,131072,
      XH,256,262144,65536,  nullptr,0,0,  nullptr,0,0,  nullptr,0,0, nullptr, 256,256,256, 4);
  k_gemm<5><<<dim3(4,4,8),256,0,stream>>>(ATT,256,262144,65536,  HS,512,256,131072,
      XP,256,262144,65536,  nullptr,0,0,  nullptr,0,0,  nullptr,0,0, nullptr, 256,256,256, 4);

  // 9. weighted norms
  k_wnorm<<<10240,256,0,stream>>>(HS, w3, w4, WN1, WN2);

  // 10-13. pairwise mm (fw then bw, buffer reused), z = b*10+l
  k_gemm<1><<<dim3(4,4,40),256,0,stream>>>(HS,512,131072,0,  HS+524288,512,131072,0,
      MM,256,655360,65536,  w3,0,256,  WN1,2560,256,  WN2,2560,256,
      nullptr, 256,256,256, 10);
  k_rowred<<<2560,256,0,stream>>>(MM, nullptr, MMR, 256);
  k_colred<<<dim3(1,1,40),256,0,stream>>>(MM, 65536, 256, 256, nullptr, MMC);
  k_gemm<1><<<dim3(4,4,40),256,0,stream>>>(HS+256,512,131072,0,  HS+524288+256,512,131072,0,
      MM,256,655360,65536,  w4,0,256,  WN1+10240,2560,256,  WN2+10240,2560,256,
      nullptr, 256,256,256, 10);
  k_rowred<<<2560,256,0,stream>>>(MM, nullptr, MMR+10240, 256);
  k_colred<<<dim3(1,1,40),256,0,stream>>>(MM, 65536, 256, 256, nullptr, MMC+10240);

  // 14. assemble mv (2048 rows x 62)
  k_mv<<<2048,256,0,stream>>>(HS, MEANH, MEANP, XH, XP, RS, RMAX, CS, CMAX,
                              MMR, MMC, w5, w6, w7, w8, MV);

  // 15. agg projections
  k_gemm<0><<<dim3(16,32,1),256,0,stream>>>(MV,62,0,0,  aWihF,62,0,0,  PREf,1024,0,0,
      nullptr,0,0, nullptr,0,0, nullptr,0,0, abF, 2048,1024,62, 1);
  k_gemm<0><<<dim3(16,32,1),256,0,stream>>>(MV,62,0,0,  aWihB,62,0,0,  PREb,1024,0,0,
      nullptr,0,0, nullptr,0,0, nullptr,0,0, abB, 2048,1024,62, 1);

  // 16. agg scan (keep only final h)
  hipMemsetAsync(FLG, 0, 512*sizeof(int), stream);
  k_scan8<<<64,256,0,stream>>>(PREf, PREb, WT+524288, WT+786432, HXB, FLG, nullptr, HT);

  // 17-19. head
  k_means<<<8,320,0,stream>>>(left, right, XM);
  k_fc1<<<4,512,0,stream>>>(HT, XM, W1T, fc1b, X2);
  k_fc2<<<4,64,0,stream>>>(X2, fc2W, fc2b, out);
}

// Round 9
// 2702.218 us; speedup vs baseline: 1.4429x; 1.0509x over previous
//
#include <hip/hip_runtime.h>
#include <hip/hip_bf16.h>
#include <math.h>

#define EPSV 1e-8f

__device__ __forceinline__ float dsmall(float d){ return d > EPSV ? d : EPSV; }
__device__ __forceinline__ float sigf(float x){ return 1.f/(1.f+expf(-x)); }

// ---------------------------------------------------------------------------
// Transpose: W (R x C) -> WT (C x R)
// ---------------------------------------------------------------------------
__global__ __launch_bounds__(1024) void k_transpose(const float* __restrict__ W,
                                                    float* __restrict__ WT, int R, int C){
  __shared__ float t[32][33];
  int rb = blockIdx.y*32, cb = blockIdx.x*32;
  int r = rb + threadIdx.y, c = cb + threadIdx.x;
  if (r < R && c < C) t[threadIdx.y][threadIdx.x] = W[(size_t)r*C + c];
  __syncthreads();
  int rr = cb + threadIdx.y, cc = rb + threadIdx.x;
  if (rr < C && cc < R) WT[(size_t)rr*R + cc] = t[threadIdx.x][threadIdx.y];
}

// ---------------------------------------------------------------------------
// Generic z-batched tiled GEMM-like kernel. 64x64 tile, 256 thr, 4x4/thread.
// MODE 0: C=A(MxK)@B(NxK)^T + bias[zi*bstride+n]
// MODE 1: C=(A*w^2)(MxK)@B(NxK)^T / dsmall(U[m]*V[n])
// ---------------------------------------------------------------------------
template<int MODE>
__global__ __launch_bounds__(256) void k_gemm(
    const float* __restrict__ A0, int lda, long long sAo, long long sAi,
    const float* __restrict__ B0, int ldb, long long sBo, long long sBi,
    float* __restrict__ C0, int ldc, long long sCo, long long sCi,
    const float* __restrict__ W0, long long sWo, long long sWi,
    const float* __restrict__ U0, long long sUo, long long sUi,
    const float* __restrict__ V0, long long sVo, long long sVi,
    const float* __restrict__ bias, int bstride,
    int M, int N, int K, int zdiv)
{
  const int z = blockIdx.z, zo = z / zdiv, zi = z % zdiv;
  const float* A = A0 + zo*sAo + zi*sAi;
  const float* B = B0 + zo*sBo + zi*sBi;
  float* C = C0 + zo*sCo + zi*sCi;
  const float* Wv = W0 ? (W0 + zo*sWo + zi*sWi) : nullptr;
  const float* U  = U0 ? (U0 + zo*sUo + zi*sUi) : nullptr;
  const float* V  = V0 ? (V0 + zo*sVo + zi*sVi) : nullptr;

  __shared__ float As[16][68];
  __shared__ float Bs[16][68];
  const int mb = blockIdx.y*64, nb = blockIdx.x*64;
  const int tid = threadIdx.x;
  const int tx = tid & 15, ty = tid >> 4;

  float acc[4][4];
  #pragma unroll
  for (int i=0;i<4;i++)
    #pragma unroll
    for (int j=0;j<4;j++) acc[i][j] = 0.f;

  for (int kt = 0; kt < K; kt += 16) {
    int ka = tid & 15, ma = tid >> 4;
    #pragma unroll
    for (int q=0;q<4;q++){
      int m = ma + q*16;
      float v = 0.f;
      if (mb+m < M && kt+ka < K){
        v = A[(size_t)(mb+m)*lda + kt+ka];
        if (MODE==1 && Wv){ float w = Wv[kt+ka]; v *= w*w; }
      }
      As[ka][m] = v;
      float bvv = 0.f;
      if (nb+m < N && kt+ka < K) bvv = B[(size_t)(nb+m)*ldb + kt+ka];
      Bs[ka][m] = bvv;
    }
    __syncthreads();
    #pragma unroll
    for (int k=0;k<16;k++){
      float a[4], bv[4];
      #pragma unroll
      for (int i=0;i<4;i++) a[i] = As[k][ty*4+i];
      #pragma unroll
      for (int j=0;j<4;j++) bv[j] = Bs[k][tx*4+j];
      #pragma unroll
      for (int i=0;i<4;i++)
        #pragma unroll
        for (int j=0;j<4;j++) acc[i][j] += a[i]*bv[j];
    }
    __syncthreads();
  }
  #pragma unroll
  for (int i=0;i<4;i++){
    int m = mb + ty*4 + i;
    if (m >= M) continue;
    #pragma unroll
    for (int j=0;j<4;j++){
      int n = nb + tx*4 + j;
      if (n >= N) continue;
      float v = acc[i][j];
      if (MODE==0){ if (bias) v += bias[zi*bstride + n]; }
      else { v = v / dsmall(U[m]*V[n]); }
      C[(size_t)m*ldc + n] = v;
    }
  }
}

// ---------------------------------------------------------------------------
// Fused attentive stats: mean (sum/dsmall(U)) and max in one pass.
// grid (4,4,16): z16>=8 -> col variant (mean_p / max_p), else row variant.
// All dims 256.
// ---------------------------------------------------------------------------
__global__ __launch_bounds__(256) void k_attstat(
    const float* __restrict__ ATT_, const float* __restrict__ HS_,
    const float* __restrict__ RS_, const float* __restrict__ CS_,
    float* __restrict__ MEANH_, float* __restrict__ XH_,
    float* __restrict__ MEANP_, float* __restrict__ XP_)
{
  const int z16 = blockIdx.z;
  const int var = z16 >> 3;          // 0: row (A@B), 1: col (A^T@B)
  const int z = z16 & 7;             // d*4+b
  const int d = z >> 2, b = z & 3;
  const float* A = ATT_ + (size_t)z*65536;                 // lda 256
  const float* B = (var ? HS_ : HS_ + 524288) + d*256 + (size_t)b*131072; // ldb 512
  const float* U = (var ? CS_ : RS_) + z*256;
  float* C1 = (var ? MEANP_ : MEANH_) + (size_t)z*65536;
  float* C2 = (var ? XP_    : XH_   ) + (size_t)z*65536;

  __shared__ float As[16][68];
  __shared__ float Bs[16][68];
  const int mb = blockIdx.y*64, nb = blockIdx.x*64;
  const int tid = threadIdx.x;
  const int tx = tid & 15, ty = tid >> 4;

  float asum[4][4], amax[4][4];
  #pragma unroll
  for (int i=0;i<4;i++)
    #pragma unroll
    for (int j=0;j<4;j++){ asum[i][j]=0.f; amax[i][j]=-INFINITY; }

  for (int kt = 0; kt < 256; kt += 16) {
    if (var == 0) {
      int ka = tid & 15, ma = tid >> 4;
      #pragma unroll
      for (int q=0;q<4;q++)
        As[ka][ma+q*16] = A[(size_t)(mb+ma+q*16)*256 + kt+ka];
    } else {
      int ma = tid & 63, ka = tid >> 6;
      #pragma unroll
      for (int q=0;q<4;q++)
        As[ka+q*4][ma] = A[(size_t)(kt+ka+q*4)*256 + mb+ma];
    }
    {
      int nbi = tid & 63, kb = tid >> 6;
      #pragma unroll
      for (int q=0;q<4;q++)
        Bs[kb+q*4][nbi] = B[(size_t)(kt+kb+q*4)*512 + nb+nbi];
    }
    __syncthreads();
    #pragma unroll
    for (int k=0;k<16;k++){
      float a[4], bv[4];
      #pragma unroll
      for (int i=0;i<4;i++) a[i] = As[k][ty*4+i];
      #pragma unroll
      for (int j=0;j<4;j++) bv[j] = Bs[k][tx*4+j];
      #pragma unroll
      for (int i=0;i<4;i++)
        #pragma unroll
        for (int j=0;j<4;j++){
          float p = a[i]*bv[j];
          asum[i][j] += p;
          amax[i][j] = fmaxf(amax[i][j], p);
        }
    }
    __syncthreads();
  }
  #pragma unroll
  for (int i=0;i<4;i++){
    int m = mb + ty*4 + i;
    float ud = dsmall(U[m]);
    #pragma unroll
    for (int j=0;j<4;j++){
      int n = nb + tx*4 + j;
      C1[(size_t)m*256 + n] = asum[i][j] / ud;
      C2[(size_t)m*256 + n] = amax[i][j];
    }
  }
}

// ---------------------------------------------------------------------------
// Pairwise mp-match with fused row/col max reduction (never materializes MM).
// grid (4,4,40), z=b*10+l. Outputs partial maxes PARTR[(z*4+bx)*256+row],
// PARTC[(z*4+by)*256+col].
// ---------------------------------------------------------------------------
__global__ __launch_bounds__(256) void k_pmm(
    const float* __restrict__ A0, const float* __restrict__ B0,
    const float* __restrict__ W0, const float* __restrict__ U0,
    const float* __restrict__ V0,
    float* __restrict__ PARTR, float* __restrict__ PARTC)
{
  const int z = blockIdx.z;
  const int bq = z / 10, l = z % 10;
  const float* A = A0 + (size_t)bq*131072;
  const float* B = B0 + (size_t)bq*131072;
  const float* Wv = W0 + l*256;
  const float* U = U0 + bq*2560 + l*256;
  const float* V = V0 + bq*2560 + l*256;

  __shared__ float As[16][68];
  __shared__ float Bs[16][68];
  const int mb = blockIdx.y*64, nb = blockIdx.x*64;
  const int tid = threadIdx.x;
  const int tx = tid & 15, ty = tid >> 4;

  float acc[4][4];
  #pragma unroll
  for (int i=0;i<4;i++)
    #pragma unroll
    for (int j=0;j<4;j++) acc[i][j] = 0.f;

  for (int kt = 0; kt < 256; kt += 16) {
    int ka = tid & 15, ma = tid >> 4;
    float w = Wv[kt+ka]; float w2 = w*w;
    #pragma unroll
    for (int q=0;q<4;q++){
      As[ka][ma+q*16] = A[(size_t)(mb+ma+q*16)*512 + kt+ka] * w2;
      Bs[ka][ma+q*16] = B[(size_t)(nb+ma+q*16)*512 + kt+ka];
    }
    __syncthreads();
    #pragma unroll
    for (int k=0;k<16;k++){
      float a[4], bv[4];
      #pragma unroll
      for (int i=0;i<4;i++) a[i] = As[k][ty*4+i];
      #pragma unroll
      for (int j=0;j<4;j++) bv[j] = Bs[k][tx*4+j];
      #pragma unroll
      for (int i=0;i<4;i++)
        #pragma unroll
        for (int j=0;j<4;j++) acc[i][j] += a[i]*bv[j];
    }
    __syncthreads();
  }
  float um[4], vn[4];
  #pragma unroll
  for (int i=0;i<4;i++) um[i] = U[mb + ty*4 + i];
  #pragma unroll
  for (int j=0;j<4;j++) vn[j] = V[nb + tx*4 + j];
  float c[4][4];
  #pragma unroll
  for (int i=0;i<4;i++)
    #pragma unroll
    for (int j=0;j<4;j++) c[i][j] = acc[i][j] / dsmall(um[i]*vn[j]);

  // row-max: reduce over the 16 tx lanes (16-aligned shfl groups)
  float rm[4];
  #pragma unroll
  for (int i=0;i<4;i++){
    rm[i] = fmaxf(fmaxf(c[i][0], c[i][1]), fmaxf(c[i][2], c[i][3]));
    rm[i] = fmaxf(rm[i], __shfl_xor(rm[i], 1, 64));
    rm[i] = fmaxf(rm[i], __shfl_xor(rm[i], 2, 64));
    rm[i] = fmaxf(rm[i], __shfl_xor(rm[i], 4, 64));
    rm[i] = fmaxf(rm[i], __shfl_xor(rm[i], 8, 64));
  }
  if ((tid & 15) == 0){
    #pragma unroll
    for (int i=0;i<4;i++)
      PARTR[((size_t)z*4 + blockIdx.x)*256 + mb + ty*4 + i] = rm[i];
  }
  // col-max via LDS (reuse As)
  __syncthreads();
  float* colp = &As[0][0];           // 1088 floats >= 16*64
  #pragma unroll
  for (int j=0;j<4;j++)
    colp[ty*64 + tx*4 + j] = fmaxf(fmaxf(c[0][j], c[1][j]), fmaxf(c[2][j], c[3][j]));
  __syncthreads();
  if (tid < 64){
    float m = colp[tid];
    #pragma unroll
    for (int r=1;r<16;r++) m = fmaxf(m, colp[r*64 + tid]);
    PARTC[((size_t)z*4 + blockIdx.y)*256 + nb + tid] = m;
  }
}

__global__ void k_pcomb(const float* __restrict__ PARTR, const float* __restrict__ PARTC,
                        float* __restrict__ MMRo, float* __restrict__ MMCo){
  int z = blockIdx.x, i = threadIdx.x;
  size_t b0 = (size_t)z*4*256 + i;
  float r = fmaxf(fmaxf(PARTR[b0], PARTR[b0+256]), fmaxf(PARTR[b0+512], PARTR[b0+768]));
  float c = fmaxf(fmaxf(PARTC[b0], PARTC[b0+256]), fmaxf(PARTC[b0+512], PARTC[b0+768]));
  MMRo[(size_t)z*256 + i] = r;
  MMCo[(size_t)z*256 + i] = c;
}

// ---------------------------------------------------------------------------
// LSTM scan v9 = v8 + per-wave sub-flags (flag post before B2; each wave
// drains its own Hb stores via s_waitcnt vmcnt(0), posts its sub-flag) +
// 16B sub-flag poll + sched_barrier hardening, no s_sleep.
// fl line per WG: ints [0..3] = per-wave sub-flags (one 128B line).
// ---------------------------------------------------------------------------
__global__ __launch_bounds__(256, 1) void k_scan9(
    const float* __restrict__ PREf, const float* __restrict__ PREb,
    const float* __restrict__ WTf, const float* __restrict__ WTb,
    float* __restrict__ Hbuf, int* __restrict__ flg,
    float* __restrict__ HSo, float* __restrict__ HTo)
{
  const int xcd = blockIdx.x & 7;
  if (xcd > 1) return;
  const int d  = xcd;
  const int wg = blockIdx.x >> 3;
  const float* PRE = d ? PREb : PREf;
  const float* WT  = d ? WTb  : WTf;
  float* Hb = Hbuf + (size_t)d*2*2048;
  int* fl = flg + d*8*32;

  __shared__ float Wl[256][128];     // 128 KB  Wl[k][gt*32+j]
  __shared__ float hl[256][8];       // 8 KB    hl[k][s]; chunk c = rows [c*32,c*32+32)
  __shared__ float red[4][32][40];   // 20 KB   red[kp][s*4+cc][gq] (bank-disjoint)

  const int tid = threadIdx.x;
  const int kc = tid >> 5;   // k-chunk 0..7 (32 k each)
  const int gq = tid & 31;   // gate-col quad
  const int as = tid >> 5;   // activation: seq 0..7
  const int aj = tid & 31;   // activation: h-col within slice

  for (int e = tid; e < 256*128; e += 256) {
    int k = e >> 7, c = e & 127;
    Wl[k][c] = WT[(size_t)k*1024 + (c>>5)*256 + wg*32 + (c&31)];
  }
  for (int e = tid; e < 2048; e += 256) ((float*)hl)[e] = 0.f;
  float cst = 0.f;
  __syncthreads();

  for (int tt = 0; tt < 256; ++tt) {
    const int t = d ? 255 - tt : tt;
    const int wp = tt & 1;
    const int sp = (tt + 1) & 1;

    // prefetch PRE (latency hides under poll+matmul)
    const size_t pbase = ((size_t)(as*256 + t))*1024 + wg*32 + aj;
    const float pre0 = PRE[pbase];       const float pre1 = PRE[pbase + 256];
    const float pre2 = PRE[pbase + 512]; const float pre3 = PRE[pbase + 768];

    // ---- per-half-wave: poll 4 sub-flags (16B) + fetch 1KB chunk ----
    if (tt > 0 && kc != wg) {
      const unsigned long long* flu = (const unsigned long long*)&fl[kc*32];
      for (;;) {
        unsigned long long a = __hip_atomic_load(flu+0, __ATOMIC_RELAXED, __HIP_MEMORY_SCOPE_AGENT);
        unsigned long long b = __hip_atomic_load(flu+1, __ATOMIC_RELAXED, __HIP_MEMORY_SCOPE_AGENT);
        int m01 = min((int)(unsigned)a, (int)(a >> 32));
        int m23 = min((int)(unsigned)b, (int)(b >> 32));
        if (min(m01, m23) >= tt) break;
      }
      __builtin_amdgcn_sched_barrier(0);
      const unsigned long long* srcu =
          (const unsigned long long*)&Hb[sp*2048 + kc*256 + gq*8];
      unsigned long long u0 = __hip_atomic_load(srcu+0, __ATOMIC_RELAXED, __HIP_MEMORY_SCOPE_AGENT);
      unsigned long long u1 = __hip_atomic_load(srcu+1, __ATOMIC_RELAXED, __HIP_MEMORY_SCOPE_AGENT);
      unsigned long long u2 = __hip_atomic_load(srcu+2, __ATOMIC_RELAXED, __HIP_MEMORY_SCOPE_AGENT);
      unsigned long long u3 = __hip_atomic_load(srcu+3, __ATOMIC_RELAXED, __HIP_MEMORY_SCOPE_AGENT);
      unsigned long long* dst = (unsigned long long*)&((float*)hl)[kc*256 + gq*8];
      dst[0] = u0; dst[1] = u1; dst[2] = u2; dst[3] = u3;
    }

    // ---- gate matmul over chunk kc, weights from LDS ----
    float acc[8][4];
    #pragma unroll
    for (int s=0;s<8;s++){ acc[s][0]=0.f; acc[s][1]=0.f; acc[s][2]=0.f; acc[s][3]=0.f; }
    #pragma unroll 8
    for (int kk = 0; kk < 32; ++kk) {
      const int k = kc*32 + kk;
      float4 w  = *(const float4*)&Wl[k][gq*4];
      float4 ha = *(const float4*)&hl[k][0];
      float4 hb = *(const float4*)&hl[k][4];
      acc[0][0] += ha.x*w.x; acc[0][1] += ha.x*w.y; acc[0][2] += ha.x*w.z; acc[0][3] += ha.x*w.w;
      acc[1][0] += ha.y*w.x; acc[1][1] += ha.y*w.y; acc[1][2] += ha.y*w.z; acc[1][3] += ha.y*w.w;
      acc[2][0] += ha.z*w.x; acc[2][1] += ha.z*w.y; acc[2][2] += ha.z*w.z; acc[2][3] += ha.z*w.w;
      acc[3][0] += ha.w*w.x; acc[3][1] += ha.w*w.y; acc[3][2] += ha.w*w.z; acc[3][3] += ha.w*w.w;
      acc[4][0] += hb.x*w.x; acc[4][1] += hb.x*w.y; acc[4][2] += hb.x*w.z; acc[4][3] += hb.x*w.w;
      acc[5][0] += hb.y*w.x; acc[5][1] += hb.y*w.y; acc[5][2] += hb.y*w.z; acc[5][3] += hb.y*w.w;
      acc[6][0] += hb.z*w.x; acc[6][1] += hb.z*w.y; acc[6][2] += hb.z*w.z; acc[6][3] += hb.z*w.w;
      acc[7][0] += hb.w*w.x; acc[7][1] += hb.w*w.y; acc[7][2] += hb.w*w.z; acc[7][3] += hb.w*w.w;
    }
    #pragma unroll
    for (int s=0;s<8;s++)
      #pragma unroll
      for (int c2=0;c2<4;c2++)
        acc[s][c2] += __shfl_xor(acc[s][c2], 32, 64);
    if ((tid & 32) == 0) {
      const int kp = kc >> 1;
      #pragma unroll
      for (int s=0;s<8;s++)
        #pragma unroll
        for (int c2=0;c2<4;c2++)
          red[kp][s*4+c2][gq] = acc[s][c2];
    }
    __syncthreads();   // B1

    // ---- activation + h/c update ----
    float hreg;
    {
      float g[4];
      #pragma unroll
      for (int gt=0; gt<4; ++gt) {
        const int c = gt*32 + aj;
        const int gqq = c >> 2, cc = c & 3;
        const int ii = as*4 + cc;
        g[gt] = red[0][ii][gqq] + red[1][ii][gqq] + red[2][ii][gqq] + red[3][ii][gqq];
      }
      g[0] += pre0; g[1] += pre1; g[2] += pre2; g[3] += pre3;
      const float ig = sigf(g[0]), fg = sigf(g[1]), gg = tanhf(g[2]), og = sigf(g[3]);
      cst = fg*cst + ig*gg;
      hreg = og*tanhf(cst);
      hl[wg*32 + aj][as] = hreg;
      __hip_atomic_store(&Hb[wp*2048 + (wg*32 + aj)*8 + as], hreg,
                         __ATOMIC_RELAXED, __HIP_MEMORY_SCOPE_AGENT);
    }
    // per-wave early sub-flag: drain own Hb stores, then post (before B2)
    asm volatile("s_waitcnt vmcnt(0)" ::: "memory");
    if ((tid & 63) == 0)
      __hip_atomic_store(&fl[wg*32 + (tid >> 6)], tt + 1,
                         __ATOMIC_RELAXED, __HIP_MEMORY_SCOPE_AGENT);
    __builtin_amdgcn_sched_barrier(0);

    // off-critical-path outputs
    if (HSo) HSo[((size_t)(as*256 + t))*512 + d*256 + wg*32 + aj] = hreg;
    if (HTo && tt == 255) HTo[((size_t)(as*2 + d))*256 + wg*32 + aj] = hreg;

    __syncthreads();   // B2: hl own-chunk visibility for next step
  }
}

// ---------------------------------------------------------------------------
// Row L2 norms of the 4096 (seq,dir,i) hidden rows.
// ---------------------------------------------------------------------------
__global__ __launch_bounds__(256) void k_rownorm(const float* __restrict__ HS_,
                                                 float* __restrict__ NORM_){
  int r = blockIdx.x*4 + (threadIdx.x >> 6);
  int lane = threadIdx.x & 63;
  int seq = r >> 9, d = (r >> 8) & 1, i = r & 255;
  const float* row = HS_ + ((size_t)(seq*256 + i))*512 + d*256;
  float s = 0.f;
  #pragma unroll
  for (int q=0;q<4;q++){ float v = row[lane + 64*q]; s += v*v; }
  for (int off=32; off; off>>=1) s += __shfl_xor(s, off, 64);
  if (lane == 0) NORM_[r] = sqrtf(s);
}

// ---------------------------------------------------------------------------
// Row sum+max reduction (cols elements per row, 4 rows/block)
// ---------------------------------------------------------------------------
__global__ __launch_bounds__(256) void k_rowred(const float* __restrict__ in,
                                                float* __restrict__ osum,
                                                float* __restrict__ omax, int cols){
  int r = blockIdx.x*4 + (threadIdx.x >> 6);
  int lane = threadIdx.x & 63;
  const float* row = in + (size_t)r*cols;
  float s = 0.f, m = -INFINITY;
  for (int cidx=lane; cidx<cols; cidx+=64){ float v=row[cidx]; s += v; m = fmaxf(m,v); }
  for (int off=32; off; off>>=1){ s += __shfl_xor(s,off,64); m = fmaxf(m, __shfl_xor(m,off,64)); }
  if (lane == 0){ if (osum) osum[r] = s; if (omax) omax[r] = m; }
}

// Column sum+max reduction over nrows, 256 cols, one block per z.
__global__ __launch_bounds__(256) void k_colred(const float* __restrict__ in0, long long zstride,
                                                int nrows, int ld,
                                                float* __restrict__ osum, float* __restrict__ omax){
  const float* in = in0 + (size_t)blockIdx.z*zstride;
  int j = threadIdx.x;
  float s = 0.f, m = -INFINITY;
  for (int r=0;r<nrows;r++){ float v = in[(size_t)r*ld + j]; s += v; m = fmaxf(m,v); }
  if (osum) osum[blockIdx.z*256 + j] = s;
  if (omax) omax[blockIdx.z*256 + j] = m;
}

// ---------------------------------------------------------------------------
// Weighted norms for pairwise matching: out[side][d][b][l][i]
// ---------------------------------------------------------------------------
__global__ __launch_bounds__(256) void k_wnorm(const float* __restrict__ HS_,
                                               const float* __restrict__ w3, const float* __restrict__ w4,
                                               float* __restrict__ WN1_, float* __restrict__ WN2_){
  int rid = blockIdx.x*4 + (threadIdx.x >> 6);
  int lane = threadIdx.x & 63;
  int side = rid / 20480; int rem = rid % 20480;
  int d = rem / 10240; int rem2 = rem % 10240;
  int b = rem2 / 2560; int l = (rem2 / 256) % 10; int i = rem2 & 255;
  int seq = side ? 4+b : b;
  const float* row = HS_ + ((size_t)(seq*256 + i))*512 + d*256;
  const float* w = (d ? w4 : w3) + l*256;
  float s = 0.f;
  #pragma unroll
  for (int q=0;q<4;q++){ float wv = w[lane+64*q]; float v = row[lane+64*q]; s += wv*wv*v*v; }
  for (int off=32; off; off>>=1) s += __shfl_xor(s, off, 64);
  if (lane == 0) (side ? WN2_ : WN1_)[rem] = sqrtf(s);
}

// ---------------------------------------------------------------------------
// Assemble mv rows (62 channels) incl. the 40 mp_match channels.
// ---------------------------------------------------------------------------
__global__ __launch_bounds__(256) void k_mv(
    const float* __restrict__ HS_, const float* __restrict__ MEANH_, const float* __restrict__ MEANP_,
    const float* __restrict__ XH_, const float* __restrict__ XP_,
    const float* __restrict__ RS_, const float* __restrict__ RMAX_,
    const float* __restrict__ CS_, const float* __restrict__ CMAX_,
    const float* __restrict__ MMR_, const float* __restrict__ MMC_,
    const float* __restrict__ w5, const float* __restrict__ w6,
    const float* __restrict__ w7, const float* __restrict__ w8,
    float* __restrict__ MV_)
{
  const int blk = blockIdx.x;
  const int side = blk >> 10, b = (blk >> 8) & 3, i = blk & 255;
  const int wv = threadIdx.x >> 6, lane = threadIdx.x & 63;
  float* mvrow = MV_ + (size_t)blk*62;

  if (threadIdx.x == 0){
    const float* rmax = side ? CMAX_ : RMAX_;
    const float* rsum = side ? CS_   : RS_;
    mvrow[0] = rmax[b*256 + i];
    mvrow[1] = rsum[b*256 + i] * (1.f/256.f);
  }
  if (threadIdx.x < 20){
    int dd = threadIdx.x / 10, l = threadIdx.x % 10;
    const float* mm = side ? MMC_ : MMR_;
    mvrow[2 + dd*10 + l] = mm[dd*10240 + (b*10 + l)*256 + i];
  }
  const int d = wv & 1;
  const int seq = side ? 4+b : b;
  const float* arow = HS_ + ((size_t)(seq*256 + i))*512 + d*256;
  const float* Mside = side ? MEANP_ : MEANH_;
  const float* Xside = side ? XP_ : XH_;
  const float* brow = (wv < 2 ? Mside : Xside) + (size_t)d*262144 + (size_t)b*65536 + (size_t)i*256;
  const float* wp = (wv==0) ? w5 : (wv==1) ? w6 : (wv==2) ? w7 : w8;

  float av[4], bv[4];
  #pragma unroll
  for (int q=0;q<4;q++){ av[q] = arow[lane+64*q]; bv[q] = brow[lane+64*q]; }
  for (int l=0;l<10;l++){
    const float* wrow = wp + l*256;
    float s1=0.f, s2=0.f, s3=0.f;
    #pragma unroll
    for (int q=0;q<4;q++){
      float w = wrow[lane+64*q]; float w2v = w*w;
      s1 += w2v*av[q]*bv[q]; s2 += w2v*av[q]*av[q]; s3 += w2v*bv[q]*bv[q];
    }
    for (int off=32; off; off>>=1){
      s1 += __shfl_xor(s1,off,64); s2 += __shfl_xor(s2,off,64); s3 += __shfl_xor(s3,off,64);
    }
    if (lane == 0) mvrow[22 + wv*10 + l] = s1 / fmaxf(sqrtf(s2)*sqrtf(s3), EPSV);
  }
}

// ---------------------------------------------------------------------------
// Mean over time of left/right: XM[b][side*300+d]
// ---------------------------------------------------------------------------
__global__ void k_means(const float* __restrict__ L, const float* __restrict__ R,
                        float* __restrict__ XM){
  int b = blockIdx.x & 3, sideR = blockIdx.x >> 2;
  const float* src = sideR ? R : L;
  int dch = threadIdx.x;
  if (dch >= 300) return;
  float s = 0.f;
  for (int t=0;t<256;t++) s += src[((size_t)(b*256 + t))*300 + dch];
  XM[b*600 + sideR*300 + dch] = s*(1.f/256.f);
}

// ---------------------------------------------------------------------------
// Head: fc1 (tanh), fc2
// ---------------------------------------------------------------------------
__global__ __launch_bounds__(512) void k_fc1(const float* __restrict__ HT_,
                                             const float* __restrict__ XM,
                                             const float* __restrict__ W1T,
                                             const float* __restrict__ b1,
                                             float* __restrict__ X2){
  __shared__ float x[1626];
  int b = blockIdx.x, t = threadIdx.x;
  if (t < 256){
    x[t]       = HT_[(b*2+0)*256 + t];
    x[256+t]   = HT_[(b*2+1)*256 + t];
    x[512+t]   = HT_[((4+b)*2+0)*256 + t];
    x[768+t]   = HT_[((4+b)*2+1)*256 + t];
  }
  if (t == 0){ x[1024] = 0.5f; x[1025] = 0.5f; }
  if (t < 300){ x[1026+t] = XM[b*600 + t]; x[1326+t] = XM[b*600 + 300 + t]; }
  __syncthreads();
  float acc = b1[t];
  for (int k=0;k<1626;k++) acc += x[k]*W1T[(size_t)k*512 + t];
  X2[b*512 + t] = tanhf(acc);
}

__global__ void k_fc2(const float* __restrict__ X2, const float* __restrict__ W2,
                      const float* __restrict__ b2, float* __restrict__ out){
  int b = blockIdx.x, o = threadIdx.x;
  if (o >= 22) return;
  float acc = b2[o];
  const float* xr = X2 + b*512;
  const float* wr = W2 + (size_t)o*512;
  for (int k=0;k<512;k++) acc += xr[k]*wr[k];
  out[b*22 + o] = acc;
}

// ---------------------------------------------------------------------------
extern "C" void kernel_launch(void* const* d_in, const int* in_sizes, int n_in,
                              void* d_out, int out_size, void* d_ws, size_t ws_size,
                              hipStream_t stream) {
  const float* left  = (const float*)d_in[0];
  const float* right = (const float*)d_in[1];
  const float* cWihF = (const float*)d_in[2];
  const float* cWhhF = (const float*)d_in[3];
  const float* cbF   = (const float*)d_in[4];
  const float* cWihB = (const float*)d_in[5];
  const float* cWhhB = (const float*)d_in[6];
  const float* cbB   = (const float*)d_in[7];
  const float* aWihF = (const float*)d_in[8];
  const float* aWhhF = (const float*)d_in[9];
  const float* abF   = (const float*)d_in[10];
  const float* aWihB = (const float*)d_in[11];
  const float* aWhhB = (const float*)d_in[12];
  const float* abB   = (const float*)d_in[13];
  const float* w3 = (const float*)d_in[14];
  const float* w4 = (const float*)d_in[15];
  const float* w5 = (const float*)d_in[16];
  const float* w6 = (const float*)d_in[17];
  const float* w7 = (const float*)d_in[18];
  const float* w8 = (const float*)d_in[19];
  const float* fc1W = (const float*)d_in[20];
  const float* fc1b = (const float*)d_in[21];
  const float* fc2W = (const float*)d_in[22];
  const float* fc2b = (const float*)d_in[23];
  float* out = (float*)d_out;
  float* ws = (float*)d_ws;

  // workspace layout (floats)
  float* WT    = ws;                 // 4 * 262144
  float* PREf  = ws + 1048576;       // 2097152
  float* PREb  = ws + 3145728;       // 2097152
  float* HS    = ws + 5242880;       // 1048576  (8,256,512)
  float* NORM  = ws + 6291456;       // 4096
  float* ATT   = ws + 6295552;       // 524288   [d][b][i][j]
  float* RS    = ws + 6819840;       // 2048
  float* RMAX  = ws + 6821888;       // 2048
  float* CS    = ws + 6823936;       // 2048
  float* CMAX  = ws + 6825984;       // 2048
  float* MEANH = ws + 6828032;       // 524288
  float* MEANP = ws + 7352320;       // 524288
  float* XH    = ws + 7876608;       // 524288
  float* XP    = ws + 8400896;       // 524288
  float* WN1   = ws + 8925184;       // 20480
  float* WN2   = ws + 8945664;       // 20480
  float* MM    = ws + 8966144;       // 2621440 scratch (HXB/FLG, copies, PART)
  float* MMR   = ws + 11587584;      // 20480
  float* MMC   = ws + 11608064;      // 20480
  float* MV    = ws + 11628544;      // 126976
  float* HT    = ws + 11755520;      // 4096
  float* XM    = ws + 11759616;      // 2400
  float* X2    = ws + 11762016;      // 2048
  float* W1T   = ws + 11764064;      // 832512

  // MM-region overlays (time-multiplexed):
  float* HXB  = MM;                   // scans: 8192 floats
  int*   FLG  = (int*)(MM + 8192);    // scans: 512 ints
  float* XCAT = MM;                   // ctx proj staging (pre-scan): 614400
  float* WCAT = MM + 614400;          // 614400
  float* BCAT = MM + 1228800;         // 2048
  float* PARTR= MM;                   // pairwise partials: 40960
  float* PARTC= MM + 40960;           // 40960
  float* AGGW = MM + 1048576;         // agg proj staging: 126976
  float* AGGB = MM + 1175552;         // 2048

  // 1. transposes
  k_transpose<<<dim3(8,32),  dim3(32,32), 0, stream>>>(cWhhF, WT + 0,      1024, 256);
  k_transpose<<<dim3(8,32),  dim3(32,32), 0, stream>>>(cWhhB, WT + 262144, 1024, 256);
  k_transpose<<<dim3(8,32),  dim3(32,32), 0, stream>>>(aWhhF, WT + 524288, 1024, 256);
  k_transpose<<<dim3(8,32),  dim3(32,32), 0, stream>>>(aWhhB, WT + 786432, 1024, 256);
  k_transpose<<<dim3(51,16), dim3(32,32), 0, stream>>>(fc1W, W1T, 512, 1626);

  // 2. ctx input projections, batched z=4 (zo=side, zi=wdir)
  hipMemcpyAsync(XCAT,          left,  307200*4, hipMemcpyDeviceToDevice, stream);
  hipMemcpyAsync(XCAT + 307200, right, 307200*4, hipMemcpyDeviceToDevice, stream);
  hipMemcpyAsync(WCAT,          cWihF, 307200*4, hipMemcpyDeviceToDevice, stream);
  hipMemcpyAsync(WCAT + 307200, cWihB, 307200*4, hipMemcpyDeviceToDevice, stream);
  hipMemcpyAsync(BCAT,          cbF,   1024*4,   hipMemcpyDeviceToDevice, stream);
  hipMemcpyAsync(BCAT + 1024,   cbB,   1024*4,   hipMemcpyDeviceToDevice, stream);
  k_gemm<0><<<dim3(16,16,4),256,0,stream>>>(XCAT,300, 307200,0,  WCAT,300, 0,307200,
      PREf,1024, 1048576,2097152,  nullptr,0,0, nullptr,0,0, nullptr,0,0,
      BCAT, 1024, 1024,1024,300, 2);

  // 3. ctx scan
  hipMemsetAsync(FLG, 0, 512*sizeof(int), stream);
  k_scan9<<<64,256,0,stream>>>(PREf, PREb, WT, WT+262144, HXB, FLG, HS, nullptr);

  // 4. row norms
  k_rownorm<<<1024,256,0,stream>>>(HS, NORM);

  // 5. att (cosine matrix), z = d*4+b
  k_gemm<1><<<dim3(4,4,8),256,0,stream>>>(HS,512,256,131072,  HS+524288,512,256,131072,
      ATT,256,262144,65536,  nullptr,0,0,  NORM,256,512,  NORM+2048,256,512,
      nullptr,0, 256,256,256, 4);

  // 6-7. att reductions
  k_rowred<<<512,256,0,stream>>>(ATT, RS, RMAX, 256);
  k_colred<<<dim3(1,1,8),256,0,stream>>>(ATT, 65536, 256, 256, CS, CMAX);

  // 8. attentive means and maxes (fused, one launch)
  k_attstat<<<dim3(4,4,16),256,0,stream>>>(ATT, HS, RS, CS, MEANH, XH, MEANP, XP);

  // 9. weighted norms
  k_wnorm<<<10240,256,0,stream>>>(HS, w3, w4, WN1, WN2);

  // 10-13. pairwise mm with fused max-reductions (MM never materialized)
  k_pmm<<<dim3(4,4,40),256,0,stream>>>(HS, HS+524288, w3, WN1, WN2, PARTR, PARTC);
  k_pcomb<<<40,256,0,stream>>>(PARTR, PARTC, MMR, MMC);
  k_pmm<<<dim3(4,4,40),256,0,stream>>>(HS+256, HS+524288+256, w4, WN1+10240, WN2+10240, PARTR, PARTC);
  k_pcomb<<<40,256,0,stream>>>(PARTR, PARTC, MMR+10240, MMC+10240);

  // 14. assemble mv (2048 rows x 62)
  k_mv<<<2048,256,0,stream>>>(HS, MEANH, MEANP, XH, XP, RS, RMAX, CS, CMAX,
                              MMR, MMC, w5, w6, w7, w8, MV);

  // 15. agg projections, batched z=2 (zi=wdir)
  hipMemcpyAsync(AGGW,         aWihF, 63488*4, hipMemcpyDeviceToDevice, stream);
  hipMemcpyAsync(AGGW + 63488, aWihB, 63488*4, hipMemcpyDeviceToDevice, stream);
  hipMemcpyAsync(AGGB,         abF,   1024*4,  hipMemcpyDeviceToDevice, stream);
  hipMemcpyAsync(AGGB + 1024,  abB,   1024*4,  hipMemcpyDeviceToDevice, stream);
  k_gemm<0><<<dim3(16,32,2),256,0,stream>>>(MV,62, 0,0,  AGGW,62, 0,63488,
      PREf,1024, 0,2097152,  nullptr,0,0, nullptr,0,0, nullptr,0,0,
      AGGB, 1024, 2048,1024,62, 2);

  // 16. agg scan (keep only final h)
  hipMemsetAsync(FLG, 0, 512*sizeof(int), stream);
  k_scan9<<<64,256,0,stream>>>(PREf, PREb, WT+524288, WT+786432, HXB, FLG, nullptr, HT);

  // 17-19. head
  k_means<<<8,320,0,stream>>>(left, right, XM);
  k_fc1<<<4,512,0,stream>>>(HT, XM, W1T, fc1b, X2);
  k_fc2<<<4,64,0,stream>>>(X2, fc2W, fc2b, out);
}

// Round 10
// 2429.534 us; speedup vs baseline: 1.6048x; 1.1122x over previous
//
#include <hip/hip_runtime.h>
#include <hip/hip_bf16.h>
#include <math.h>

#define EPSV 1e-8f

__device__ __forceinline__ float dsmall(float d){ return d > EPSV ? d : EPSV; }
__device__ __forceinline__ float sigf(float x){ return 1.f/(1.f+expf(-x)); }

// ---------------------------------------------------------------------------
// Transpose: W (R x C) -> WT (C x R)
// ---------------------------------------------------------------------------
__global__ __launch_bounds__(1024) void k_transpose(const float* __restrict__ W,
                                                    float* __restrict__ WT, int R, int C){
  __shared__ float t[32][33];
  int rb = blockIdx.y*32, cb = blockIdx.x*32;
  int r = rb + threadIdx.y, c = cb + threadIdx.x;
  if (r < R && c < C) t[threadIdx.y][threadIdx.x] = W[(size_t)r*C + c];
  __syncthreads();
  int rr = cb + threadIdx.y, cc = rb + threadIdx.x;
  if (rr < C && cc < R) WT[(size_t)rr*R + cc] = t[threadIdx.x][threadIdx.y];
}

// ---------------------------------------------------------------------------
// Generic z-batched tiled GEMM-like kernel. 64x64 tile, 256 thr, 4x4/thread.
// MODE 0: C=A(MxK)@B(NxK)^T + bias[zi*bstride+n]
// MODE 1: C=(A*w^2)(MxK)@B(NxK)^T / dsmall(U[m]*V[n])
// ---------------------------------------------------------------------------
template<int MODE>
__global__ __launch_bounds__(256) void k_gemm(
    const float* __restrict__ A0, int lda, long long sAo, long long sAi,
    const float* __restrict__ B0, int ldb, long long sBo, long long sBi,
    float* __restrict__ C0, int ldc, long long sCo, long long sCi,
    const float* __restrict__ W0, long long sWo, long long sWi,
    const float* __restrict__ U0, long long sUo, long long sUi,
    const float* __restrict__ V0, long long sVo, long long sVi,
    const float* __restrict__ bias, int bstride,
    int M, int N, int K, int zdiv)
{
  const int z = blockIdx.z, zo = z / zdiv, zi = z % zdiv;
  const float* A = A0 + zo*sAo + zi*sAi;
  const float* B = B0 + zo*sBo + zi*sBi;
  float* C = C0 + zo*sCo + zi*sCi;
  const float* Wv = W0 ? (W0 + zo*sWo + zi*sWi) : nullptr;
  const float* U  = U0 ? (U0 + zo*sUo + zi*sUi) : nullptr;
  const float* V  = V0 ? (V0 + zo*sVo + zi*sVi) : nullptr;

  __shared__ float As[16][68];
  __shared__ float Bs[16][68];
  const int mb = blockIdx.y*64, nb = blockIdx.x*64;
  const int tid = threadIdx.x;
  const int tx = tid & 15, ty = tid >> 4;

  float acc[4][4];
  #pragma unroll
  for (int i=0;i<4;i++)
    #pragma unroll
    for (int j=0;j<4;j++) acc[i][j] = 0.f;

  for (int kt = 0; kt < K; kt += 16) {
    int ka = tid & 15, ma = tid >> 4;
    #pragma unroll
    for (int q=0;q<4;q++){
      int m = ma + q*16;
      float v = 0.f;
      if (mb+m < M && kt+ka < K){
        v = A[(size_t)(mb+m)*lda + kt+ka];
        if (MODE==1 && Wv){ float w = Wv[kt+ka]; v *= w*w; }
      }
      As[ka][m] = v;
      float bvv = 0.f;
      if (nb+m < N && kt+ka < K) bvv = B[(size_t)(nb+m)*ldb + kt+ka];
      Bs[ka][m] = bvv;
    }
    __syncthreads();
    #pragma unroll
    for (int k=0;k<16;k++){
      float a[4], bv[4];
      #pragma unroll
      for (int i=0;i<4;i++) a[i] = As[k][ty*4+i];
      #pragma unroll
      for (int j=0;j<4;j++) bv[j] = Bs[k][tx*4+j];
      #pragma unroll
      for (int i=0;i<4;i++)
        #pragma unroll
        for (int j=0;j<4;j++) acc[i][j] += a[i]*bv[j];
    }
    __syncthreads();
  }
  #pragma unroll
  for (int i=0;i<4;i++){
    int m = mb + ty*4 + i;
    if (m >= M) continue;
    #pragma unroll
    for (int j=0;j<4;j++){
      int n = nb + tx*4 + j;
      if (n >= N) continue;
      float v = acc[i][j];
      if (MODE==0){ if (bias) v += bias[zi*bstride + n]; }
      else { v = v / dsmall(U[m]*V[n]); }
      C[(size_t)m*ldc + n] = v;
    }
  }
}

// ---------------------------------------------------------------------------
// Fused attentive stats: mean (sum/dsmall(U)) and max in one pass.
// grid (4,4,16): z16>=8 -> col variant (mean_p / max_p), else row variant.
// ---------------------------------------------------------------------------
__global__ __launch_bounds__(256) void k_attstat(
    const float* __restrict__ ATT_, const float* __restrict__ HS_,
    const float* __restrict__ RS_, const float* __restrict__ CS_,
    float* __restrict__ MEANH_, float* __restrict__ XH_,
    float* __restrict__ MEANP_, float* __restrict__ XP_)
{
  const int z16 = blockIdx.z;
  const int var = z16 >> 3;          // 0: row (A@B), 1: col (A^T@B)
  const int z = z16 & 7;             // d*4+b
  const int d = z >> 2, b = z & 3;
  const float* A = ATT_ + (size_t)z*65536;                 // lda 256
  const float* B = (var ? HS_ : HS_ + 524288) + d*256 + (size_t)b*131072; // ldb 512
  const float* U = (var ? CS_ : RS_) + z*256;
  float* C1 = (var ? MEANP_ : MEANH_) + (size_t)z*65536;
  float* C2 = (var ? XP_    : XH_   ) + (size_t)z*65536;

  __shared__ float As[16][68];
  __shared__ float Bs[16][68];
  const int mb = blockIdx.y*64, nb = blockIdx.x*64;
  const int tid = threadIdx.x;
  const int tx = tid & 15, ty = tid >> 4;

  float asum[4][4], amax[4][4];
  #pragma unroll
  for (int i=0;i<4;i++)
    #pragma unroll
    for (int j=0;j<4;j++){ asum[i][j]=0.f; amax[i][j]=-INFINITY; }

  for (int kt = 0; kt < 256; kt += 16) {
    if (var == 0) {
      int ka = tid & 15, ma = tid >> 4;
      #pragma unroll
      for (int q=0;q<4;q++)
        As[ka][ma+q*16] = A[(size_t)(mb+ma+q*16)*256 + kt+ka];
    } else {
      int ma = tid & 63, ka = tid >> 6;
      #pragma unroll
      for (int q=0;q<4;q++)
        As[ka+q*4][ma] = A[(size_t)(kt+ka+q*4)*256 + mb+ma];
    }
    {
      int nbi = tid & 63, kb = tid >> 6;
      #pragma unroll
      for (int q=0;q<4;q++)
        Bs[kb+q*4][nbi] = B[(size_t)(kt+kb+q*4)*512 + nb+nbi];
    }
    __syncthreads();
    #pragma unroll
    for (int k=0;k<16;k++){
      float a[4], bv[4];
      #pragma unroll
      for (int i=0;i<4;i++) a[i] = As[k][ty*4+i];
      #pragma unroll
      for (int j=0;j<4;j++) bv[j] = Bs[k][tx*4+j];
      #pragma unroll
      for (int i=0;i<4;i++)
        #pragma unroll
        for (int j=0;j<4;j++){
          float p = a[i]*bv[j];
          asum[i][j] += p;
          amax[i][j] = fmaxf(amax[i][j], p);
        }
    }
    __syncthreads();
  }
  #pragma unroll
  for (int i=0;i<4;i++){
    int m = mb + ty*4 + i;
    float ud = dsmall(U[m]);
    #pragma unroll
    for (int j=0;j<4;j++){
      int n = nb + tx*4 + j;
      C1[(size_t)m*256 + n] = asum[i][j] / ud;
      C2[(size_t)m*256 + n] = amax[i][j];
    }
  }
}

// ---------------------------------------------------------------------------
// Pairwise mp-match with fused row/col max reduction (never materializes MM).
// grid (4,4,40), z=b*10+l.
// ---------------------------------------------------------------------------
__global__ __launch_bounds__(256) void k_pmm(
    const float* __restrict__ A0, const float* __restrict__ B0,
    const float* __restrict__ W0, const float* __restrict__ U0,
    const float* __restrict__ V0,
    float* __restrict__ PARTR, float* __restrict__ PARTC)
{
  const int z = blockIdx.z;
  const int bq = z / 10, l = z % 10;
  const float* A = A0 + (size_t)bq*131072;
  const float* B = B0 + (size_t)bq*131072;
  const float* Wv = W0 + l*256;
  const float* U = U0 + bq*2560 + l*256;
  const float* V = V0 + bq*2560 + l*256;

  __shared__ float As[16][68];
  __shared__ float Bs[16][68];
  const int mb = blockIdx.y*64, nb = blockIdx.x*64;
  const int tid = threadIdx.x;
  const int tx = tid & 15, ty = tid >> 4;

  float acc[4][4];
  #pragma unroll
  for (int i=0;i<4;i++)
    #pragma unroll
    for (int j=0;j<4;j++) acc[i][j] = 0.f;

  for (int kt = 0; kt < 256; kt += 16) {
    int ka = tid & 15, ma = tid >> 4;
    float w = Wv[kt+ka]; float w2 = w*w;
    #pragma unroll
    for (int q=0;q<4;q++){
      As[ka][ma+q*16] = A[(size_t)(mb+ma+q*16)*512 + kt+ka] * w2;
      Bs[ka][ma+q*16] = B[(size_t)(nb+ma+q*16)*512 + kt+ka];
    }
    __syncthreads();
    #pragma unroll
    for (int k=0;k<16;k++){
      float a[4], bv[4];
      #pragma unroll
      for (int i=0;i<4;i++) a[i] = As[k][ty*4+i];
      #pragma unroll
      for (int j=0;j<4;j++) bv[j] = Bs[k][tx*4+j];
      #pragma unroll
      for (int i=0;i<4;i++)
        #pragma unroll
        for (int j=0;j<4;j++) acc[i][j] += a[i]*bv[j];
    }
    __syncthreads();
  }
  float um[4], vn[4];
  #pragma unroll
  for (int i=0;i<4;i++) um[i] = U[mb + ty*4 + i];
  #pragma unroll
  for (int j=0;j<4;j++) vn[j] = V[nb + tx*4 + j];
  float c[4][4];
  #pragma unroll
  for (int i=0;i<4;i++)
    #pragma unroll
    for (int j=0;j<4;j++) c[i][j] = acc[i][j] / dsmall(um[i]*vn[j]);

  float rm[4];
  #pragma unroll
  for (int i=0;i<4;i++){
    rm[i] = fmaxf(fmaxf(c[i][0], c[i][1]), fmaxf(c[i][2], c[i][3]));
    rm[i] = fmaxf(rm[i], __shfl_xor(rm[i], 1, 64));
    rm[i] = fmaxf(rm[i], __shfl_xor(rm[i], 2, 64));
    rm[i] = fmaxf(rm[i], __shfl_xor(rm[i], 4, 64));
    rm[i] = fmaxf(rm[i], __shfl_xor(rm[i], 8, 64));
  }
  if ((tid & 15) == 0){
    #pragma unroll
    for (int i=0;i<4;i++)
      PARTR[((size_t)z*4 + blockIdx.x)*256 + mb + ty*4 + i] = rm[i];
  }
  __syncthreads();
  float* colp = &As[0][0];
  #pragma unroll
  for (int j=0;j<4;j++)
    colp[ty*64 + tx*4 + j] = fmaxf(fmaxf(c[0][j], c[1][j]), fmaxf(c[2][j], c[3][j]));
  __syncthreads();
  if (tid < 64){
    float m = colp[tid];
    #pragma unroll
    for (int r=1;r<16;r++) m = fmaxf(m, colp[r*64 + tid]);
    PARTC[((size_t)z*4 + blockIdx.y)*256 + nb + tid] = m;
  }
}

__global__ void k_pcomb(const float* __restrict__ PARTR, const float* __restrict__ PARTC,
                        float* __restrict__ MMRo, float* __restrict__ MMCo){
  int z = blockIdx.x, i = threadIdx.x;
  size_t b0 = (size_t)z*4*256 + i;
  float r = fmaxf(fmaxf(PARTR[b0], PARTR[b0+256]), fmaxf(PARTR[b0+512], PARTR[b0+768]));
  float c = fmaxf(fmaxf(PARTC[b0], PARTC[b0+256]), fmaxf(PARTC[b0+512], PARTC[b0+768]));
  MMRo[(size_t)z*256 + i] = r;
  MMCo[(size_t)z*256 + i] = c;
}

// ---------------------------------------------------------------------------
// LSTM scan (R8-proven config): 8 WGs/dir, LDS weights, per-half-wave
// exchange, RELAXED WG-flag posted after B2, s_sleep poll backoff.
// ---------------------------------------------------------------------------
__global__ __launch_bounds__(256, 1) void k_scan8(
    const float* __restrict__ PREf, const float* __restrict__ PREb,
    const float* __restrict__ WTf, const float* __restrict__ WTb,
    float* __restrict__ Hbuf, int* __restrict__ flg,
    float* __restrict__ HSo, float* __restrict__ HTo)
{
  const int xcd = blockIdx.x & 7;
  if (xcd > 1) return;
  const int d  = xcd;
  const int wg = blockIdx.x >> 3;
  const float* PRE = d ? PREb : PREf;
  const float* WT  = d ? WTb  : WTf;
  float* Hb = Hbuf + (size_t)d*2*2048;
  int* fl = flg + d*8*32;

  __shared__ float Wl[256][128];     // 128 KB
  __shared__ float hl[256][8];       // 8 KB
  __shared__ float red[4][32][40];   // 20 KB

  const int tid = threadIdx.x;
  const int kc = tid >> 5;
  const int gq = tid & 31;
  const int as = tid >> 5;
  const int aj = tid & 31;

  for (int e = tid; e < 256*128; e += 256) {
    int k = e >> 7, c = e & 127;
    Wl[k][c] = WT[(size_t)k*1024 + (c>>5)*256 + wg*32 + (c&31)];
  }
  for (int e = tid; e < 2048; e += 256) ((float*)hl)[e] = 0.f;
  float cst = 0.f;
  __syncthreads();

  for (int tt = 0; tt < 256; ++tt) {
    const int t = d ? 255 - tt : tt;
    const int wp = tt & 1;
    const int sp = (tt + 1) & 1;

    const size_t pbase = ((size_t)(as*256 + t))*1024 + wg*32 + aj;
    const float pre0 = PRE[pbase];       const float pre1 = PRE[pbase + 256];
    const float pre2 = PRE[pbase + 512]; const float pre3 = PRE[pbase + 768];

    if (tt > 0 && kc != wg) {
      const int* flp = &fl[kc*32];
      while (__hip_atomic_load(flp, __ATOMIC_RELAXED, __HIP_MEMORY_SCOPE_AGENT) < tt)
        __builtin_amdgcn_s_sleep(1);
      const unsigned long long* srcu =
          (const unsigned long long*)&Hb[sp*2048 + kc*256 + gq*8];
      unsigned long long u0 = __hip_atomic_load(srcu+0, __ATOMIC_RELAXED, __HIP_MEMORY_SCOPE_AGENT);
      unsigned long long u1 = __hip_atomic_load(srcu+1, __ATOMIC_RELAXED, __HIP_MEMORY_SCOPE_AGENT);
      unsigned long long u2 = __hip_atomic_load(srcu+2, __ATOMIC_RELAXED, __HIP_MEMORY_SCOPE_AGENT);
      unsigned long long u3 = __hip_atomic_load(srcu+3, __ATOMIC_RELAXED, __HIP_MEMORY_SCOPE_AGENT);
      unsigned long long* dst = (unsigned long long*)&((float*)hl)[kc*256 + gq*8];
      dst[0] = u0; dst[1] = u1; dst[2] = u2; dst[3] = u3;
    }

    float acc[8][4];
    #pragma unroll
    for (int s=0;s<8;s++){ acc[s][0]=0.f; acc[s][1]=0.f; acc[s][2]=0.f; acc[s][3]=0.f; }
    #pragma unroll 8
    for (int kk = 0; kk < 32; ++kk) {
      const int k = kc*32 + kk;
      float4 w  = *(const float4*)&Wl[k][gq*4];
      float4 ha = *(const float4*)&hl[k][0];
      float4 hb = *(const float4*)&hl[k][4];
      acc[0][0] += ha.x*w.x; acc[0][1] += ha.x*w.y; acc[0][2] += ha.x*w.z; acc[0][3] += ha.x*w.w;
      acc[1][0] += ha.y*w.x; acc[1][1] += ha.y*w.y; acc[1][2] += ha.y*w.z; acc[1][3] += ha.y*w.w;
      acc[2][0] += ha.z*w.x; acc[2][1] += ha.z*w.y; acc[2][2] += ha.z*w.z; acc[2][3] += ha.z*w.w;
      acc[3][0] += ha.w*w.x; acc[3][1] += ha.w*w.y; acc[3][2] += ha.w*w.z; acc[3][3] += ha.w*w.w;
      acc[4][0] += hb.x*w.x; acc[4][1] += hb.x*w.y; acc[4][2] += hb.x*w.z; acc[4][3] += hb.x*w.w;
      acc[5][0] += hb.y*w.x; acc[5][1] += hb.y*w.y; acc[5][2] += hb.y*w.z; acc[5][3] += hb.y*w.w;
      acc[6][0] += hb.z*w.x; acc[6][1] += hb.z*w.y; acc[6][2] += hb.z*w.z; acc[6][3] += hb.z*w.w;
      acc[7][0] += hb.w*w.x; acc[7][1] += hb.w*w.y; acc[7][2] += hb.w*w.z; acc[7][3] += hb.w*w.w;
    }
    #pragma unroll
    for (int s=0;s<8;s++)
      #pragma unroll
      for (int c2=0;c2<4;c2++)
        acc[s][c2] += __shfl_xor(acc[s][c2], 32, 64);
    if ((tid & 32) == 0) {
      const int kp = kc >> 1;
      #pragma unroll
      for (int s=0;s<8;s++)
        #pragma unroll
        for (int c2=0;c2<4;c2++)
          red[kp][s*4+c2][gq] = acc[s][c2];
    }
    __syncthreads();   // B1

    float hreg;
    {
      float g[4];
      #pragma unroll
      for (int gt=0; gt<4; ++gt) {
        const int c = gt*32 + aj;
        const int gqq = c >> 2, cc = c & 3;
        const int ii = as*4 + cc;
        g[gt] = red[0][ii][gqq] + red[1][ii][gqq] + red[2][ii][gqq] + red[3][ii][gqq];
      }
      g[0] += pre0; g[1] += pre1; g[2] += pre2; g[3] += pre3;
      const float ig = sigf(g[0]), fg = sigf(g[1]), gg = tanhf(g[2]), og = sigf(g[3]);
      cst = fg*cst + ig*gg;
      hreg = og*tanhf(cst);
      hl[wg*32 + aj][as] = hreg;
      __hip_atomic_store(&Hb[wp*2048 + (wg*32 + aj)*8 + as], hreg,
                         __ATOMIC_RELAXED, __HIP_MEMORY_SCOPE_AGENT);
    }
    __syncthreads();   // B2: drains Hb stores (vmcnt(0)) + hl ds_writes

    if (tid == 0)
      __hip_atomic_store(&fl[wg*32], tt+1, __ATOMIC_RELAXED, __HIP_MEMORY_SCOPE_AGENT);

    if (HSo) HSo[((size_t)(as*256 + t))*512 + d*256 + wg*32 + aj] = hreg;
    if (HTo && tt == 255) HTo[((size_t)(as*2 + d))*256 + wg*32 + aj] = hreg;
  }
}

// ---------------------------------------------------------------------------
// Row L2 norms of the 4096 (seq,dir,i) hidden rows.
// ---------------------------------------------------------------------------
__global__ __launch_bounds__(256) void k_rownorm(const float* __restrict__ HS_,
                                                 float* __restrict__ NORM_){
  int r = blockIdx.x*4 + (threadIdx.x >> 6);
  int lane = threadIdx.x & 63;
  int seq = r >> 9, d = (r >> 8) & 1, i = r & 255;
  const float* row = HS_ + ((size_t)(seq*256 + i))*512 + d*256;
  float s = 0.f;
  #pragma unroll
  for (int q=0;q<4;q++){ float v = row[lane + 64*q]; s += v*v; }
  for (int off=32; off; off>>=1) s += __shfl_xor(s, off, 64);
  if (lane == 0) NORM_[r] = sqrtf(s);
}

// ---------------------------------------------------------------------------
// Row sum+max reduction
// ---------------------------------------------------------------------------
__global__ __launch_bounds__(256) void k_rowred(const float* __restrict__ in,
                                                float* __restrict__ osum,
                                                float* __restrict__ omax, int cols){
  int r = blockIdx.x*4 + (threadIdx.x >> 6);
  int lane = threadIdx.x & 63;
  const float* row = in + (size_t)r*cols;
  float s = 0.f, m = -INFINITY;
  for (int cidx=lane; cidx<cols; cidx+=64){ float v=row[cidx]; s += v; m = fmaxf(m,v); }
  for (int off=32; off; off>>=1){ s += __shfl_xor(s,off,64); m = fmaxf(m, __shfl_xor(m,off,64)); }
  if (lane == 0){ if (osum) osum[r] = s; if (omax) omax[r] = m; }
}

__global__ __launch_bounds__(256) void k_colred(const float* __restrict__ in0, long long zstride,
                                                int nrows, int ld,
                                                float* __restrict__ osum, float* __restrict__ omax){
  const float* in = in0 + (size_t)blockIdx.z*zstride;
  int j = threadIdx.x;
  float s = 0.f, m = -INFINITY;
  for (int r=0;r<nrows;r++){ float v = in[(size_t)r*ld + j]; s += v; m = fmaxf(m,v); }
  if (osum) osum[blockIdx.z*256 + j] = s;
  if (omax) omax[blockIdx.z*256 + j] = m;
}

// ---------------------------------------------------------------------------
// Weighted norms for pairwise matching: out[side][d][b][l][i]
// ---------------------------------------------------------------------------
__global__ __launch_bounds__(256) void k_wnorm(const float* __restrict__ HS_,
                                               const float* __restrict__ w3, const float* __restrict__ w4,
                                               float* __restrict__ WN1_, float* __restrict__ WN2_){
  int rid = blockIdx.x*4 + (threadIdx.x >> 6);
  int lane = threadIdx.x & 63;
  int side = rid / 20480; int rem = rid % 20480;
  int d = rem / 10240; int rem2 = rem % 10240;
  int b = rem2 / 2560; int l = (rem2 / 256) % 10; int i = rem2 & 255;
  int seq = side ? 4+b : b;
  const float* row = HS_ + ((size_t)(seq*256 + i))*512 + d*256;
  const float* w = (d ? w4 : w3) + l*256;
  float s = 0.f;
  #pragma unroll
  for (int q=0;q<4;q++){ float wv = w[lane+64*q]; float v = row[lane+64*q]; s += wv*wv*v*v; }
  for (int off=32; off; off>>=1) s += __shfl_xor(s, off, 64);
  if (lane == 0) (side ? WN2_ : WN1_)[rem] = sqrtf(s);
}

// ---------------------------------------------------------------------------
// Assemble mv rows (62 channels).
// ---------------------------------------------------------------------------
__global__ __launch_bounds__(256) void k_mv(
    const float* __restrict__ HS_, const float* __restrict__ MEANH_, const float* __restrict__ MEANP_,
    const float* __restrict__ XH_, const float* __restrict__ XP_,
    const float* __restrict__ RS_, const float* __restrict__ RMAX_,
    const float* __restrict__ CS_, const float* __restrict__ CMAX_,
    const float* __restrict__ MMR_, const float* __restrict__ MMC_,
    const float* __restrict__ w5, const float* __restrict__ w6,
    const float* __restrict__ w7, const float* __restrict__ w8,
    float* __restrict__ MV_)
{
  const int blk = blockIdx.x;
  const int side = blk >> 10, b = (blk >> 8) & 3, i = blk & 255;
  const int wv = threadIdx.x >> 6, lane = threadIdx.x & 63;
  float* mvrow = MV_ + (size_t)blk*62;

  if (threadIdx.x == 0){
    const float* rmax = side ? CMAX_ : RMAX_;
    const float* rsum = side ? CS_   : RS_;
    mvrow[0] = rmax[b*256 + i];
    mvrow[1] = rsum[b*256 + i] * (1.f/256.f);
  }
  if (threadIdx.x < 20){
    int dd = threadIdx.x / 10, l = threadIdx.x % 10;
    const float* mm = side ? MMC_ : MMR_;
    mvrow[2 + dd*10 + l] = mm[dd*10240 + (b*10 + l)*256 + i];
  }
  const int d = wv & 1;
  const int seq = side ? 4+b : b;
  const float* arow = HS_ + ((size_t)(seq*256 + i))*512 + d*256;
  const float* Mside = side ? MEANP_ : MEANH_;
  const float* Xside = side ? XP_ : XH_;
  const float* brow = (wv < 2 ? Mside : Xside) + (size_t)d*262144 + (size_t)b*65536 + (size_t)i*256;
  const float* wp = (wv==0) ? w5 : (wv==1) ? w6 : (wv==2) ? w7 : w8;

  float av[4], bv[4];
  #pragma unroll
  for (int q=0;q<4;q++){ av[q] = arow[lane+64*q]; bv[q] = brow[lane+64*q]; }
  for (int l=0;l<10;l++){
    const float* wrow = wp + l*256;
    float s1=0.f, s2=0.f, s3=0.f;
    #pragma unroll
    for (int q=0;q<4;q++){
      float w = wrow[lane+64*q]; float w2v = w*w;
      s1 += w2v*av[q]*bv[q]; s2 += w2v*av[q]*av[q]; s3 += w2v*bv[q]*bv[q];
    }
    for (int off=32; off; off>>=1){
      s1 += __shfl_xor(s1,off,64); s2 += __shfl_xor(s2,off,64); s3 += __shfl_xor(s3,off,64);
    }
    if (lane == 0) mvrow[22 + wv*10 + l] = s1 / fmaxf(sqrtf(s2)*sqrtf(s3), EPSV);
  }
}

// ---------------------------------------------------------------------------
// Mean over time of left/right: XM[b][side*300+d]
// ---------------------------------------------------------------------------
__global__ void k_means(const float* __restrict__ L, const float* __restrict__ R,
                        float* __restrict__ XM){
  int b = blockIdx.x & 3, sideR = blockIdx.x >> 2;
  const float* src = sideR ? R : L;
  int dch = threadIdx.x;
  if (dch >= 300) return;
  float s = 0.f;
  for (int t=0;t<256;t++) s += src[((size_t)(b*256 + t))*300 + dch];
  XM[b*600 + sideR*300 + dch] = s*(1.f/256.f);
}

// ---------------------------------------------------------------------------
// Head: fc1 (tanh), fc2
// ---------------------------------------------------------------------------
__global__ __launch_bounds__(512) void k_fc1(const float* __restrict__ HT_,
                                             const float* __restrict__ XM,
                                             const float* __restrict__ W1T,
                                             const float* __restrict__ b1,
                                             float* __restrict__ X2){
  __shared__ float x[1626];
  int b = blockIdx.x, t = threadIdx.x;
  if (t < 256){
    x[t]       = HT_[(b*2+0)*256 + t];
    x[256+t]   = HT_[(b*2+1)*256 + t];
    x[512+t]   = HT_[((4+b)*2+0)*256 + t];
    x[768+t]   = HT_[((4+b)*2+1)*256 + t];
  }
  if (t == 0){ x[1024] = 0.5f; x[1025] = 0.5f; }
  if (t < 300){ x[1026+t] = XM[b*600 + t]; x[1326+t] = XM[b*600 + 300 + t]; }
  __syncthreads();
  float acc = b1[t];
  for (int k=0;k<1626;k++) acc += x[k]*W1T[(size_t)k*512 + t];
  X2[b*512 + t] = tanhf(acc);
}

__global__ void k_fc2(const float* __restrict__ X2, const float* __restrict__ W2,
                      const float* __restrict__ b2, float* __restrict__ out){
  int b = blockIdx.x, o = threadIdx.x;
  if (o >= 22) return;
  float acc = b2[o];
  const float* xr = X2 + b*512;
  const float* wr = W2 + (size_t)o*512;
  for (int k=0;k<512;k++) acc += xr[k]*wr[k];
  out[b*22 + o] = acc;
}

// ---------------------------------------------------------------------------
extern "C" void kernel_launch(void* const* d_in, const int* in_sizes, int n_in,
                              void* d_out, int out_size, void* d_ws, size_t ws_size,
                              hipStream_t stream) {
  const float* left  = (const float*)d_in[0];
  const float* right = (const float*)d_in[1];
  const float* cWihF = (const float*)d_in[2];
  const float* cWhhF = (const float*)d_in[3];
  const float* cbF   = (const float*)d_in[4];
  const float* cWihB = (const float*)d_in[5];
  const float* cWhhB = (const float*)d_in[6];
  const float* cbB   = (const float*)d_in[7];
  const float* aWihF = (const float*)d_in[8];
  const float* aWhhF = (const float*)d_in[9];
  const float* abF   = (const float*)d_in[10];
  const float* aWihB = (const float*)d_in[11];
  const float* aWhhB = (const float*)d_in[12];
  const float* abB   = (const float*)d_in[13];
  const float* w3 = (const float*)d_in[14];
  const float* w4 = (const float*)d_in[15];
  const float* w5 = (const float*)d_in[16];
  const float* w6 = (const float*)d_in[17];
  const float* w7 = (const float*)d_in[18];
  const float* w8 = (const float*)d_in[19];
  const float* fc1W = (const float*)d_in[20];
  const float* fc1b = (const float*)d_in[21];
  const float* fc2W = (const float*)d_in[22];
  const float* fc2b = (const float*)d_in[23];
  float* out = (float*)d_out;
  float* ws = (float*)d_ws;

  // workspace layout (floats)
  float* WT    = ws;                 // 4 * 262144
  float* PREf  = ws + 1048576;       // 2097152
  float* PREb  = ws + 3145728;       // 2097152
  float* HS    = ws + 5242880;       // 1048576  (8,256,512)
  float* NORM  = ws + 6291456;       // 4096
  float* ATT   = ws + 6295552;       // 524288
  float* RS    = ws + 6819840;       // 2048
  float* RMAX  = ws + 6821888;       // 2048
  float* CS    = ws + 6823936;       // 2048
  float* CMAX  = ws + 6825984;       // 2048
  float* MEANH = ws + 6828032;       // 524288
  float* MEANP = ws + 7352320;       // 524288
  float* XH    = ws + 7876608;       // 524288
  float* XP    = ws + 8400896;       // 524288
  float* WN1   = ws + 8925184;       // 20480
  float* WN2   = ws + 8945664;       // 20480
  float* MM    = ws + 8966144;       // 2621440 scratch (HXB/FLG, copies, PART)
  float* MMR   = ws + 11587584;      // 20480
  float* MMC   = ws + 11608064;      // 20480
  float* MV    = ws + 11628544;      // 126976
  float* HT    = ws + 11755520;      // 4096
  float* XM    = ws + 11759616;      // 2400
  float* X2    = ws + 11762016;      // 2048
  float* W1T   = ws + 11764064;      // 832512

  // MM-region overlays (time-multiplexed):
  float* HXB  = MM;                   // scans: 8192 floats
  int*   FLG  = (int*)(MM + 8192);    // scans: 512 ints
  float* XCAT = MM;                   // ctx proj staging: 614400
  float* WCAT = MM + 614400;          // 614400
  float* BCAT = MM + 1228800;         // 2048
  float* PARTR= MM;                   // pairwise partials: 40960
  float* PARTC= MM + 40960;           // 40960
  float* AGGW = MM + 1048576;         // agg proj staging: 126976
  float* AGGB = MM + 1175552;         // 2048

  // 1. transposes
  k_transpose<<<dim3(8,32),  dim3(32,32), 0, stream>>>(cWhhF, WT + 0,      1024, 256);
  k_transpose<<<dim3(8,32),  dim3(32,32), 0, stream>>>(cWhhB, WT + 262144, 1024, 256);
  k_transpose<<<dim3(8,32),  dim3(32,32), 0, stream>>>(aWhhF, WT + 524288, 1024, 256);
  k_transpose<<<dim3(8,32),  dim3(32,32), 0, stream>>>(aWhhB, WT + 786432, 1024, 256);
  k_transpose<<<dim3(51,16), dim3(32,32), 0, stream>>>(fc1W, W1T, 512, 1626);

  // 2. ctx input projections, batched z=4 (zo=side, zi=wdir)
  hipMemcpyAsync(XCAT,          left,  307200*4, hipMemcpyDeviceToDevice, stream);
  hipMemcpyAsync(XCAT + 307200, right, 307200*4, hipMemcpyDeviceToDevice, stream);
  hipMemcpyAsync(WCAT,          cWihF, 307200*4, hipMemcpyDeviceToDevice, stream);
  hipMemcpyAsync(WCAT + 307200, cWihB, 307200*4, hipMemcpyDeviceToDevice, stream);
  hipMemcpyAsync(BCAT,          cbF,   1024*4,   hipMemcpyDeviceToDevice, stream);
  hipMemcpyAsync(BCAT + 1024,   cbB,   1024*4,   hipMemcpyDeviceToDevice, stream);
  k_gemm<0><<<dim3(16,16,4),256,0,stream>>>(XCAT,300, 307200,0,  WCAT,300, 0,307200,
      PREf,1024, 1048576,2097152,  nullptr,0,0, nullptr,0,0, nullptr,0,0,
      BCAT, 1024, 1024,1024,300, 2);

  // 3. ctx scan
  hipMemsetAsync(FLG, 0, 512*sizeof(int), stream);
  k_scan8<<<64,256,0,stream>>>(PREf, PREb, WT, WT+262144, HXB, FLG, HS, nullptr);

  // 4. row norms
  k_rownorm<<<1024,256,0,stream>>>(HS, NORM);

  // 5. att (cosine matrix), z = d*4+b
  k_gemm<1><<<dim3(4,4,8),256,0,stream>>>(HS,512,256,131072,  HS+524288,512,256,131072,
      ATT,256,262144,65536,  nullptr,0,0,  NORM,256,512,  NORM+2048,256,512,
      nullptr,0, 256,256,256, 4);

  // 6-7. att reductions
  k_rowred<<<512,256,0,stream>>>(ATT, RS, RMAX, 256);
  k_colred<<<dim3(1,1,8),256,0,stream>>>(ATT, 65536, 256, 256, CS, CMAX);

  // 8. attentive means and maxes (fused, one launch)
  k_attstat<<<dim3(4,4,16),256,0,stream>>>(ATT, HS, RS, CS, MEANH, XH, MEANP, XP);

  // 9. weighted norms
  k_wnorm<<<10240,256,0,stream>>>(HS, w3, w4, WN1, WN2);

  // 10-13. pairwise mm with fused max-reductions (MM never materialized)
  k_pmm<<<dim3(4,4,40),256,0,stream>>>(HS, HS+524288, w3, WN1, WN2, PARTR, PARTC);
  k_pcomb<<<40,256,0,stream>>>(PARTR, PARTC, MMR, MMC);
  k_pmm<<<dim3(4,4,40),256,0,stream>>>(HS+256, HS+524288+256, w4, WN1+10240, WN2+10240, PARTR, PARTC);
  k_pcomb<<<40,256,0,stream>>>(PARTR, PARTC, MMR+10240, MMC+10240);

  // 14. assemble mv (2048 rows x 62)
  k_mv<<<2048,256,0,stream>>>(HS, MEANH, MEANP, XH, XP, RS, RMAX, CS, CMAX,
                              MMR, MMC, w5, w6, w7, w8, MV);

  // 15. agg projections, batched z=2 (zi=wdir)
  hipMemcpyAsync(AGGW,         aWihF, 63488*4, hipMemcpyDeviceToDevice, stream);
  hipMemcpyAsync(AGGW + 63488, aWihB, 63488*4, hipMemcpyDeviceToDevice, stream);
  hipMemcpyAsync(AGGB,         abF,   1024*4,  hipMemcpyDeviceToDevice, stream);
  hipMemcpyAsync(AGGB + 1024,  abB,   1024*4,  hipMemcpyDeviceToDevice, stream);
  k_gemm<0><<<dim3(16,32,2),256,0,stream>>>(MV,62, 0,0,  AGGW,62, 0,63488,
      PREf,1024, 0,2097152,  nullptr,0,0, nullptr,0,0, nullptr,0,0,
      AGGB, 1024, 2048,1024,62, 2);

  // 16. agg scan (keep only final h)
  hipMemsetAsync(FLG, 0, 512*sizeof(int), stream);
  k_scan8<<<64,256,0,stream>>>(PREf, PREb, WT+524288, WT+786432, HXB, FLG, nullptr, HT);

  // 17-19. head
  k_means<<<8,320,0,stream>>>(left, right, XM);
  k_fc1<<<4,512,0,stream>>>(HT, XM, W1T, fc1b, X2);
  k_fc2<<<4,64,0,stream>>>(X2, fc2W, fc2b, out);
}

// Round 11
// 2192.736 us; speedup vs baseline: 1.7781x; 1.1080x over previous
//
#include <hip/hip_runtime.h>
#include <hip/hip_bf16.h>
#include <math.h>

#define EPSV 1e-8f

__device__ __forceinline__ float dsmall(float d){ return d > EPSV ? d : EPSV; }
__device__ __forceinline__ float sigf(float x){ return 1.f/(1.f+expf(-x)); }

// ---------------------------------------------------------------------------
// Transpose ctx Whh (z selects F/B): W (1024x256) -> WT (256x1024)
// ---------------------------------------------------------------------------
__global__ __launch_bounds__(1024) void k_transpose2(const float* __restrict__ WF,
                                                     const float* __restrict__ WB,
                                                     float* __restrict__ WT0,
                                                     float* __restrict__ WT1){
  const float* W = blockIdx.z ? WB : WF;
  float* WT = blockIdx.z ? WT1 : WT0;
  __shared__ float t[32][33];
  int rb = blockIdx.y*32, cb = blockIdx.x*32;
  int r = rb + threadIdx.y, c = cb + threadIdx.x;
  t[threadIdx.y][threadIdx.x] = W[(size_t)r*256 + c];
  __syncthreads();
  int rr = cb + threadIdx.y, cc = rb + threadIdx.x;
  WT[(size_t)rr*1024 + cc] = t[threadIdx.x][threadIdx.y];
}

// ---------------------------------------------------------------------------
// ctx projections: z in 0..3 (zo=z>>1: left/right; zi=z&1: F/B dir)
// C = X(1024x300) @ Wih(1024x300)^T + b  -> PRE[dir] + zo*1048576
// ---------------------------------------------------------------------------
__global__ __launch_bounds__(256) void k_proj(
    const float* __restrict__ left, const float* __restrict__ right,
    const float* __restrict__ WihF, const float* __restrict__ WihB,
    const float* __restrict__ bF, const float* __restrict__ bB,
    float* __restrict__ PREf, float* __restrict__ PREb)
{
  const int z = blockIdx.z, zo = z >> 1, zi = z & 1;
  const float* A = zo ? right : left;
  const float* B = zi ? WihB : WihF;
  const float* bias = zi ? bB : bF;
  float* C = (zi ? PREb : PREf) + (size_t)zo*1048576;
  const int M = 1024, N = 1024, K = 300;

  __shared__ float As[16][68];
  __shared__ float Bs[16][68];
  const int mb = blockIdx.y*64, nb = blockIdx.x*64;
  const int tid = threadIdx.x;
  const int tx = tid & 15, ty = tid >> 4;

  float acc[4][4];
  #pragma unroll
  for (int i=0;i<4;i++)
    #pragma unroll
    for (int j=0;j<4;j++) acc[i][j] = 0.f;

  for (int kt = 0; kt < K; kt += 16) {
    int ka = tid & 15, ma = tid >> 4;
    #pragma unroll
    for (int q=0;q<4;q++){
      int m = ma + q*16;
      float v = 0.f, bvv = 0.f;
      if (kt+ka < K){
        v = A[(size_t)(mb+m)*300 + kt+ka];
        bvv = B[(size_t)(nb+m)*300 + kt+ka];
      }
      As[ka][m] = v; Bs[ka][m] = bvv;
    }
    __syncthreads();
    #pragma unroll
    for (int k=0;k<16;k++){
      float a[4], bv[4];
      #pragma unroll
      for (int i=0;i<4;i++) a[i] = As[k][ty*4+i];
      #pragma unroll
      for (int j=0;j<4;j++) bv[j] = Bs[k][tx*4+j];
      #pragma unroll
      for (int i=0;i<4;i++)
        #pragma unroll
        for (int j=0;j<4;j++) acc[i][j] += a[i]*bv[j];
    }
    __syncthreads();
  }
  #pragma unroll
  for (int i=0;i<4;i++){
    int m = mb + ty*4 + i;
    #pragma unroll
    for (int j=0;j<4;j++){
      int n = nb + tx*4 + j;
      C[(size_t)m*1024 + n] = acc[i][j] + bias[n];
    }
  }
}

// ---------------------------------------------------------------------------
// agg projections: z in 0..1 (F/B). C = MV(2048x62) @ aWih^T + b -> PRE[dir]
// ---------------------------------------------------------------------------
__global__ __launch_bounds__(256) void k_aggproj(
    const float* __restrict__ MV_,
    const float* __restrict__ WihF, const float* __restrict__ WihB,
    const float* __restrict__ bF, const float* __restrict__ bB,
    float* __restrict__ PREf, float* __restrict__ PREb)
{
  const int zi = blockIdx.z;
  const float* B = zi ? WihB : WihF;
  const float* bias = zi ? bB : bF;
  float* C = zi ? PREb : PREf;
  const int K = 62;

  __shared__ float As[16][68];
  __shared__ float Bs[16][68];
  const int mb = blockIdx.y*64, nb = blockIdx.x*64;
  const int tid = threadIdx.x;
  const int tx = tid & 15, ty = tid >> 4;

  float acc[4][4];
  #pragma unroll
  for (int i=0;i<4;i++)
    #pragma unroll
    for (int j=0;j<4;j++) acc[i][j] = 0.f;

  for (int kt = 0; kt < K; kt += 16) {
    int ka = tid & 15, ma = tid >> 4;
    #pragma unroll
    for (int q=0;q<4;q++){
      int m = ma + q*16;
      float v = 0.f, bvv = 0.f;
      if (kt+ka < K){
        v = MV_[(size_t)(mb+m)*62 + kt+ka];
        bvv = B[(size_t)(nb+m)*62 + kt+ka];
      }
      As[ka][m] = v; Bs[ka][m] = bvv;
    }
    __syncthreads();
    #pragma unroll
    for (int k=0;k<16;k++){
      float a[4], bv[4];
      #pragma unroll
      for (int i=0;i<4;i++) a[i] = As[k][ty*4+i];
      #pragma unroll
      for (int j=0;j<4;j++) bv[j] = Bs[k][tx*4+j];
      #pragma unroll
      for (int i=0;i<4;i++)
        #pragma unroll
        for (int j=0;j<4;j++) acc[i][j] += a[i]*bv[j];
    }
    __syncthreads();
  }
  #pragma unroll
  for (int i=0;i<4;i++){
    int m = mb + ty*4 + i;
    #pragma unroll
    for (int j=0;j<4;j++){
      int n = nb + tx*4 + j;
      C[(size_t)m*1024 + n] = acc[i][j] + bias[n];
    }
  }
}

// ---------------------------------------------------------------------------
// att cosine matrix (MODE1 gemm): C=A@B^T / dsmall(U[m]*V[n]), z = d*4+b
// ---------------------------------------------------------------------------
__global__ __launch_bounds__(256) void k_att(
    const float* __restrict__ HS_, const float* __restrict__ NORM_,
    float* __restrict__ ATT_)
{
  const int z = blockIdx.z;
  const int d = z >> 2, b = z & 3;
  const float* A = HS_ + d*256 + (size_t)b*131072;            // lda 512
  const float* B = HS_ + 524288 + d*256 + (size_t)b*131072;   // ldb 512
  const float* U = NORM_ + d*2048 + b*512;      // wait: NORM [(seq*2+d)*256+i]
  // NORM layout: r = seq*512 + d*256 + i. For seq=b (left): U[i]=NORM[b*512+d*256+i]
  const float* Uv = NORM_ + (size_t)b*512 + d*256;
  const float* Vv = NORM_ + (size_t)(4+b)*512 + d*256;
  float* C = ATT_ + (size_t)z*65536;

  __shared__ float As[16][68];
  __shared__ float Bs[16][68];
  const int mb = blockIdx.y*64, nb = blockIdx.x*64;
  const int tid = threadIdx.x;
  const int tx = tid & 15, ty = tid >> 4;

  float acc[4][4];
  #pragma unroll
  for (int i=0;i<4;i++)
    #pragma unroll
    for (int j=0;j<4;j++) acc[i][j] = 0.f;

  for (int kt = 0; kt < 256; kt += 16) {
    int ka = tid & 15, ma = tid >> 4;
    #pragma unroll
    for (int q=0;q<4;q++){
      int m = ma + q*16;
      As[ka][m] = A[(size_t)(mb+m)*512 + kt+ka];
      Bs[ka][m] = B[(size_t)(nb+m)*512 + kt+ka];
    }
    __syncthreads();
    #pragma unroll
    for (int k=0;k<16;k++){
      float a[4], bv[4];
      #pragma unroll
      for (int i=0;i<4;i++) a[i] = As[k][ty*4+i];
      #pragma unroll
      for (int j=0;j<4;j++) bv[j] = Bs[k][tx*4+j];
      #pragma unroll
      for (int i=0;i<4;i++)
        #pragma unroll
        for (int j=0;j<4;j++) acc[i][j] += a[i]*bv[j];
    }
    __syncthreads();
  }
  #pragma unroll
  for (int i=0;i<4;i++){
    int m = mb + ty*4 + i;
    float um = Uv[m];
    #pragma unroll
    for (int j=0;j<4;j++){
      int n = nb + tx*4 + j;
      C[(size_t)m*256 + n] = acc[i][j] / dsmall(um * Vv[n]);
    }
  }
}

// ---------------------------------------------------------------------------
// Fused attentive stats (unchanged from R9/R10)
// ---------------------------------------------------------------------------
__global__ __launch_bounds__(256) void k_attstat(
    const float* __restrict__ ATT_, const float* __restrict__ HS_,
    const float* __restrict__ RS_, const float* __restrict__ CS_,
    float* __restrict__ MEANH_, float* __restrict__ XH_,
    float* __restrict__ MEANP_, float* __restrict__ XP_)
{
  const int z16 = blockIdx.z;
  const int var = z16 >> 3;
  const int z = z16 & 7;
  const int d = z >> 2, b = z & 3;
  const float* A = ATT_ + (size_t)z*65536;
  const float* B = (var ? HS_ : HS_ + 524288) + d*256 + (size_t)b*131072;
  const float* U = (var ? CS_ : RS_) + z*256;
  float* C1 = (var ? MEANP_ : MEANH_) + (size_t)z*65536;
  float* C2 = (var ? XP_    : XH_   ) + (size_t)z*65536;

  __shared__ float As[16][68];
  __shared__ float Bs[16][68];
  const int mb = blockIdx.y*64, nb = blockIdx.x*64;
  const int tid = threadIdx.x;
  const int tx = tid & 15, ty = tid >> 4;

  float asum[4][4], amax[4][4];
  #pragma unroll
  for (int i=0;i<4;i++)
    #pragma unroll
    for (int j=0;j<4;j++){ asum[i][j]=0.f; amax[i][j]=-INFINITY; }

  for (int kt = 0; kt < 256; kt += 16) {
    if (var == 0) {
      int ka = tid & 15, ma = tid >> 4;
      #pragma unroll
      for (int q=0;q<4;q++)
        As[ka][ma+q*16] = A[(size_t)(mb+ma+q*16)*256 + kt+ka];
    } else {
      int ma = tid & 63, ka = tid >> 6;
      #pragma unroll
      for (int q=0;q<4;q++)
        As[ka+q*4][ma] = A[(size_t)(kt+ka+q*4)*256 + mb+ma];
    }
    {
      int nbi = tid & 63, kb = tid >> 6;
      #pragma unroll
      for (int q=0;q<4;q++)
        Bs[kb+q*4][nbi] = B[(size_t)(kt+kb+q*4)*512 + nb+nbi];
    }
    __syncthreads();
    #pragma unroll
    for (int k=0;k<16;k++){
      float a[4], bv[4];
      #pragma unroll
      for (int i=0;i<4;i++) a[i] = As[k][ty*4+i];
      #pragma unroll
      for (int j=0;j<4;j++) bv[j] = Bs[k][tx*4+j];
      #pragma unroll
      for (int i=0;i<4;i++)
        #pragma unroll
        for (int j=0;j<4;j++){
          float p = a[i]*bv[j];
          asum[i][j] += p;
          amax[i][j] = fmaxf(amax[i][j], p);
        }
    }
    __syncthreads();
  }
  #pragma unroll
  for (int i=0;i<4;i++){
    int m = mb + ty*4 + i;
    float ud = dsmall(U[m]);
    #pragma unroll
    for (int j=0;j<4;j++){
      int n = nb + tx*4 + j;
      C1[(size_t)m*256 + n] = asum[i][j] / ud;
      C2[(size_t)m*256 + n] = amax[i][j];
    }
  }
}

// ---------------------------------------------------------------------------
// Pairwise mp-match, fw+bw in one launch: z in 0..79 (dir = z>=40)
// ---------------------------------------------------------------------------
__global__ __launch_bounds__(256) void k_pmm2(
    const float* __restrict__ HS_,
    const float* __restrict__ w3, const float* __restrict__ w4,
    const float* __restrict__ WN1_, const float* __restrict__ WN2_,
    float* __restrict__ PARTR, float* __restrict__ PARTC)
{
  const int z = blockIdx.z;
  const int dir = z >= 40;
  const int zz = z - dir*40;
  const int bq = zz / 10, l = zz % 10;
  const float* A = HS_ + dir*256 + (size_t)bq*131072;
  const float* B = HS_ + 524288 + dir*256 + (size_t)bq*131072;
  const float* Wv = (dir ? w4 : w3) + l*256;
  const float* U = WN1_ + dir*10240 + bq*2560 + l*256;
  const float* V = WN2_ + dir*10240 + bq*2560 + l*256;

  __shared__ float As[16][68];
  __shared__ float Bs[16][68];
  const int mb = blockIdx.y*64, nb = blockIdx.x*64;
  const int tid = threadIdx.x;
  const int tx = tid & 15, ty = tid >> 4;

  float acc[4][4];
  #pragma unroll
  for (int i=0;i<4;i++)
    #pragma unroll
    for (int j=0;j<4;j++) acc[i][j] = 0.f;

  for (int kt = 0; kt < 256; kt += 16) {
    int ka = tid & 15, ma = tid >> 4;
    float w = Wv[kt+ka]; float w2 = w*w;
    #pragma unroll
    for (int q=0;q<4;q++){
      As[ka][ma+q*16] = A[(size_t)(mb+ma+q*16)*512 + kt+ka] * w2;
      Bs[ka][ma+q*16] = B[(size_t)(nb+ma+q*16)*512 + kt+ka];
    }
    __syncthreads();
    #pragma unroll
    for (int k=0;k<16;k++){
      float a[4], bv[4];
      #pragma unroll
      for (int i=0;i<4;i++) a[i] = As[k][ty*4+i];
      #pragma unroll
      for (int j=0;j<4;j++) bv[j] = Bs[k][tx*4+j];
      #pragma unroll
      for (int i=0;i<4;i++)
        #pragma unroll
        for (int j=0;j<4;j++) acc[i][j] += a[i]*bv[j];
    }
    __syncthreads();
  }
  float um[4], vn[4];
  #pragma unroll
  for (int i=0;i<4;i++) um[i] = U[mb + ty*4 + i];
  #pragma unroll
  for (int j=0;j<4;j++) vn[j] = V[nb + tx*4 + j];
  float c[4][4];
  #pragma unroll
  for (int i=0;i<4;i++)
    #pragma unroll
    for (int j=0;j<4;j++) c[i][j] = acc[i][j] / dsmall(um[i]*vn[j]);

  float rm[4];
  #pragma unroll
  for (int i=0;i<4;i++){
    rm[i] = fmaxf(fmaxf(c[i][0], c[i][1]), fmaxf(c[i][2], c[i][3]));
    rm[i] = fmaxf(rm[i], __shfl_xor(rm[i], 1, 64));
    rm[i] = fmaxf(rm[i], __shfl_xor(rm[i], 2, 64));
    rm[i] = fmaxf(rm[i], __shfl_xor(rm[i], 4, 64));
    rm[i] = fmaxf(rm[i], __shfl_xor(rm[i], 8, 64));
  }
  if ((tid & 15) == 0){
    #pragma unroll
    for (int i=0;i<4;i++)
      PARTR[((size_t)z*4 + blockIdx.x)*256 + mb + ty*4 + i] = rm[i];
  }
  __syncthreads();
  float* colp = &As[0][0];
  #pragma unroll
  for (int j=0;j<4;j++)
    colp[ty*64 + tx*4 + j] = fmaxf(fmaxf(c[0][j], c[1][j]), fmaxf(c[2][j], c[3][j]));
  __syncthreads();
  if (tid < 64){
    float m = colp[tid];
    #pragma unroll
    for (int r=1;r<16;r++) m = fmaxf(m, colp[r*64 + tid]);
    PARTC[((size_t)z*4 + blockIdx.y)*256 + nb + tid] = m;
  }
}

__global__ void k_pcomb(const float* __restrict__ PARTR, const float* __restrict__ PARTC,
                        float* __restrict__ MMRo, float* __restrict__ MMCo){
  int z = blockIdx.x, i = threadIdx.x;
  size_t b0 = (size_t)z*4*256 + i;
  float r = fmaxf(fmaxf(PARTR[b0], PARTR[b0+256]), fmaxf(PARTR[b0+512], PARTR[b0+768]));
  float c = fmaxf(fmaxf(PARTC[b0], PARTC[b0+256]), fmaxf(PARTC[b0+512], PARTC[b0+768]));
  MMRo[(size_t)z*256 + i] = r;
  MMCo[(size_t)z*256 + i] = c;
}

// ---------------------------------------------------------------------------
// LSTM scan (R8-proven) + aux work on idle blocks during ctx scan.
// Scan blocks: bx&7 in {0,1}. Aux blocks (bx&7>=2, do_aux): grid-stride over
// {W1T transpose tiles, agg-Whh transpose tiles, input means}.
// ---------------------------------------------------------------------------
__global__ __launch_bounds__(256, 1) void k_scanaux(
    const float* __restrict__ PREf, const float* __restrict__ PREb,
    const float* __restrict__ WTf, const float* __restrict__ WTb,
    float* __restrict__ Hbuf, int* __restrict__ flg,
    float* __restrict__ HSo, float* __restrict__ HTo,
    int do_aux,
    const float* __restrict__ fc1W, float* __restrict__ W1T,
    const float* __restrict__ aWhhF, float* __restrict__ WTaggF,
    const float* __restrict__ aWhhB, float* __restrict__ WTaggB,
    const float* __restrict__ left, const float* __restrict__ right,
    float* __restrict__ XM)
{
  __shared__ float Wl[256][128];     // 128 KB (aux reuses as 32x33 tile)
  __shared__ float hl[256][8];       // 8 KB
  __shared__ float red[4][32][40];   // 20 KB

  const int bx = blockIdx.x;
  const int tid = threadIdx.x;

  if ((bx & 7) >= 2) {
    if (!do_aux) return;
    float (*tl)[33] = (float(*)[33])Wl;
    const int aux = (bx >> 3)*6 + (bx & 7) - 2;   // 0..47
    for (int u = aux; u < 816 + 512 + 8; u += 48) {
      if (u < 816) {                // fc1W (512x1626) -> W1T (1626x512)
        int tI = u % 16, tJ = u / 16;
        int r0 = tI*32, c0 = tJ*32;
        for (int e = tid; e < 1024; e += 256) {
          int rr = e >> 5, cc = e & 31;
          int c = c0 + cc;
          tl[rr][cc] = (c < 1626) ? fc1W[(size_t)(r0+rr)*1626 + c] : 0.f;
        }
        __syncthreads();
        for (int e = tid; e < 1024; e += 256) {
          int cc = e >> 5, rr = e & 31;
          int c = c0 + cc;
          if (c < 1626) W1T[(size_t)c*512 + r0 + rr] = tl[rr][cc];
        }
        __syncthreads();
      } else if (u < 1328) {        // aWhh (1024x256) -> WTagg (256x1024)
        int u2 = u - 816;
        const float* S = (u2 >= 256) ? aWhhB : aWhhF;
        float* D = (u2 >= 256) ? WTaggB : WTaggF;
        int tile = u2 & 255;
        int r0 = (tile >> 3)*32, c0 = (tile & 7)*32;
        for (int e = tid; e < 1024; e += 256) {
          int rr = e >> 5, cc = e & 31;
          tl[rr][cc] = S[(size_t)(r0+rr)*256 + c0 + cc];
        }
        __syncthreads();
        for (int e = tid; e < 1024; e += 256) {
          int cc = e >> 5, rr = e & 31;
          D[(size_t)(c0+cc)*1024 + r0 + rr] = tl[rr][cc];
        }
        __syncthreads();
      } else {                      // means: m = u-1328: b, side
        int m = u - 1328;
        int b = m & 3, sideR = m >> 2;
        const float* src = sideR ? right : left;
        for (int ch = tid; ch < 300; ch += 256) {
          float s = 0.f;
          for (int t = 0; t < 256; t++) s += src[((size_t)(b*256+t))*300 + ch];
          XM[b*600 + sideR*300 + ch] = s * (1.f/256.f);
        }
      }
    }
    return;
  }

  // ----------------- scan path (R8 verbatim) -----------------
  const int d  = bx & 7;
  const int wg = bx >> 3;
  const float* PRE = d ? PREb : PREf;
  const float* WT  = d ? WTb  : WTf;
  float* Hb = Hbuf + (size_t)d*2*2048;
  int* fl = flg + d*8*32;

  const int kc = tid >> 5;
  const int gq = tid & 31;
  const int as = tid >> 5;
  const int aj = tid & 31;

  for (int e = tid; e < 256*128; e += 256) {
    int k = e >> 7, c = e & 127;
    Wl[k][c] = WT[(size_t)k*1024 + (c>>5)*256 + wg*32 + (c&31)];
  }
  for (int e = tid; e < 2048; e += 256) ((float*)hl)[e] = 0.f;
  float cst = 0.f;
  __syncthreads();

  for (int tt = 0; tt < 256; ++tt) {
    const int t = d ? 255 - tt : tt;
    const int wp = tt & 1;
    const int sp = (tt + 1) & 1;

    const size_t pbase = ((size_t)(as*256 + t))*1024 + wg*32 + aj;
    const float pre0 = PRE[pbase];       const float pre1 = PRE[pbase + 256];
    const float pre2 = PRE[pbase + 512]; const float pre3 = PRE[pbase + 768];

    if (tt > 0 && kc != wg) {
      const int* flp = &fl[kc*32];
      while (__hip_atomic_load(flp, __ATOMIC_RELAXED, __HIP_MEMORY_SCOPE_AGENT) < tt)
        __builtin_amdgcn_s_sleep(1);
      const unsigned long long* srcu =
          (const unsigned long long*)&Hb[sp*2048 + kc*256 + gq*8];
      unsigned long long u0 = __hip_atomic_load(srcu+0, __ATOMIC_RELAXED, __HIP_MEMORY_SCOPE_AGENT);
      unsigned long long u1 = __hip_atomic_load(srcu+1, __ATOMIC_RELAXED, __HIP_MEMORY_SCOPE_AGENT);
      unsigned long long u2 = __hip_atomic_load(srcu+2, __ATOMIC_RELAXED, __HIP_MEMORY_SCOPE_AGENT);
      unsigned long long u3 = __hip_atomic_load(srcu+3, __ATOMIC_RELAXED, __HIP_MEMORY_SCOPE_AGENT);
      unsigned long long* dst = (unsigned long long*)&((float*)hl)[kc*256 + gq*8];
      dst[0] = u0; dst[1] = u1; dst[2] = u2; dst[3] = u3;
    }

    float acc[8][4];
    #pragma unroll
    for (int s=0;s<8;s++){ acc[s][0]=0.f; acc[s][1]=0.f; acc[s][2]=0.f; acc[s][3]=0.f; }
    #pragma unroll 8
    for (int kk = 0; kk < 32; ++kk) {
      const int k = kc*32 + kk;
      float4 w  = *(const float4*)&Wl[k][gq*4];
      float4 ha = *(const float4*)&hl[k][0];
      float4 hb = *(const float4*)&hl[k][4];
      acc[0][0] += ha.x*w.x; acc[0][1] += ha.x*w.y; acc[0][2] += ha.x*w.z; acc[0][3] += ha.x*w.w;
      acc[1][0] += ha.y*w.x; acc[1][1] += ha.y*w.y; acc[1][2] += ha.y*w.z; acc[1][3] += ha.y*w.w;
      acc[2][0] += ha.z*w.x; acc[2][1] += ha.z*w.y; acc[2][2] += ha.z*w.z; acc[2][3] += ha.z*w.w;
      acc[3][0] += ha.w*w.x; acc[3][1] += ha.w*w.y; acc[3][2] += ha.w*w.z; acc[3][3] += ha.w*w.w;
      acc[4][0] += hb.x*w.x; acc[4][1] += hb.x*w.y; acc[4][2] += hb.x*w.z; acc[4][3] += hb.x*w.w;
      acc[5][0] += hb.y*w.x; acc[5][1] += hb.y*w.y; acc[5][2] += hb.y*w.z; acc[5][3] += hb.y*w.w;
      acc[6][0] += hb.z*w.x; acc[6][1] += hb.z*w.y; acc[6][2] += hb.z*w.z; acc[6][3] += hb.z*w.w;
      acc[7][0] += hb.w*w.x; acc[7][1] += hb.w*w.y; acc[7][2] += hb.w*w.z; acc[7][3] += hb.w*w.w;
    }
    #pragma unroll
    for (int s=0;s<8;s++)
      #pragma unroll
      for (int c2=0;c2<4;c2++)
        acc[s][c2] += __shfl_xor(acc[s][c2], 32, 64);
    if ((tid & 32) == 0) {
      const int kp = kc >> 1;
      #pragma unroll
      for (int s=0;s<8;s++)
        #pragma unroll
        for (int c2=0;c2<4;c2++)
          red[kp][s*4+c2][gq] = acc[s][c2];
    }
    __syncthreads();   // B1

    float hreg;
    {
      float g[4];
      #pragma unroll
      for (int gt=0; gt<4; ++gt) {
        const int c = gt*32 + aj;
        const int gqq = c >> 2, cc = c & 3;
        const int ii = as*4 + cc;
        g[gt] = red[0][ii][gqq] + red[1][ii][gqq] + red[2][ii][gqq] + red[3][ii][gqq];
      }
      g[0] += pre0; g[1] += pre1; g[2] += pre2; g[3] += pre3;
      const float ig = sigf(g[0]), fg = sigf(g[1]), gg = tanhf(g[2]), og = sigf(g[3]);
      cst = fg*cst + ig*gg;
      hreg = og*tanhf(cst);
      hl[wg*32 + aj][as] = hreg;
      __hip_atomic_store(&Hb[wp*2048 + (wg*32 + aj)*8 + as], hreg,
                         __ATOMIC_RELAXED, __HIP_MEMORY_SCOPE_AGENT);
    }
    __syncthreads();   // B2

    if (tid == 0)
      __hip_atomic_store(&fl[wg*32], tt+1, __ATOMIC_RELAXED, __HIP_MEMORY_SCOPE_AGENT);

    if (HSo) HSo[((size_t)(as*256 + t))*512 + d*256 + wg*32 + aj] = hreg;
    if (HTo && tt == 255) HTo[((size_t)(as*2 + d))*256 + wg*32 + aj] = hreg;
  }
}

// ---------------------------------------------------------------------------
// Norms: bx<1024 -> row L2 norms of HS; else weighted norms (wnorm)
// ---------------------------------------------------------------------------
__global__ __launch_bounds__(256) void k_norms(const float* __restrict__ HS_,
                                               const float* __restrict__ w3, const float* __restrict__ w4,
                                               float* __restrict__ NORM_,
                                               float* __restrict__ WN1_, float* __restrict__ WN2_){
  const int bx = blockIdx.x;
  int lane = threadIdx.x & 63;
  if (bx < 1024) {
    int r = bx*4 + (threadIdx.x >> 6);
    int seq = r >> 9, d = (r >> 8) & 1, i = r & 255;
    const float* row = HS_ + ((size_t)(seq*256 + i))*512 + d*256;
    float s = 0.f;
    #pragma unroll
    for (int q=0;q<4;q++){ float v = row[lane + 64*q]; s += v*v; }
    for (int off=32; off; off>>=1) s += __shfl_xor(s, off, 64);
    if (lane == 0) NORM_[r] = sqrtf(s);
  } else {
    int rid = (bx-1024)*4 + (threadIdx.x >> 6);
    int side = rid / 20480; int rem = rid % 20480;
    int d = rem / 10240; int rem2 = rem % 10240;
    int b = rem2 / 2560; int l = (rem2 / 256) % 10; int i = rem2 & 255;
    int seq = side ? 4+b : b;
    const float* row = HS_ + ((size_t)(seq*256 + i))*512 + d*256;
    const float* w = (d ? w4 : w3) + l*256;
    float s = 0.f;
    #pragma unroll
    for (int q=0;q<4;q++){ float wv = w[lane+64*q]; float v = row[lane+64*q]; s += wv*wv*v*v; }
    for (int off=32; off; off>>=1) s += __shfl_xor(s, off, 64);
    if (lane == 0) (side ? WN2_ : WN1_)[rem] = sqrtf(s);
  }
}

// ---------------------------------------------------------------------------
// Combined att reductions: bx<512 -> row sum+max; else col sum+max (z=bx-512)
// ---------------------------------------------------------------------------
__global__ __launch_bounds__(256) void k_redcomb(const float* __restrict__ ATT_,
                                                 float* __restrict__ RS_, float* __restrict__ RMAX_,
                                                 float* __restrict__ CS_, float* __restrict__ CMAX_){
  const int bx = blockIdx.x;
  if (bx < 512) {
    int r = bx*4 + (threadIdx.x >> 6);
    int lane = threadIdx.x & 63;
    const float* row = ATT_ + (size_t)r*256;
    float s = 0.f, m = -INFINITY;
    #pragma unroll
    for (int q=0;q<4;q++){ float v = row[lane + 64*q]; s += v; m = fmaxf(m,v); }
    for (int off=32; off; off>>=1){ s += __shfl_xor(s,off,64); m = fmaxf(m, __shfl_xor(m,off,64)); }
    if (lane == 0){ RS_[r] = s; RMAX_[r] = m; }
  } else {
    int z = bx - 512;
    const float* in = ATT_ + (size_t)z*65536;
    int j = threadIdx.x;
    float s = 0.f, m = -INFINITY;
    for (int r=0;r<256;r++){ float v = in[(size_t)r*256 + j]; s += v; m = fmaxf(m,v); }
    CS_[z*256 + j] = s;
    CMAX_[z*256 + j] = m;
  }
}

// ---------------------------------------------------------------------------
// Assemble mv rows (62 channels) -- unchanged
// ---------------------------------------------------------------------------
__global__ __launch_bounds__(256) void k_mv(
    const float* __restrict__ HS_, const float* __restrict__ MEANH_, const float* __restrict__ MEANP_,
    const float* __restrict__ XH_, const float* __restrict__ XP_,
    const float* __restrict__ RS_, const float* __restrict__ RMAX_,
    const float* __restrict__ CS_, const float* __restrict__ CMAX_,
    const float* __restrict__ MMR_, const float* __restrict__ MMC_,
    const float* __restrict__ w5, const float* __restrict__ w6,
    const float* __restrict__ w7, const float* __restrict__ w8,
    float* __restrict__ MV_)
{
  const int blk = blockIdx.x;
  const int side = blk >> 10, b = (blk >> 8) & 3, i = blk & 255;
  const int wv = threadIdx.x >> 6, lane = threadIdx.x & 63;
  float* mvrow = MV_ + (size_t)blk*62;

  if (threadIdx.x == 0){
    const float* rmax = side ? CMAX_ : RMAX_;
    const float* rsum = side ? CS_   : RS_;
    mvrow[0] = rmax[b*256 + i];
    mvrow[1] = rsum[b*256 + i] * (1.f/256.f);
  }
  if (threadIdx.x < 20){
    int dd = threadIdx.x / 10, l = threadIdx.x % 10;
    const float* mm = side ? MMC_ : MMR_;
    mvrow[2 + dd*10 + l] = mm[dd*10240 + (b*10 + l)*256 + i];
  }
  const int d = wv & 1;
  const int seq = side ? 4+b : b;
  const float* arow = HS_ + ((size_t)(seq*256 + i))*512 + d*256;
  const float* Mside = side ? MEANP_ : MEANH_;
  const float* Xside = side ? XP_ : XH_;
  const float* brow = (wv < 2 ? Mside : Xside) + (size_t)d*262144 + (size_t)b*65536 + (size_t)i*256;
  const float* wp = (wv==0) ? w5 : (wv==1) ? w6 : (wv==2) ? w7 : w8;

  float av[4], bv[4];
  #pragma unroll
  for (int q=0;q<4;q++){ av[q] = arow[lane+64*q]; bv[q] = brow[lane+64*q]; }
  for (int l=0;l<10;l++){
    const float* wrow = wp + l*256;
    float s1=0.f, s2=0.f, s3=0.f;
    #pragma unroll
    for (int q=0;q<4;q++){
      float w = wrow[lane+64*q]; float w2v = w*w;
      s1 += w2v*av[q]*bv[q]; s2 += w2v*av[q]*av[q]; s3 += w2v*bv[q]*bv[q];
    }
    for (int off=32; off; off>>=1){
      s1 += __shfl_xor(s1,off,64); s2 += __shfl_xor(s2,off,64); s3 += __shfl_xor(s3,off,64);
    }
    if (lane == 0) mvrow[22 + wv*10 + l] = s1 / fmaxf(sqrtf(s2)*sqrtf(s3), EPSV);
  }
}

// ---------------------------------------------------------------------------
// Fused head: fc1 (tanh) + fc2, one block per batch b, 512 threads.
// ---------------------------------------------------------------------------
__global__ __launch_bounds__(512) void k_fc12(const float* __restrict__ HT_,
                                              const float* __restrict__ XM,
                                              const float* __restrict__ W1T,
                                              const float* __restrict__ b1,
                                              const float* __restrict__ W2,
                                              const float* __restrict__ b2,
                                              float* __restrict__ out){
  __shared__ float x[1626];
  __shared__ float xs2[512];
  int b = blockIdx.x, t = threadIdx.x;
  if (t < 256){
    x[t]       = HT_[(b*2+0)*256 + t];
    x[256+t]   = HT_[(b*2+1)*256 + t];
    x[512+t]   = HT_[((4+b)*2+0)*256 + t];
    x[768+t]   = HT_[((4+b)*2+1)*256 + t];
  }
  if (t == 0){ x[1024] = 0.5f; x[1025] = 0.5f; }
  if (t < 300){ x[1026+t] = XM[b*600 + t]; x[1326+t] = XM[b*600 + 300 + t]; }
  __syncthreads();
  float acc = b1[t];
  for (int k=0;k<1626;k++) acc += x[k]*W1T[(size_t)k*512 + t];
  xs2[t] = tanhf(acc);
  __syncthreads();
  if (t < 22){
    float o = b2[t];
    const float* wr = W2 + (size_t)t*512;
    for (int k=0;k<512;k++) o += xs2[k]*wr[k];
    out[b*22 + t] = o;
  }
}

// ---------------------------------------------------------------------------
extern "C" void kernel_launch(void* const* d_in, const int* in_sizes, int n_in,
                              void* d_out, int out_size, void* d_ws, size_t ws_size,
                              hipStream_t stream) {
  const float* left  = (const float*)d_in[0];
  const float* right = (const float*)d_in[1];
  const float* cWihF = (const float*)d_in[2];
  const float* cWhhF = (const float*)d_in[3];
  const float* cbF   = (const float*)d_in[4];
  const float* cWihB = (const float*)d_in[5];
  const float* cWhhB = (const float*)d_in[6];
  const float* cbB   = (const float*)d_in[7];
  const float* aWihF = (const float*)d_in[8];
  const float* aWhhF = (const float*)d_in[9];
  const float* abF   = (const float*)d_in[10];
  const float* aWihB = (const float*)d_in[11];
  const float* aWhhB = (const float*)d_in[12];
  const float* abB   = (const float*)d_in[13];
  const float* w3 = (const float*)d_in[14];
  const float* w4 = (const float*)d_in[15];
  const float* w5 = (const float*)d_in[16];
  const float* w6 = (const float*)d_in[17];
  const float* w7 = (const float*)d_in[18];
  const float* w8 = (const float*)d_in[19];
  const float* fc1W = (const float*)d_in[20];
  const float* fc1b = (const float*)d_in[21];
  const float* fc2W = (const float*)d_in[22];
  const float* fc2b = (const float*)d_in[23];
  float* out = (float*)d_out;
  float* ws = (float*)d_ws;

  // workspace layout (floats)
  float* WT    = ws;                 // 4 * 262144 (ctx_f, ctx_b, agg_f, agg_b)
  float* PREf  = ws + 1048576;       // 2097152
  float* PREb  = ws + 3145728;       // 2097152
  float* HS    = ws + 5242880;       // 1048576
  float* NORM  = ws + 6291456;       // 4096
  float* ATT   = ws + 6295552;       // 524288
  float* RS    = ws + 6819840;       // 2048
  float* RMAX  = ws + 6821888;       // 2048
  float* CS    = ws + 6823936;       // 2048
  float* CMAX  = ws + 6825984;       // 2048
  float* MEANH = ws + 6828032;       // 524288
  float* MEANP = ws + 7352320;       // 524288
  float* XH    = ws + 7876608;       // 524288
  float* XP    = ws + 8400896;       // 524288
  float* WN1   = ws + 8925184;       // 20480
  float* WN2   = ws + 8945664;       // 20480
  float* MM    = ws + 8966144;       // 2621440 scratch
  float* MMR   = ws + 11587584;      // 20480
  float* MMC   = ws + 11608064;      // 20480
  float* MV    = ws + 11628544;      // 126976
  float* HT    = ws + 11755520;      // 4096
  float* XM    = ws + 11759616;      // 2400
  float* W1T   = ws + 11764064;      // 832512

  // MM overlays (time-multiplexed)
  float* HXB  = MM;                   // scans: 8192
  int*   FLG  = (int*)(MM + 8192);    // scans: 512 ints
  float* PARTR= MM;                   // pairwise: 81920
  float* PARTC= MM + 81920;           // 81920

  // 1. ctx Whh transposes (needed before ctx scan)
  k_transpose2<<<dim3(8,32,2), dim3(32,32), 0, stream>>>(cWhhF, cWhhB, WT, WT + 262144);

  // 2. ctx projections (z=4, pointers selected in-kernel)
  k_proj<<<dim3(16,16,4),256,0,stream>>>(left, right, cWihF, cWihB, cbF, cbB, PREf, PREb);

  // 3. ctx scan + hidden aux work (W1T / agg-Whh transposes, input means)
  hipMemsetAsync(FLG, 0, 512*sizeof(int), stream);
  k_scanaux<<<64,256,0,stream>>>(PREf, PREb, WT, WT+262144, HXB, FLG, HS, nullptr,
                                 1, fc1W, W1T, aWhhF, WT+524288, aWhhB, WT+786432,
                                 left, right, XM);

  // 4. norms (row L2 + weighted) in one launch
  k_norms<<<11264,256,0,stream>>>(HS, w3, w4, NORM, WN1, WN2);

  // 5. att cosine matrix
  k_att<<<dim3(4,4,8),256,0,stream>>>(HS, NORM, ATT);

  // 6. att row+col reductions in one launch
  k_redcomb<<<520,256,0,stream>>>(ATT, RS, RMAX, CS, CMAX);

  // 7. attentive means and maxes
  k_attstat<<<dim3(4,4,16),256,0,stream>>>(ATT, HS, RS, CS, MEANH, XH, MEANP, XP);

  // 8. pairwise mp-match fw+bw (one launch) + combine
  k_pmm2<<<dim3(4,4,80),256,0,stream>>>(HS, w3, w4, WN1, WN2, PARTR, PARTC);
  k_pcomb<<<80,256,0,stream>>>(PARTR, PARTC, MMR, MMC);

  // 9. assemble mv
  k_mv<<<2048,256,0,stream>>>(HS, MEANH, MEANP, XH, XP, RS, RMAX, CS, CMAX,
                              MMR, MMC, w5, w6, w7, w8, MV);

  // 10. agg projections (z=2)
  k_aggproj<<<dim3(16,32,2),256,0,stream>>>(MV, aWihF, aWihB, abF, abB, PREf, PREb);

  // 11. agg scan (no aux)
  hipMemsetAsync(FLG, 0, 512*sizeof(int), stream);
  k_scanaux<<<64,256,0,stream>>>(PREf, PREb, WT+524288, WT+786432, HXB, FLG, nullptr, HT,
                                 0, fc1W, W1T, aWhhF, WT+524288, aWhhB, WT+786432,
                                 left, right, XM);

  // 12. fused head
  k_fc12<<<4,512,0,stream>>>(HT, XM, W1T, fc1b, fc2W, fc2b, out);
}

// Round 12
// 1875.622 us; speedup vs baseline: 2.0787x; 1.1691x over previous
//
#include <hip/hip_runtime.h>
#include <hip/hip_bf16.h>
#include <math.h>

#define EPSV 1e-8f

__device__ __forceinline__ float dsmall(float d){ return d > EPSV ? d : EPSV; }
__device__ __forceinline__ float sigf(float x){ return 1.f/(1.f+expf(-x)); }

// ---------------------------------------------------------------------------
// Transpose ctx Whh (z selects F/B): W (1024x256) -> WT (256x1024)
// ---------------------------------------------------------------------------
__global__ __launch_bounds__(1024) void k_transpose2(const float* __restrict__ WF,
                                                     const float* __restrict__ WB,
                                                     float* __restrict__ WT0,
                                                     float* __restrict__ WT1){
  const float* W = blockIdx.z ? WB : WF;
  float* WT = blockIdx.z ? WT1 : WT0;
  __shared__ float t[32][33];
  int rb = blockIdx.y*32, cb = blockIdx.x*32;
  int r = rb + threadIdx.y, c = cb + threadIdx.x;
  t[threadIdx.y][threadIdx.x] = W[(size_t)r*256 + c];
  __syncthreads();
  int rr = cb + threadIdx.y, cc = rb + threadIdx.x;
  WT[(size_t)rr*1024 + cc] = t[threadIdx.x][threadIdx.y];
}

// ---------------------------------------------------------------------------
// ctx projections: z in 0..3 (zo=z>>1: left/right; zi=z&1: F/B dir)
// ---------------------------------------------------------------------------
__global__ __launch_bounds__(256) void k_proj(
    const float* __restrict__ left, const float* __restrict__ right,
    const float* __restrict__ WihF, const float* __restrict__ WihB,
    const float* __restrict__ bF, const float* __restrict__ bB,
    float* __restrict__ PREf, float* __restrict__ PREb)
{
  const int z = blockIdx.z, zo = z >> 1, zi = z & 1;
  const float* A = zo ? right : left;
  const float* B = zi ? WihB : WihF;
  const float* bias = zi ? bB : bF;
  float* C = (zi ? PREb : PREf) + (size_t)zo*1048576;
  const int K = 300;

  __shared__ float As[16][68];
  __shared__ float Bs[16][68];
  const int mb = blockIdx.y*64, nb = blockIdx.x*64;
  const int tid = threadIdx.x;
  const int tx = tid & 15, ty = tid >> 4;

  float acc[4][4];
  #pragma unroll
  for (int i=0;i<4;i++)
    #pragma unroll
    for (int j=0;j<4;j++) acc[i][j] = 0.f;

  for (int kt = 0; kt < K; kt += 16) {
    int ka = tid & 15, ma = tid >> 4;
    #pragma unroll
    for (int q=0;q<4;q++){
      int m = ma + q*16;
      float v = 0.f, bvv = 0.f;
      if (kt+ka < K){
        v = A[(size_t)(mb+m)*300 + kt+ka];
        bvv = B[(size_t)(nb+m)*300 + kt+ka];
      }
      As[ka][m] = v; Bs[ka][m] = bvv;
    }
    __syncthreads();
    #pragma unroll
    for (int k=0;k<16;k++){
      float a[4], bv[4];
      #pragma unroll
      for (int i=0;i<4;i++) a[i] = As[k][ty*4+i];
      #pragma unroll
      for (int j=0;j<4;j++) bv[j] = Bs[k][tx*4+j];
      #pragma unroll
      for (int i=0;i<4;i++)
        #pragma unroll
        for (int j=0;j<4;j++) acc[i][j] += a[i]*bv[j];
    }
    __syncthreads();
  }
  #pragma unroll
  for (int i=0;i<4;i++){
    int m = mb + ty*4 + i;
    #pragma unroll
    for (int j=0;j<4;j++){
      int n = nb + tx*4 + j;
      C[(size_t)m*1024 + n] = acc[i][j] + bias[n];
    }
  }
}

// ---------------------------------------------------------------------------
// agg projections: z in 0..1 (F/B)
// ---------------------------------------------------------------------------
__global__ __launch_bounds__(256) void k_aggproj(
    const float* __restrict__ MV_,
    const float* __restrict__ WihF, const float* __restrict__ WihB,
    const float* __restrict__ bF, const float* __restrict__ bB,
    float* __restrict__ PREf, float* __restrict__ PREb)
{
  const int zi = blockIdx.z;
  const float* B = zi ? WihB : WihF;
  const float* bias = zi ? bB : bF;
  float* C = zi ? PREb : PREf;
  const int K = 62;

  __shared__ float As[16][68];
  __shared__ float Bs[16][68];
  const int mb = blockIdx.y*64, nb = blockIdx.x*64;
  const int tid = threadIdx.x;
  const int tx = tid & 15, ty = tid >> 4;

  float acc[4][4];
  #pragma unroll
  for (int i=0;i<4;i++)
    #pragma unroll
    for (int j=0;j<4;j++) acc[i][j] = 0.f;

  for (int kt = 0; kt < K; kt += 16) {
    int ka = tid & 15, ma = tid >> 4;
    #pragma unroll
    for (int q=0;q<4;q++){
      int m = ma + q*16;
      float v = 0.f, bvv = 0.f;
      if (kt+ka < K){
        v = MV_[(size_t)(mb+m)*62 + kt+ka];
        bvv = B[(size_t)(nb+m)*62 + kt+ka];
      }
      As[ka][m] = v; Bs[ka][m] = bvv;
    }
    __syncthreads();
    #pragma unroll
    for (int k=0;k<16;k++){
      float a[4], bv[4];
      #pragma unroll
      for (int i=0;i<4;i++) a[i] = As[k][ty*4+i];
      #pragma unroll
      for (int j=0;j<4;j++) bv[j] = Bs[k][tx*4+j];
      #pragma unroll
      for (int i=0;i<4;i++)
        #pragma unroll
        for (int j=0;j<4;j++) acc[i][j] += a[i]*bv[j];
    }
    __syncthreads();
  }
  #pragma unroll
  for (int i=0;i<4;i++){
    int m = mb + ty*4 + i;
    #pragma unroll
    for (int j=0;j<4;j++){
      int n = nb + tx*4 + j;
      C[(size_t)m*1024 + n] = acc[i][j] + bias[n];
    }
  }
}

// ---------------------------------------------------------------------------
// att cosine matrix: C=A@B^T / dsmall(U[m]*V[n]), z = d*4+b
// ---------------------------------------------------------------------------
__global__ __launch_bounds__(256) void k_att(
    const float* __restrict__ HS_, const float* __restrict__ NORM_,
    float* __restrict__ ATT_)
{
  const int z = blockIdx.z;
  const int d = z >> 2, b = z & 3;
  const float* A = HS_ + d*256 + (size_t)b*131072;
  const float* B = HS_ + 524288 + d*256 + (size_t)b*131072;
  const float* Uv = NORM_ + (size_t)b*512 + d*256;
  const float* Vv = NORM_ + (size_t)(4+b)*512 + d*256;
  float* C = ATT_ + (size_t)z*65536;

  __shared__ float As[16][68];
  __shared__ float Bs[16][68];
  const int mb = blockIdx.y*64, nb = blockIdx.x*64;
  const int tid = threadIdx.x;
  const int tx = tid & 15, ty = tid >> 4;

  float acc[4][4];
  #pragma unroll
  for (int i=0;i<4;i++)
    #pragma unroll
    for (int j=0;j<4;j++) acc[i][j] = 0.f;

  for (int kt = 0; kt < 256; kt += 16) {
    int ka = tid & 15, ma = tid >> 4;
    #pragma unroll
    for (int q=0;q<4;q++){
      int m = ma + q*16;
      As[ka][m] = A[(size_t)(mb+m)*512 + kt+ka];
      Bs[ka][m] = B[(size_t)(nb+m)*512 + kt+ka];
    }
    __syncthreads();
    #pragma unroll
    for (int k=0;k<16;k++){
      float a[4], bv[4];
      #pragma unroll
      for (int i=0;i<4;i++) a[i] = As[k][ty*4+i];
      #pragma unroll
      for (int j=0;j<4;j++) bv[j] = Bs[k][tx*4+j];
      #pragma unroll
      for (int i=0;i<4;i++)
        #pragma unroll
        for (int j=0;j<4;j++) acc[i][j] += a[i]*bv[j];
    }
    __syncthreads();
  }
  #pragma unroll
  for (int i=0;i<4;i++){
    int m = mb + ty*4 + i;
    float um = Uv[m];
    #pragma unroll
    for (int j=0;j<4;j++){
      int n = nb + tx*4 + j;
      C[(size_t)m*256 + n] = acc[i][j] / dsmall(um * Vv[n]);
    }
  }
}

// ---------------------------------------------------------------------------
// Fused attentive stats
// ---------------------------------------------------------------------------
__global__ __launch_bounds__(256) void k_attstat(
    const float* __restrict__ ATT_, const float* __restrict__ HS_,
    const float* __restrict__ RS_, const float* __restrict__ CS_,
    float* __restrict__ MEANH_, float* __restrict__ XH_,
    float* __restrict__ MEANP_, float* __restrict__ XP_)
{
  const int z16 = blockIdx.z;
  const int var = z16 >> 3;
  const int z = z16 & 7;
  const int d = z >> 2, b = z & 3;
  const float* A = ATT_ + (size_t)z*65536;
  const float* B = (var ? HS_ : HS_ + 524288) + d*256 + (size_t)b*131072;
  const float* U = (var ? CS_ : RS_) + z*256;
  float* C1 = (var ? MEANP_ : MEANH_) + (size_t)z*65536;
  float* C2 = (var ? XP_    : XH_   ) + (size_t)z*65536;

  __shared__ float As[16][68];
  __shared__ float Bs[16][68];
  const int mb = blockIdx.y*64, nb = blockIdx.x*64;
  const int tid = threadIdx.x;
  const int tx = tid & 15, ty = tid >> 4;

  float asum[4][4], amax[4][4];
  #pragma unroll
  for (int i=0;i<4;i++)
    #pragma unroll
    for (int j=0;j<4;j++){ asum[i][j]=0.f; amax[i][j]=-INFINITY; }

  for (int kt = 0; kt < 256; kt += 16) {
    if (var == 0) {
      int ka = tid & 15, ma = tid >> 4;
      #pragma unroll
      for (int q=0;q<4;q++)
        As[ka][ma+q*16] = A[(size_t)(mb+ma+q*16)*256 + kt+ka];
    } else {
      int ma = tid & 63, ka = tid >> 6;
      #pragma unroll
      for (int q=0;q<4;q++)
        As[ka+q*4][ma] = A[(size_t)(kt+ka+q*4)*256 + mb+ma];
    }
    {
      int nbi = tid & 63, kb = tid >> 6;
      #pragma unroll
      for (int q=0;q<4;q++)
        Bs[kb+q*4][nbi] = B[(size_t)(kt+kb+q*4)*512 + nb+nbi];
    }
    __syncthreads();
    #pragma unroll
    for (int k=0;k<16;k++){
      float a[4], bv[4];
      #pragma unroll
      for (int i=0;i<4;i++) a[i] = As[k][ty*4+i];
      #pragma unroll
      for (int j=0;j<4;j++) bv[j] = Bs[k][tx*4+j];
      #pragma unroll
      for (int i=0;i<4;i++)
        #pragma unroll
        for (int j=0;j<4;j++){
          float p = a[i]*bv[j];
          asum[i][j] += p;
          amax[i][j] = fmaxf(amax[i][j], p);
        }
    }
    __syncthreads();
  }
  #pragma unroll
  for (int i=0;i<4;i++){
    int m = mb + ty*4 + i;
    float ud = dsmall(U[m]);
    #pragma unroll
    for (int j=0;j<4;j++){
      int n = nb + tx*4 + j;
      C1[(size_t)m*256 + n] = asum[i][j] / ud;
      C2[(size_t)m*256 + n] = amax[i][j];
    }
  }
}

// ---------------------------------------------------------------------------
// Pairwise mp-match, fw+bw in one launch: z in 0..79 (dir = z>=40)
// ---------------------------------------------------------------------------
__global__ __launch_bounds__(256) void k_pmm2(
    const float* __restrict__ HS_,
    const float* __restrict__ w3, const float* __restrict__ w4,
    const float* __restrict__ WN1_, const float* __restrict__ WN2_,
    float* __restrict__ PARTR, float* __restrict__ PARTC)
{
  const int z = blockIdx.z;
  const int dir = z >= 40;
  const int zz = z - dir*40;
  const int bq = zz / 10, l = zz % 10;
  const float* A = HS_ + dir*256 + (size_t)bq*131072;
  const float* B = HS_ + 524288 + dir*256 + (size_t)bq*131072;
  const float* Wv = (dir ? w4 : w3) + l*256;
  const float* U = WN1_ + dir*10240 + bq*2560 + l*256;
  const float* V = WN2_ + dir*10240 + bq*2560 + l*256;

  __shared__ float As[16][68];
  __shared__ float Bs[16][68];
  const int mb = blockIdx.y*64, nb = blockIdx.x*64;
  const int tid = threadIdx.x;
  const int tx = tid & 15, ty = tid >> 4;

  float acc[4][4];
  #pragma unroll
  for (int i=0;i<4;i++)
    #pragma unroll
    for (int j=0;j<4;j++) acc[i][j] = 0.f;

  for (int kt = 0; kt < 256; kt += 16) {
    int ka = tid & 15, ma = tid >> 4;
    float w = Wv[kt+ka]; float w2 = w*w;
    #pragma unroll
    for (int q=0;q<4;q++){
      As[ka][ma+q*16] = A[(size_t)(mb+ma+q*16)*512 + kt+ka] * w2;
      Bs[ka][ma+q*16] = B[(size_t)(nb+ma+q*16)*512 + kt+ka];
    }
    __syncthreads();
    #pragma unroll
    for (int k=0;k<16;k++){
      float a[4], bv[4];
      #pragma unroll
      for (int i=0;i<4;i++) a[i] = As[k][ty*4+i];
      #pragma unroll
      for (int j=0;j<4;j++) bv[j] = Bs[k][tx*4+j];
      #pragma unroll
      for (int i=0;i<4;i++)
        #pragma unroll
        for (int j=0;j<4;j++) acc[i][j] += a[i]*bv[j];
    }
    __syncthreads();
  }
  float um[4], vn[4];
  #pragma unroll
  for (int i=0;i<4;i++) um[i] = U[mb + ty*4 + i];
  #pragma unroll
  for (int j=0;j<4;j++) vn[j] = V[nb + tx*4 + j];
  float c[4][4];
  #pragma unroll
  for (int i=0;i<4;i++)
    #pragma unroll
    for (int j=0;j<4;j++) c[i][j] = acc[i][j] / dsmall(um[i]*vn[j]);

  float rm[4];
  #pragma unroll
  for (int i=0;i<4;i++){
    rm[i] = fmaxf(fmaxf(c[i][0], c[i][1]), fmaxf(c[i][2], c[i][3]));
    rm[i] = fmaxf(rm[i], __shfl_xor(rm[i], 1, 64));
    rm[i] = fmaxf(rm[i], __shfl_xor(rm[i], 2, 64));
    rm[i] = fmaxf(rm[i], __shfl_xor(rm[i], 4, 64));
    rm[i] = fmaxf(rm[i], __shfl_xor(rm[i], 8, 64));
  }
  if ((tid & 15) == 0){
    #pragma unroll
    for (int i=0;i<4;i++)
      PARTR[((size_t)z*4 + blockIdx.x)*256 + mb + ty*4 + i] = rm[i];
  }
  __syncthreads();
  float* colp = &As[0][0];
  #pragma unroll
  for (int j=0;j<4;j++)
    colp[ty*64 + tx*4 + j] = fmaxf(fmaxf(c[0][j], c[1][j]), fmaxf(c[2][j], c[3][j]));
  __syncthreads();
  if (tid < 64){
    float m = colp[tid];
    #pragma unroll
    for (int r=1;r<16;r++) m = fmaxf(m, colp[r*64 + tid]);
    PARTC[((size_t)z*4 + blockIdx.y)*256 + nb + tid] = m;
  }
}

__global__ void k_pcomb(const float* __restrict__ PARTR, const float* __restrict__ PARTC,
                        float* __restrict__ MMRo, float* __restrict__ MMCo){
  int z = blockIdx.x, i = threadIdx.x;
  size_t b0 = (size_t)z*4*256 + i;
  float r = fmaxf(fmaxf(PARTR[b0], PARTR[b0+256]), fmaxf(PARTR[b0+512], PARTR[b0+768]));
  float c = fmaxf(fmaxf(PARTC[b0], PARTC[b0+256]), fmaxf(PARTC[b0+512], PARTC[b0+768]));
  MMRo[(size_t)z*256 + i] = r;
  MMCo[(size_t)z*256 + i] = c;
}

// ---------------------------------------------------------------------------
// LSTM scan v10: 2 teams/dir x 8 WGs, 4 seqs per team. Active: (bx&7)<4:
// xcd = bx&7 = d*2+tm (team's 8 WGs share one XCD). wg = bx>>3.
// Per-thread matmul halves vs R8 (acc[4][4]); sync structure R8-verbatim
// per team. Aux work on (bx&7)>=4 during ctx scan.
// Hbuf: [d*2+tm][parity][256 h][4 s] = 4*2048 floats.
// flg: [d*2+tm][wg]*32 ints = 1024 ints.
// ---------------------------------------------------------------------------
__global__ __launch_bounds__(256, 1) void k_scanaux(
    const float* __restrict__ PREf, const float* __restrict__ PREb,
    const float* __restrict__ WTf, const float* __restrict__ WTb,
    float* __restrict__ Hbuf, int* __restrict__ flg,
    float* __restrict__ HSo, float* __restrict__ HTo,
    int do_aux,
    const float* __restrict__ fc1W, float* __restrict__ W1T,
    const float* __restrict__ aWhhF, float* __restrict__ WTaggF,
    const float* __restrict__ aWhhB, float* __restrict__ WTaggB,
    const float* __restrict__ left, const float* __restrict__ right,
    float* __restrict__ XM)
{
  __shared__ float Wl[256][128];     // 128 KB (aux reuses as 32x33 tile)
  __shared__ float hl[256][4];       // 4 KB   hl[h][s]
  __shared__ float red[4][16][40];   // 10 KB  red[kp][s*4+cc][gq]

  const int bx = blockIdx.x;
  const int tid = threadIdx.x;

  if ((bx & 7) >= 4) {
    if (!do_aux) return;
    float (*tl)[33] = (float(*)[33])Wl;
    const int aux = (bx >> 3)*4 + (bx & 7) - 4;   // 0..31
    for (int u = aux; u < 816 + 512 + 8; u += 32) {
      if (u < 816) {                // fc1W (512x1626) -> W1T (1626x512)
        int tI = u % 16, tJ = u / 16;
        int r0 = tI*32, c0 = tJ*32;
        for (int e = tid; e < 1024; e += 256) {
          int rr = e >> 5, cc = e & 31;
          int c = c0 + cc;
          tl[rr][cc] = (c < 1626) ? fc1W[(size_t)(r0+rr)*1626 + c] : 0.f;
        }
        __syncthreads();
        for (int e = tid; e < 1024; e += 256) {
          int cc = e >> 5, rr = e & 31;
          int c = c0 + cc;
          if (c < 1626) W1T[(size_t)c*512 + r0 + rr] = tl[rr][cc];
        }
        __syncthreads();
      } else if (u < 1328) {        // aWhh (1024x256) -> WTagg (256x1024)
        int u2 = u - 816;
        const float* S = (u2 >= 256) ? aWhhB : aWhhF;
        float* D = (u2 >= 256) ? WTaggB : WTaggF;
        int tile = u2 & 255;
        int r0 = (tile >> 3)*32, c0 = (tile & 7)*32;
        for (int e = tid; e < 1024; e += 256) {
          int rr = e >> 5, cc = e & 31;
          tl[rr][cc] = S[(size_t)(r0+rr)*256 + c0 + cc];
        }
        __syncthreads();
        for (int e = tid; e < 1024; e += 256) {
          int cc = e >> 5, rr = e & 31;
          D[(size_t)(c0+cc)*1024 + r0 + rr] = tl[rr][cc];
        }
        __syncthreads();
      } else {                      // means
        int m = u - 1328;
        int b = m & 3, sideR = m >> 2;
        const float* src = sideR ? right : left;
        for (int ch = tid; ch < 300; ch += 256) {
          float s = 0.f;
          for (int t = 0; t < 256; t++) s += src[((size_t)(b*256+t))*300 + ch];
          XM[b*600 + sideR*300 + ch] = s * (1.f/256.f);
        }
      }
    }
    return;
  }

  // ----------------- scan path -----------------
  const int xcd = bx & 7;          // 0..3
  const int d  = xcd >> 1;
  const int tm = xcd & 1;
  const int wg = bx >> 3;
  const int sq0 = tm*4;            // team's first seq
  const float* PRE = d ? PREb : PREf;
  const float* WT  = d ? WTb  : WTf;
  float* Hb = Hbuf + (size_t)xcd*2048;
  int* fl = flg + xcd*256;

  const int kc = tid >> 5;   // k-chunk 0..7
  const int gq = tid & 31;
  const int as = tid >> 5;   // activation seq (only tid<128 active)
  const int aj = tid & 31;

  for (int e = tid; e < 256*128; e += 256) {
    int k = e >> 7, c = e & 127;
    Wl[k][c] = WT[(size_t)k*1024 + (c>>5)*256 + wg*32 + (c&31)];
  }
  for (int e = tid; e < 1024; e += 256) ((float*)hl)[e] = 0.f;
  float cst = 0.f;
  __syncthreads();

  for (int tt = 0; tt < 256; ++tt) {
    const int t = d ? 255 - tt : tt;
    const int wp = tt & 1;
    const int sp = (tt + 1) & 1;

    // prefetch PRE (tid<128: as<4)
    float pre0=0.f, pre1=0.f, pre2=0.f, pre3=0.f;
    if (tid < 128) {
      const size_t pbase = ((size_t)((sq0+as)*256 + t))*1024 + wg*32 + aj;
      pre0 = PRE[pbase];       pre1 = PRE[pbase + 256];
      pre2 = PRE[pbase + 512]; pre3 = PRE[pbase + 768];
    }

    // per-half-wave fetch of remote chunk kc (32 rows x 4 seqs = 512B)
    if (tt > 0 && kc != wg) {
      const int* flp = &fl[kc*32];
      while (__hip_atomic_load(flp, __ATOMIC_RELAXED, __HIP_MEMORY_SCOPE_AGENT) < tt)
        __builtin_amdgcn_s_sleep(1);
      const unsigned long long* srcu =
          (const unsigned long long*)&Hb[sp*1024 + (kc*32 + gq)*4];
      unsigned long long u0 = __hip_atomic_load(srcu+0, __ATOMIC_RELAXED, __HIP_MEMORY_SCOPE_AGENT);
      unsigned long long u1 = __hip_atomic_load(srcu+1, __ATOMIC_RELAXED, __HIP_MEMORY_SCOPE_AGENT);
      unsigned long long* dst = (unsigned long long*)&hl[kc*32 + gq][0];
      dst[0] = u0; dst[1] = u1;
    }

    // gate matmul: acc[s][cc] over 32 k of chunk kc
    float acc[4][4];
    #pragma unroll
    for (int s=0;s<4;s++){ acc[s][0]=0.f; acc[s][1]=0.f; acc[s][2]=0.f; acc[s][3]=0.f; }
    #pragma unroll 8
    for (int kk = 0; kk < 32; ++kk) {
      const int k = kc*32 + kk;
      float4 w  = *(const float4*)&Wl[k][gq*4];
      float4 ha = *(const float4*)&hl[k][0];
      acc[0][0] += ha.x*w.x; acc[0][1] += ha.x*w.y; acc[0][2] += ha.x*w.z; acc[0][3] += ha.x*w.w;
      acc[1][0] += ha.y*w.x; acc[1][1] += ha.y*w.y; acc[1][2] += ha.y*w.z; acc[1][3] += ha.y*w.w;
      acc[2][0] += ha.z*w.x; acc[2][1] += ha.z*w.y; acc[2][2] += ha.z*w.z; acc[2][3] += ha.z*w.w;
      acc[3][0] += ha.w*w.x; acc[3][1] += ha.w*w.y; acc[3][2] += ha.w*w.z; acc[3][3] += ha.w*w.w;
    }
    #pragma unroll
    for (int s=0;s<4;s++)
      #pragma unroll
      for (int c2=0;c2<4;c2++)
        acc[s][c2] += __shfl_xor(acc[s][c2], 32, 64);
    if ((tid & 32) == 0) {
      const int kp = kc >> 1;
      #pragma unroll
      for (int s=0;s<4;s++)
        #pragma unroll
        for (int c2=0;c2<4;c2++)
          red[kp][s*4+c2][gq] = acc[s][c2];
    }
    __syncthreads();   // B1

    float hreg = 0.f;
    if (tid < 128) {
      float g[4];
      #pragma unroll
      for (int gt=0; gt<4; ++gt) {
        const int c = gt*32 + aj;
        const int gqq = c >> 2, cc = c & 3;
        const int ii = as*4 + cc;
        g[gt] = red[0][ii][gqq] + red[1][ii][gqq] + red[2][ii][gqq] + red[3][ii][gqq];
      }
      g[0] += pre0; g[1] += pre1; g[2] += pre2; g[3] += pre3;
      const float ig = sigf(g[0]), fg = sigf(g[1]), gg = tanhf(g[2]), og = sigf(g[3]);
      cst = fg*cst + ig*gg;
      hreg = og*tanhf(cst);
      hl[wg*32 + aj][as] = hreg;
      __hip_atomic_store(&Hb[wp*1024 + (wg*32 + aj)*4 + as], hreg,
                         __ATOMIC_RELAXED, __HIP_MEMORY_SCOPE_AGENT);
    }
    __syncthreads();   // B2: drains Hb stores + hl ds_writes

    if (tid == 0)
      __hip_atomic_store(&fl[wg*32], tt+1, __ATOMIC_RELAXED, __HIP_MEMORY_SCOPE_AGENT);

    if (tid < 128) {
      if (HSo) HSo[((size_t)((sq0+as)*256 + t))*512 + d*256 + wg*32 + aj] = hreg;
      if (HTo && tt == 255) HTo[((size_t)((sq0+as)*2 + d))*256 + wg*32 + aj] = hreg;
    }
  }
}

// ---------------------------------------------------------------------------
// Norms: bx<1024 -> row L2 norms of HS; else weighted norms
// ---------------------------------------------------------------------------
__global__ __launch_bounds__(256) void k_norms(const float* __restrict__ HS_,
                                               const float* __restrict__ w3, const float* __restrict__ w4,
                                               float* __restrict__ NORM_,
                                               float* __restrict__ WN1_, float* __restrict__ WN2_){
  const int bx = blockIdx.x;
  int lane = threadIdx.x & 63;
  if (bx < 1024) {
    int r = bx*4 + (threadIdx.x >> 6);
    int seq = r >> 9, d = (r >> 8) & 1, i = r & 255;
    const float* row = HS_ + ((size_t)(seq*256 + i))*512 + d*256;
    float s = 0.f;
    #pragma unroll
    for (int q=0;q<4;q++){ float v = row[lane + 64*q]; s += v*v; }
    for (int off=32; off; off>>=1) s += __shfl_xor(s, off, 64);
    if (lane == 0) NORM_[r] = sqrtf(s);
  } else {
    int rid = (bx-1024)*4 + (threadIdx.x >> 6);
    int side = rid / 20480; int rem = rid % 20480;
    int d = rem / 10240; int rem2 = rem % 10240;
    int b = rem2 / 2560; int l = (rem2 / 256) % 10; int i = rem2 & 255;
    int seq = side ? 4+b : b;
    const float* row = HS_ + ((size_t)(seq*256 + i))*512 + d*256;
    const float* w = (d ? w4 : w3) + l*256;
    float s = 0.f;
    #pragma unroll
    for (int q=0;q<4;q++){ float wv = w[lane+64*q]; float v = row[lane+64*q]; s += wv*wv*v*v; }
    for (int off=32; off; off>>=1) s += __shfl_xor(s, off, 64);
    if (lane == 0) (side ? WN2_ : WN1_)[rem] = sqrtf(s);
  }
}

// ---------------------------------------------------------------------------
// Combined att reductions
// ---------------------------------------------------------------------------
__global__ __launch_bounds__(256) void k_redcomb(const float* __restrict__ ATT_,
                                                 float* __restrict__ RS_, float* __restrict__ RMAX_,
                                                 float* __restrict__ CS_, float* __restrict__ CMAX_){
  const int bx = blockIdx.x;
  if (bx < 512) {
    int r = bx*4 + (threadIdx.x >> 6);
    int lane = threadIdx.x & 63;
    const float* row = ATT_ + (size_t)r*256;
    float s = 0.f, m = -INFINITY;
    #pragma unroll
    for (int q=0;q<4;q++){ float v = row[lane + 64*q]; s += v; m = fmaxf(m,v); }
    for (int off=32; off; off>>=1){ s += __shfl_xor(s,off,64); m = fmaxf(m, __shfl_xor(m,off,64)); }
    if (lane == 0){ RS_[r] = s; RMAX_[r] = m; }
  } else {
    int z = bx - 512;
    const float* in = ATT_ + (size_t)z*65536;
    int j = threadIdx.x;
    float s = 0.f, m = -INFINITY;
    for (int r=0;r<256;r++){ float v = in[(size_t)r*256 + j]; s += v; m = fmaxf(m,v); }
    CS_[z*256 + j] = s;
    CMAX_[z*256 + j] = m;
  }
}

// ---------------------------------------------------------------------------
// Assemble mv rows (62 channels)
// ---------------------------------------------------------------------------
__global__ __launch_bounds__(256) void k_mv(
    const float* __restrict__ HS_, const float* __restrict__ MEANH_, const float* __restrict__ MEANP_,
    const float* __restrict__ XH_, const float* __restrict__ XP_,
    const float* __restrict__ RS_, const float* __restrict__ RMAX_,
    const float* __restrict__ CS_, const float* __restrict__ CMAX_,
    const float* __restrict__ MMR_, const float* __restrict__ MMC_,
    const float* __restrict__ w5, const float* __restrict__ w6,
    const float* __restrict__ w7, const float* __restrict__ w8,
    float* __restrict__ MV_)
{
  const int blk = blockIdx.x;
  const int side = blk >> 10, b = (blk >> 8) & 3, i = blk & 255;
  const int wv = threadIdx.x >> 6, lane = threadIdx.x & 63;
  float* mvrow = MV_ + (size_t)blk*62;

  if (threadIdx.x == 0){
    const float* rmax = side ? CMAX_ : RMAX_;
    const float* rsum = side ? CS_   : RS_;
    mvrow[0] = rmax[b*256 + i];
    mvrow[1] = rsum[b*256 + i] * (1.f/256.f);
  }
  if (threadIdx.x < 20){
    int dd = threadIdx.x / 10, l = threadIdx.x % 10;
    const float* mm = side ? MMC_ : MMR_;
    mvrow[2 + dd*10 + l] = mm[dd*10240 + (b*10 + l)*256 + i];
  }
  const int d = wv & 1;
  const int seq = side ? 4+b : b;
  const float* arow = HS_ + ((size_t)(seq*256 + i))*512 + d*256;
  const float* Mside = side ? MEANP_ : MEANH_;
  const float* Xside = side ? XP_ : XH_;
  const float* brow = (wv < 2 ? Mside : Xside) + (size_t)d*262144 + (size_t)b*65536 + (size_t)i*256;
  const float* wp = (wv==0) ? w5 : (wv==1) ? w6 : (wv==2) ? w7 : w8;

  float av[4], bv[4];
  #pragma unroll
  for (int q=0;q<4;q++){ av[q] = arow[lane+64*q]; bv[q] = brow[lane+64*q]; }
  for (int l=0;l<10;l++){
    const float* wrow = wp + l*256;
    float s1=0.f, s2=0.f, s3=0.f;
    #pragma unroll
    for (int q=0;q<4;q++){
      float w = wrow[lane+64*q]; float w2v = w*w;
      s1 += w2v*av[q]*bv[q]; s2 += w2v*av[q]*av[q]; s3 += w2v*bv[q]*bv[q];
    }
    for (int off=32; off; off>>=1){
      s1 += __shfl_xor(s1,off,64); s2 += __shfl_xor(s2,off,64); s3 += __shfl_xor(s3,off,64);
    }
    if (lane == 0) mvrow[22 + wv*10 + l] = s1 / fmaxf(sqrtf(s2)*sqrtf(s3), EPSV);
  }
}

// ---------------------------------------------------------------------------
// Fused head: fc1 (tanh) + fc2
// ---------------------------------------------------------------------------
__global__ __launch_bounds__(512) void k_fc12(const float* __restrict__ HT_,
                                              const float* __restrict__ XM,
                                              const float* __restrict__ W1T,
                                              const float* __restrict__ b1,
                                              const float* __restrict__ W2,
                                              const float* __restrict__ b2,
                                              float* __restrict__ out){
  __shared__ float x[1626];
  __shared__ float xs2[512];
  int b = blockIdx.x, t = threadIdx.x;
  if (t < 256){
    x[t]       = HT_[(b*2+0)*256 + t];
    x[256+t]   = HT_[(b*2+1)*256 + t];
    x[512+t]   = HT_[((4+b)*2+0)*256 + t];
    x[768+t]   = HT_[((4+b)*2+1)*256 + t];
  }
  if (t == 0){ x[1024] = 0.5f; x[1025] = 0.5f; }
  if (t < 300){ x[1026+t] = XM[b*600 + t]; x[1326+t] = XM[b*600 + 300 + t]; }
  __syncthreads();
  float acc = b1[t];
  for (int k=0;k<1626;k++) acc += x[k]*W1T[(size_t)k*512 + t];
  xs2[t] = tanhf(acc);
  __syncthreads();
  if (t < 22){
    float o = b2[t];
    const float* wr = W2 + (size_t)t*512;
    for (int k=0;k<512;k++) o += xs2[k]*wr[k];
    out[b*22 + t] = o;
  }
}

// ---------------------------------------------------------------------------
extern "C" void kernel_launch(void* const* d_in, const int* in_sizes, int n_in,
                              void* d_out, int out_size, void* d_ws, size_t ws_size,
                              hipStream_t stream) {
  const float* left  = (const float*)d_in[0];
  const float* right = (const float*)d_in[1];
  const float* cWihF = (const float*)d_in[2];
  const float* cWhhF = (const float*)d_in[3];
  const float* cbF   = (const float*)d_in[4];
  const float* cWihB = (const float*)d_in[5];
  const float* cWhhB = (const float*)d_in[6];
  const float* cbB   = (const float*)d_in[7];
  const float* aWihF = (const float*)d_in[8];
  const float* aWhhF = (const float*)d_in[9];
  const float* abF   = (const float*)d_in[10];
  const float* aWihB = (const float*)d_in[11];
  const float* aWhhB = (const float*)d_in[12];
  const float* abB   = (const float*)d_in[13];
  const float* w3 = (const float*)d_in[14];
  const float* w4 = (const float*)d_in[15];
  const float* w5 = (const float*)d_in[16];
  const float* w6 = (const float*)d_in[17];
  const float* w7 = (const float*)d_in[18];
  const float* w8 = (const float*)d_in[19];
  const float* fc1W = (const float*)d_in[20];
  const float* fc1b = (const float*)d_in[21];
  const float* fc2W = (const float*)d_in[22];
  const float* fc2b = (const float*)d_in[23];
  float* out = (float*)d_out;
  float* ws = (float*)d_ws;

  // workspace layout (floats)
  float* WT    = ws;                 // 4 * 262144
  float* PREf  = ws + 1048576;       // 2097152
  float* PREb  = ws + 3145728;       // 2097152
  float* HS    = ws + 5242880;       // 1048576
  float* NORM  = ws + 6291456;       // 4096
  float* ATT   = ws + 6295552;       // 524288
  float* RS    = ws + 6819840;       // 2048
  float* RMAX  = ws + 6821888;       // 2048
  float* CS    = ws + 6823936;       // 2048
  float* CMAX  = ws + 6825984;       // 2048
  float* MEANH = ws + 6828032;       // 524288
  float* MEANP = ws + 7352320;       // 524288
  float* XH    = ws + 7876608;       // 524288
  float* XP    = ws + 8400896;       // 524288
  float* WN1   = ws + 8925184;       // 20480
  float* WN2   = ws + 8945664;       // 20480
  float* MM    = ws + 8966144;       // 2621440 scratch
  float* MMR   = ws + 11587584;      // 20480
  float* MMC   = ws + 11608064;      // 20480
  float* MV    = ws + 11628544;      // 126976
  float* HT    = ws + 11755520;      // 4096
  float* XM    = ws + 11759616;      // 2400
  float* W1T   = ws + 11764064;      // 832512

  // MM overlays
  float* HXB  = MM;                   // scans: 8192 floats (4 teams x 2048)
  int*   FLG  = (int*)(MM + 8192);    // scans: 1024 ints
  float* PARTR= MM;                   // pairwise: 81920
  float* PARTC= MM + 81920;           // 81920

  // 1. ctx Whh transposes
  k_transpose2<<<dim3(8,32,2), dim3(32,32), 0, stream>>>(cWhhF, cWhhB, WT, WT + 262144);

  // 2. ctx projections
  k_proj<<<dim3(16,16,4),256,0,stream>>>(left, right, cWihF, cWihB, cbF, cbB, PREf, PREb);

  // 3. ctx scan (2 teams/dir) + hidden aux work
  hipMemsetAsync(FLG, 0, 1024*sizeof(int), stream);
  k_scanaux<<<64,256,0,stream>>>(PREf, PREb, WT, WT+262144, HXB, FLG, HS, nullptr,
                                 1, fc1W, W1T, aWhhF, WT+524288, aWhhB, WT+786432,
                                 left, right, XM);

  // 4. norms
  k_norms<<<11264,256,0,stream>>>(HS, w3, w4, NORM, WN1, WN2);

  // 5. att cosine matrix
  k_att<<<dim3(4,4,8),256,0,stream>>>(HS, NORM, ATT);

  // 6. att reductions
  k_redcomb<<<520,256,0,stream>>>(ATT, RS, RMAX, CS, CMAX);

  // 7. attentive means and maxes
  k_attstat<<<dim3(4,4,16),256,0,stream>>>(ATT, HS, RS, CS, MEANH, XH, MEANP, XP);

  // 8. pairwise mp-match + combine
  k_pmm2<<<dim3(4,4,80),256,0,stream>>>(HS, w3, w4, WN1, WN2, PARTR, PARTC);
  k_pcomb<<<80,256,0,stream>>>(PARTR, PARTC, MMR, MMC);

  // 9. assemble mv
  k_mv<<<2048,256,0,stream>>>(HS, MEANH, MEANP, XH, XP, RS, RMAX, CS, CMAX,
                              MMR, MMC, w5, w6, w7, w8, MV);

  // 10. agg projections
  k_aggproj<<<dim3(16,32,2),256,0,stream>>>(MV, aWihF, aWihB, abF, abB, PREf, PREb);

  // 11. agg scan (no aux)
  hipMemsetAsync(FLG, 0, 1024*sizeof(int), stream);
  k_scanaux<<<64,256,0,stream>>>(PREf, PREb, WT+524288, WT+786432, HXB, FLG, nullptr, HT,
                                 0, fc1W, W1T, aWhhF, WT+524288, aWhhB, WT+786432,
                                 left, right, XM);

  // 12. fused head
  k_fc12<<<4,512,0,stream>>>(HT, XM, W1T, fc1b, fc2W, fc2b, out);
}

// Round 13
// 1630.751 us; speedup vs baseline: 2.3909x; 1.1502x over previous
//
#include <hip/hip_runtime.h>
#include <hip/hip_bf16.h>
#include <math.h>

#define EPSV 1e-8f

__device__ __forceinline__ float dsmall(float d){ return d > EPSV ? d : EPSV; }
__device__ __forceinline__ float sigf(float x){ return 1.f/(1.f+expf(-x)); }

// ---------------------------------------------------------------------------
// Transpose ctx Whh (z selects F/B): W (1024x256) -> WT (256x1024)
// ---------------------------------------------------------------------------
__global__ __launch_bounds__(1024) void k_transpose2(const float* __restrict__ WF,
                                                     const float* __restrict__ WB,
                                                     float* __restrict__ WT0,
                                                     float* __restrict__ WT1){
  const float* W = blockIdx.z ? WB : WF;
  float* WT = blockIdx.z ? WT1 : WT0;
  __shared__ float t[32][33];
  int rb = blockIdx.y*32, cb = blockIdx.x*32;
  int r = rb + threadIdx.y, c = cb + threadIdx.x;
  t[threadIdx.y][threadIdx.x] = W[(size_t)r*256 + c];
  __syncthreads();
  int rr = cb + threadIdx.y, cc = rb + threadIdx.x;
  WT[(size_t)rr*1024 + cc] = t[threadIdx.x][threadIdx.y];
}

// ---------------------------------------------------------------------------
// ctx projections: z in 0..3 (zo=z>>1: left/right; zi=z&1: F/B dir)
// ---------------------------------------------------------------------------
__global__ __launch_bounds__(256) void k_proj(
    const float* __restrict__ left, const float* __restrict__ right,
    const float* __restrict__ WihF, const float* __restrict__ WihB,
    const float* __restrict__ bF, const float* __restrict__ bB,
    float* __restrict__ PREf, float* __restrict__ PREb)
{
  const int z = blockIdx.z, zo = z >> 1, zi = z & 1;
  const float* A = zo ? right : left;
  const float* B = zi ? WihB : WihF;
  const float* bias = zi ? bB : bF;
  float* C = (zi ? PREb : PREf) + (size_t)zo*1048576;
  const int K = 300;

  __shared__ float As[16][68];
  __shared__ float Bs[16][68];
  const int mb = blockIdx.y*64, nb = blockIdx.x*64;
  const int tid = threadIdx.x;
  const int tx = tid & 15, ty = tid >> 4;

  float acc[4][4];
  #pragma unroll
  for (int i=0;i<4;i++)
    #pragma unroll
    for (int j=0;j<4;j++) acc[i][j] = 0.f;

  for (int kt = 0; kt < K; kt += 16) {
    int ka = tid & 15, ma = tid >> 4;
    #pragma unroll
    for (int q=0;q<4;q++){
      int m = ma + q*16;
      float v = 0.f, bvv = 0.f;
      if (kt+ka < K){
        v = A[(size_t)(mb+m)*300 + kt+ka];
        bvv = B[(size_t)(nb+m)*300 + kt+ka];
      }
      As[ka][m] = v; Bs[ka][m] = bvv;
    }
    __syncthreads();
    #pragma unroll
    for (int k=0;k<16;k++){
      float a[4], bv[4];
      #pragma unroll
      for (int i=0;i<4;i++) a[i] = As[k][ty*4+i];
      #pragma unroll
      for (int j=0;j<4;j++) bv[j] = Bs[k][tx*4+j];
      #pragma unroll
      for (int i=0;i<4;i++)
        #pragma unroll
        for (int j=0;j<4;j++) acc[i][j] += a[i]*bv[j];
    }
    __syncthreads();
  }
  #pragma unroll
  for (int i=0;i<4;i++){
    int m = mb + ty*4 + i;
    #pragma unroll
    for (int j=0;j<4;j++){
      int n = nb + tx*4 + j;
      C[(size_t)m*1024 + n] = acc[i][j] + bias[n];
    }
  }
}

// ---------------------------------------------------------------------------
// agg projections: z in 0..1 (F/B)
// ---------------------------------------------------------------------------
__global__ __launch_bounds__(256) void k_aggproj(
    const float* __restrict__ MV_,
    const float* __restrict__ WihF, const float* __restrict__ WihB,
    const float* __restrict__ bF, const float* __restrict__ bB,
    float* __restrict__ PREf, float* __restrict__ PREb)
{
  const int zi = blockIdx.z;
  const float* B = zi ? WihB : WihF;
  const float* bias = zi ? bB : bF;
  float* C = zi ? PREb : PREf;
  const int K = 62;

  __shared__ float As[16][68];
  __shared__ float Bs[16][68];
  const int mb = blockIdx.y*64, nb = blockIdx.x*64;
  const int tid = threadIdx.x;
  const int tx = tid & 15, ty = tid >> 4;

  float acc[4][4];
  #pragma unroll
  for (int i=0;i<4;i++)
    #pragma unroll
    for (int j=0;j<4;j++) acc[i][j] = 0.f;

  for (int kt = 0; kt < K; kt += 16) {
    int ka = tid & 15, ma = tid >> 4;
    #pragma unroll
    for (int q=0;q<4;q++){
      int m = ma + q*16;
      float v = 0.f, bvv = 0.f;
      if (kt+ka < K){
        v = MV_[(size_t)(mb+m)*62 + kt+ka];
        bvv = B[(size_t)(nb+m)*62 + kt+ka];
      }
      As[ka][m] = v; Bs[ka][m] = bvv;
    }
    __syncthreads();
    #pragma unroll
    for (int k=0;k<16;k++){
      float a[4], bv[4];
      #pragma unroll
      for (int i=0;i<4;i++) a[i] = As[k][ty*4+i];
      #pragma unroll
      for (int j=0;j<4;j++) bv[j] = Bs[k][tx*4+j];
      #pragma unroll
      for (int i=0;i<4;i++)
        #pragma unroll
        for (int j=0;j<4;j++) acc[i][j] += a[i]*bv[j];
    }
    __syncthreads();
  }
  #pragma unroll
  for (int i=0;i<4;i++){
    int m = mb + ty*4 + i;
    #pragma unroll
    for (int j=0;j<4;j++){
      int n = nb + tx*4 + j;
      C[(size_t)m*1024 + n] = acc[i][j] + bias[n];
    }
  }
}

// ---------------------------------------------------------------------------
// att cosine matrix: C=A@B^T / dsmall(U[m]*V[n]), z = d*4+b
// ---------------------------------------------------------------------------
__global__ __launch_bounds__(256) void k_att(
    const float* __restrict__ HS_, const float* __restrict__ NORM_,
    float* __restrict__ ATT_)
{
  const int z = blockIdx.z;
  const int d = z >> 2, b = z & 3;
  const float* A = HS_ + d*256 + (size_t)b*131072;
  const float* B = HS_ + 524288 + d*256 + (size_t)b*131072;
  const float* Uv = NORM_ + (size_t)b*512 + d*256;
  const float* Vv = NORM_ + (size_t)(4+b)*512 + d*256;
  float* C = ATT_ + (size_t)z*65536;

  __shared__ float As[16][68];
  __shared__ float Bs[16][68];
  const int mb = blockIdx.y*64, nb = blockIdx.x*64;
  const int tid = threadIdx.x;
  const int tx = tid & 15, ty = tid >> 4;

  float acc[4][4];
  #pragma unroll
  for (int i=0;i<4;i++)
    #pragma unroll
    for (int j=0;j<4;j++) acc[i][j] = 0.f;

  for (int kt = 0; kt < 256; kt += 16) {
    int ka = tid & 15, ma = tid >> 4;
    #pragma unroll
    for (int q=0;q<4;q++){
      int m = ma + q*16;
      As[ka][m] = A[(size_t)(mb+m)*512 + kt+ka];
      Bs[ka][m] = B[(size_t)(nb+m)*512 + kt+ka];
    }
    __syncthreads();
    #pragma unroll
    for (int k=0;k<16;k++){
      float a[4], bv[4];
      #pragma unroll
      for (int i=0;i<4;i++) a[i] = As[k][ty*4+i];
      #pragma unroll
      for (int j=0;j<4;j++) bv[j] = Bs[k][tx*4+j];
      #pragma unroll
      for (int i=0;i<4;i++)
        #pragma unroll
        for (int j=0;j<4;j++) acc[i][j] += a[i]*bv[j];
    }
    __syncthreads();
  }
  #pragma unroll
  for (int i=0;i<4;i++){
    int m = mb + ty*4 + i;
    float um = Uv[m];
    #pragma unroll
    for (int j=0;j<4;j++){
      int n = nb + tx*4 + j;
      C[(size_t)m*256 + n] = acc[i][j] / dsmall(um * Vv[n]);
    }
  }
}

// ---------------------------------------------------------------------------
// Fused attentive stats
// ---------------------------------------------------------------------------
__global__ __launch_bounds__(256) void k_attstat(
    const float* __restrict__ ATT_, const float* __restrict__ HS_,
    const float* __restrict__ RS_, const float* __restrict__ CS_,
    float* __restrict__ MEANH_, float* __restrict__ XH_,
    float* __restrict__ MEANP_, float* __restrict__ XP_)
{
  const int z16 = blockIdx.z;
  const int var = z16 >> 3;
  const int z = z16 & 7;
  const int d = z >> 2, b = z & 3;
  const float* A = ATT_ + (size_t)z*65536;
  const float* B = (var ? HS_ : HS_ + 524288) + d*256 + (size_t)b*131072;
  const float* U = (var ? CS_ : RS_) + z*256;
  float* C1 = (var ? MEANP_ : MEANH_) + (size_t)z*65536;
  float* C2 = (var ? XP_    : XH_   ) + (size_t)z*65536;

  __shared__ float As[16][68];
  __shared__ float Bs[16][68];
  const int mb = blockIdx.y*64, nb = blockIdx.x*64;
  const int tid = threadIdx.x;
  const int tx = tid & 15, ty = tid >> 4;

  float asum[4][4], amax[4][4];
  #pragma unroll
  for (int i=0;i<4;i++)
    #pragma unroll
    for (int j=0;j<4;j++){ asum[i][j]=0.f; amax[i][j]=-INFINITY; }

  for (int kt = 0; kt < 256; kt += 16) {
    if (var == 0) {
      int ka = tid & 15, ma = tid >> 4;
      #pragma unroll
      for (int q=0;q<4;q++)
        As[ka][ma+q*16] = A[(size_t)(mb+ma+q*16)*256 + kt+ka];
    } else {
      int ma = tid & 63, ka = tid >> 6;
      #pragma unroll
      for (int q=0;q<4;q++)
        As[ka+q*4][ma] = A[(size_t)(kt+ka+q*4)*256 + mb+ma];
    }
    {
      int nbi = tid & 63, kb = tid >> 6;
      #pragma unroll
      for (int q=0;q<4;q++)
        Bs[kb+q*4][nbi] = B[(size_t)(kt+kb+q*4)*512 + nb+nbi];
    }
    __syncthreads();
    #pragma unroll
    for (int k=0;k<16;k++){
      float a[4], bv[4];
      #pragma unroll
      for (int i=0;i<4;i++) a[i] = As[k][ty*4+i];
      #pragma unroll
      for (int j=0;j<4;j++) bv[j] = Bs[k][tx*4+j];
      #pragma unroll
      for (int i=0;i<4;i++)
        #pragma unroll
        for (int j=0;j<4;j++){
          float p = a[i]*bv[j];
          asum[i][j] += p;
          amax[i][j] = fmaxf(amax[i][j], p);
        }
    }
    __syncthreads();
  }
  #pragma unroll
  for (int i=0;i<4;i++){
    int m = mb + ty*4 + i;
    float ud = dsmall(U[m]);
    #pragma unroll
    for (int j=0;j<4;j++){
      int n = nb + tx*4 + j;
      C1[(size_t)m*256 + n] = asum[i][j] / ud;
      C2[(size_t)m*256 + n] = amax[i][j];
    }
  }
}

// ---------------------------------------------------------------------------
// Pairwise mp-match, fw+bw in one launch: z in 0..79 (dir = z>=40)
// ---------------------------------------------------------------------------
__global__ __launch_bounds__(256) void k_pmm2(
    const float* __restrict__ HS_,
    const float* __restrict__ w3, const float* __restrict__ w4,
    const float* __restrict__ WN1_, const float* __restrict__ WN2_,
    float* __restrict__ PARTR, float* __restrict__ PARTC)
{
  const int z = blockIdx.z;
  const int dir = z >= 40;
  const int zz = z - dir*40;
  const int bq = zz / 10, l = zz % 10;
  const float* A = HS_ + dir*256 + (size_t)bq*131072;
  const float* B = HS_ + 524288 + dir*256 + (size_t)bq*131072;
  const float* Wv = (dir ? w4 : w3) + l*256;
  const float* U = WN1_ + dir*10240 + bq*2560 + l*256;
  const float* V = WN2_ + dir*10240 + bq*2560 + l*256;

  __shared__ float As[16][68];
  __shared__ float Bs[16][68];
  const int mb = blockIdx.y*64, nb = blockIdx.x*64;
  const int tid = threadIdx.x;
  const int tx = tid & 15, ty = tid >> 4;

  float acc[4][4];
  #pragma unroll
  for (int i=0;i<4;i++)
    #pragma unroll
    for (int j=0;j<4;j++) acc[i][j] = 0.f;

  for (int kt = 0; kt < 256; kt += 16) {
    int ka = tid & 15, ma = tid >> 4;
    float w = Wv[kt+ka]; float w2 = w*w;
    #pragma unroll
    for (int q=0;q<4;q++){
      As[ka][ma+q*16] = A[(size_t)(mb+ma+q*16)*512 + kt+ka] * w2;
      Bs[ka][ma+q*16] = B[(size_t)(nb+ma+q*16)*512 + kt+ka];
    }
    __syncthreads();
    #pragma unroll
    for (int k=0;k<16;k++){
      float a[4], bv[4];
      #pragma unroll
      for (int i=0;i<4;i++) a[i] = As[k][ty*4+i];
      #pragma unroll
      for (int j=0;j<4;j++) bv[j] = Bs[k][tx*4+j];
      #pragma unroll
      for (int i=0;i<4;i++)
        #pragma unroll
        for (int j=0;j<4;j++) acc[i][j] += a[i]*bv[j];
    }
    __syncthreads();
  }
  float um[4], vn[4];
  #pragma unroll
  for (int i=0;i<4;i++) um[i] = U[mb + ty*4 + i];
  #pragma unroll
  for (int j=0;j<4;j++) vn[j] = V[nb + tx*4 + j];
  float c[4][4];
  #pragma unroll
  for (int i=0;i<4;i++)
    #pragma unroll
    for (int j=0;j<4;j++) c[i][j] = acc[i][j] / dsmall(um[i]*vn[j]);

  float rm[4];
  #pragma unroll
  for (int i=0;i<4;i++){
    rm[i] = fmaxf(fmaxf(c[i][0], c[i][1]), fmaxf(c[i][2], c[i][3]));
    rm[i] = fmaxf(rm[i], __shfl_xor(rm[i], 1, 64));
    rm[i] = fmaxf(rm[i], __shfl_xor(rm[i], 2, 64));
    rm[i] = fmaxf(rm[i], __shfl_xor(rm[i], 4, 64));
    rm[i] = fmaxf(rm[i], __shfl_xor(rm[i], 8, 64));
  }
  if ((tid & 15) == 0){
    #pragma unroll
    for (int i=0;i<4;i++)
      PARTR[((size_t)z*4 + blockIdx.x)*256 + mb + ty*4 + i] = rm[i];
  }
  __syncthreads();
  float* colp = &As[0][0];
  #pragma unroll
  for (int j=0;j<4;j++)
    colp[ty*64 + tx*4 + j] = fmaxf(fmaxf(c[0][j], c[1][j]), fmaxf(c[2][j], c[3][j]));
  __syncthreads();
  if (tid < 64){
    float m = colp[tid];
    #pragma unroll
    for (int r=1;r<16;r++) m = fmaxf(m, colp[r*64 + tid]);
    PARTC[((size_t)z*4 + blockIdx.y)*256 + nb + tid] = m;
  }
}

__global__ void k_pcomb(const float* __restrict__ PARTR, const float* __restrict__ PARTC,
                        float* __restrict__ MMRo, float* __restrict__ MMCo){
  int z = blockIdx.x, i = threadIdx.x;
  size_t b0 = (size_t)z*4*256 + i;
  float r = fmaxf(fmaxf(PARTR[b0], PARTR[b0+256]), fmaxf(PARTR[b0+512], PARTR[b0+768]));
  float c = fmaxf(fmaxf(PARTC[b0], PARTC[b0+256]), fmaxf(PARTC[b0+512], PARTC[b0+768]));
  MMRo[(size_t)z*256 + i] = r;
  MMCo[(size_t)z*256 + i] = c;
}

// ---------------------------------------------------------------------------
// LSTM scan v11: 8 teams (4/dir) x 8 WGs, 2 seqs per team. bx<64: scan,
// team = bx&7 (one XCD per team), wg = bx>>3, d = team>>2, sq0 = (team&3)*2.
// bx>=64: aux work during ctx scan.
// Hbuf: [team][parity][256 h][2 s] = 1024 floats/team.
// flg: [team*8+wg]*32 ints = 2048 ints.
// ---------------------------------------------------------------------------
__global__ __launch_bounds__(256, 1) void k_scanaux(
    const float* __restrict__ PREf, const float* __restrict__ PREb,
    const float* __restrict__ WTf, const float* __restrict__ WTb,
    float* __restrict__ Hbuf, int* __restrict__ flg,
    float* __restrict__ HSo, float* __restrict__ HTo,
    int do_aux,
    const float* __restrict__ fc1W, float* __restrict__ W1T,
    const float* __restrict__ aWhhF, float* __restrict__ WTaggF,
    const float* __restrict__ aWhhB, float* __restrict__ WTaggB,
    const float* __restrict__ left, const float* __restrict__ right,
    float* __restrict__ XM)
{
  __shared__ float Wl[256][128];     // 128 KB (aux reuses as 32x33 tile)
  __shared__ float hl[256][2];       // 2 KB   hl[h][s]
  __shared__ float red[4][8][40];    // 5 KB   red[kp][s*4+cc][gq]

  const int bx = blockIdx.x;
  const int tid = threadIdx.x;

  if (bx >= 64) {
    if (!do_aux) return;
    float (*tl)[33] = (float(*)[33])Wl;
    const int aux = bx - 64;          // 0..63
    for (int u = aux; u < 816 + 512 + 8; u += 64) {
      if (u < 816) {                // fc1W (512x1626) -> W1T (1626x512)
        int tI = u % 16, tJ = u / 16;
        int r0 = tI*32, c0 = tJ*32;
        for (int e = tid; e < 1024; e += 256) {
          int rr = e >> 5, cc = e & 31;
          int c = c0 + cc;
          tl[rr][cc] = (c < 1626) ? fc1W[(size_t)(r0+rr)*1626 + c] : 0.f;
        }
        __syncthreads();
        for (int e = tid; e < 1024; e += 256) {
          int cc = e >> 5, rr = e & 31;
          int c = c0 + cc;
          if (c < 1626) W1T[(size_t)c*512 + r0 + rr] = tl[rr][cc];
        }
        __syncthreads();
      } else if (u < 1328) {        // aWhh (1024x256) -> WTagg (256x1024)
        int u2 = u - 816;
        const float* S = (u2 >= 256) ? aWhhB : aWhhF;
        float* D = (u2 >= 256) ? WTaggB : WTaggF;
        int tile = u2 & 255;
        int r0 = (tile >> 3)*32, c0 = (tile & 7)*32;
        for (int e = tid; e < 1024; e += 256) {
          int rr = e >> 5, cc = e & 31;
          tl[rr][cc] = S[(size_t)(r0+rr)*256 + c0 + cc];
        }
        __syncthreads();
        for (int e = tid; e < 1024; e += 256) {
          int cc = e >> 5, rr = e & 31;
          D[(size_t)(c0+cc)*1024 + r0 + rr] = tl[rr][cc];
        }
        __syncthreads();
      } else {                      // means
        int m = u - 1328;
        int b = m & 3, sideR = m >> 2;
        const float* src = sideR ? right : left;
        for (int ch = tid; ch < 300; ch += 256) {
          float s = 0.f;
          for (int t = 0; t < 256; t++) s += src[((size_t)(b*256+t))*300 + ch];
          XM[b*600 + sideR*300 + ch] = s * (1.f/256.f);
        }
      }
    }
    return;
  }

  // ----------------- scan path -----------------
  const int team = bx & 7;
  const int d   = team >> 2;
  const int sq0 = (team & 3)*2;
  const int wg  = bx >> 3;
  const float* PRE = d ? PREb : PREf;
  const float* WT  = d ? WTb  : WTf;
  float* Hb = Hbuf + (size_t)team*1024;
  int* fl = flg + team*256;

  const int kc = tid >> 5;   // k-chunk 0..7
  const int gq = tid & 31;
  const int as = tid >> 5;   // activation seq (tid<64: 0..1)
  const int aj = tid & 31;

  for (int e = tid; e < 256*128; e += 256) {
    int k = e >> 7, c = e & 127;
    Wl[k][c] = WT[(size_t)k*1024 + (c>>5)*256 + wg*32 + (c&31)];
  }
  for (int e = tid; e < 512; e += 256) ((float*)hl)[e] = 0.f;
  float cst = 0.f;
  __syncthreads();

  for (int tt = 0; tt < 256; ++tt) {
    const int t = d ? 255 - tt : tt;
    const int wp = tt & 1;
    const int sp = (tt + 1) & 1;

    // prefetch PRE (tid<64)
    float pre0=0.f, pre1=0.f, pre2=0.f, pre3=0.f;
    if (tid < 64) {
      const size_t pbase = ((size_t)((sq0+as)*256 + t))*1024 + wg*32 + aj;
      pre0 = PRE[pbase];       pre1 = PRE[pbase + 256];
      pre2 = PRE[pbase + 512]; pre3 = PRE[pbase + 768];
    }

    // per-half-wave fetch of remote chunk kc (32 rows x 2 seqs = 256B)
    if (tt > 0 && kc != wg) {
      const int* flp = &fl[kc*32];
      while (__hip_atomic_load(flp, __ATOMIC_RELAXED, __HIP_MEMORY_SCOPE_AGENT) < tt)
        __builtin_amdgcn_s_sleep(1);
      const unsigned long long* srcu =
          (const unsigned long long*)&Hb[sp*512 + (kc*32 + gq)*2];
      unsigned long long u0 = __hip_atomic_load(srcu, __ATOMIC_RELAXED, __HIP_MEMORY_SCOPE_AGENT);
      *(unsigned long long*)&hl[kc*32 + gq][0] = u0;
    }

    // gate matmul: acc[s][cc] over 32 k of chunk kc
    float acc[2][4];
    #pragma unroll
    for (int s=0;s<2;s++){ acc[s][0]=0.f; acc[s][1]=0.f; acc[s][2]=0.f; acc[s][3]=0.f; }
    #pragma unroll 8
    for (int kk = 0; kk < 32; ++kk) {
      const int k = kc*32 + kk;
      float4 w  = *(const float4*)&Wl[k][gq*4];
      float2 ha = *(const float2*)&hl[k][0];
      acc[0][0] += ha.x*w.x; acc[0][1] += ha.x*w.y; acc[0][2] += ha.x*w.z; acc[0][3] += ha.x*w.w;
      acc[1][0] += ha.y*w.x; acc[1][1] += ha.y*w.y; acc[1][2] += ha.y*w.z; acc[1][3] += ha.y*w.w;
    }
    #pragma unroll
    for (int s=0;s<2;s++)
      #pragma unroll
      for (int c2=0;c2<4;c2++)
        acc[s][c2] += __shfl_xor(acc[s][c2], 32, 64);
    if ((tid & 32) == 0) {
      const int kp = kc >> 1;
      #pragma unroll
      for (int s=0;s<2;s++)
        #pragma unroll
        for (int c2=0;c2<4;c2++)
          red[kp][s*4+c2][gq] = acc[s][c2];
    }
    __syncthreads();   // B1

    float hreg = 0.f;
    if (tid < 64) {
      float g[4];
      #pragma unroll
      for (int gt=0; gt<4; ++gt) {
        const int c = gt*32 + aj;
        const int gqq = c >> 2, cc = c & 3;
        const int ii = as*4 + cc;
        g[gt] = red[0][ii][gqq] + red[1][ii][gqq] + red[2][ii][gqq] + red[3][ii][gqq];
      }
      g[0] += pre0; g[1] += pre1; g[2] += pre2; g[3] += pre3;
      const float ig = sigf(g[0]), fg = sigf(g[1]), gg = tanhf(g[2]), og = sigf(g[3]);
      cst = fg*cst + ig*gg;
      hreg = og*tanhf(cst);
      hl[wg*32 + aj][as] = hreg;
      __hip_atomic_store(&Hb[wp*512 + (wg*32 + aj)*2 + as], hreg,
                         __ATOMIC_RELAXED, __HIP_MEMORY_SCOPE_AGENT);
    }
    __syncthreads();   // B2: drains Hb stores + hl ds_writes

    if (tid == 0)
      __hip_atomic_store(&fl[wg*32], tt+1, __ATOMIC_RELAXED, __HIP_MEMORY_SCOPE_AGENT);

    if (tid < 64) {
      if (HSo) HSo[((size_t)((sq0+as)*256 + t))*512 + d*256 + wg*32 + aj] = hreg;
      if (HTo && tt == 255) HTo[((size_t)((sq0+as)*2 + d))*256 + wg*32 + aj] = hreg;
    }
  }
}

// ---------------------------------------------------------------------------
// Norms: bx<1024 -> row L2 norms of HS; else weighted norms
// ---------------------------------------------------------------------------
__global__ __launch_bounds__(256) void k_norms(const float* __restrict__ HS_,
                                               const float* __restrict__ w3, const float* __restrict__ w4,
                                               float* __restrict__ NORM_,
                                               float* __restrict__ WN1_, float* __restrict__ WN2_){
  const int bx = blockIdx.x;
  int lane = threadIdx.x & 63;
  if (bx < 1024) {
    int r = bx*4 + (threadIdx.x >> 6);
    int seq = r >> 9, d = (r >> 8) & 1, i = r & 255;
    const float* row = HS_ + ((size_t)(seq*256 + i))*512 + d*256;
    float s = 0.f;
    #pragma unroll
    for (int q=0;q<4;q++){ float v = row[lane + 64*q]; s += v*v; }
    for (int off=32; off; off>>=1) s += __shfl_xor(s, off, 64);
    if (lane == 0) NORM_[r] = sqrtf(s);
  } else {
    int rid = (bx-1024)*4 + (threadIdx.x >> 6);
    int side = rid / 20480; int rem = rid % 20480;
    int d = rem / 10240; int rem2 = rem % 10240;
    int b = rem2 / 2560; int l = (rem2 / 256) % 10; int i = rem2 & 255;
    int seq = side ? 4+b : b;
    const float* row = HS_ + ((size_t)(seq*256 + i))*512 + d*256;
    const float* w = (d ? w4 : w3) + l*256;
    float s = 0.f;
    #pragma unroll
    for (int q=0;q<4;q++){ float wv = w[lane+64*q]; float v = row[lane+64*q]; s += wv*wv*v*v; }
    for (int off=32; off; off>>=1) s += __shfl_xor(s, off, 64);
    if (lane == 0) (side ? WN2_ : WN1_)[rem] = sqrtf(s);
  }
}

// ---------------------------------------------------------------------------
// Combined att reductions
// ---------------------------------------------------------------------------
__global__ __launch_bounds__(256) void k_redcomb(const float* __restrict__ ATT_,
                                                 float* __restrict__ RS_, float* __restrict__ RMAX_,
                                                 float* __restrict__ CS_, float* __restrict__ CMAX_){
  const int bx = blockIdx.x;
  if (bx < 512) {
    int r = bx*4 + (threadIdx.x >> 6);
    int lane = threadIdx.x & 63;
    const float* row = ATT_ + (size_t)r*256;
    float s = 0.f, m = -INFINITY;
    #pragma unroll
    for (int q=0;q<4;q++){ float v = row[lane + 64*q]; s += v; m = fmaxf(m,v); }
    for (int off=32; off; off>>=1){ s += __shfl_xor(s,off,64); m = fmaxf(m, __shfl_xor(m,off,64)); }
    if (lane == 0){ RS_[r] = s; RMAX_[r] = m; }
  } else {
    int z = bx - 512;
    const float* in = ATT_ + (size_t)z*65536;
    int j = threadIdx.x;
    float s = 0.f, m = -INFINITY;
    for (int r=0;r<256;r++){ float v = in[(size_t)r*256 + j]; s += v; m = fmaxf(m,v); }
    CS_[z*256 + j] = s;
    CMAX_[z*256 + j] = m;
  }
}

// ---------------------------------------------------------------------------
// Assemble mv rows (62 channels)
// ---------------------------------------------------------------------------
__global__ __launch_bounds__(256) void k_mv(
    const float* __restrict__ HS_, const float* __restrict__ MEANH_, const float* __restrict__ MEANP_,
    const float* __restrict__ XH_, const float* __restrict__ XP_,
    const float* __restrict__ RS_, const float* __restrict__ RMAX_,
    const float* __restrict__ CS_, const float* __restrict__ CMAX_,
    const float* __restrict__ MMR_, const float* __restrict__ MMC_,
    const float* __restrict__ w5, const float* __restrict__ w6,
    const float* __restrict__ w7, const float* __restrict__ w8,
    float* __restrict__ MV_)
{
  const int blk = blockIdx.x;
  const int side = blk >> 10, b = (blk >> 8) & 3, i = blk & 255;
  const int wv = threadIdx.x >> 6, lane = threadIdx.x & 63;
  float* mvrow = MV_ + (size_t)blk*62;

  if (threadIdx.x == 0){
    const float* rmax = side ? CMAX_ : RMAX_;
    const float* rsum = side ? CS_   : RS_;
    mvrow[0] = rmax[b*256 + i];
    mvrow[1] = rsum[b*256 + i] * (1.f/256.f);
  }
  if (threadIdx.x < 20){
    int dd = threadIdx.x / 10, l = threadIdx.x % 10;
    const float* mm = side ? MMC_ : MMR_;
    mvrow[2 + dd*10 + l] = mm[dd*10240 + (b*10 + l)*256 + i];
  }
  const int d = wv & 1;
  const int seq = side ? 4+b : b;
  const float* arow = HS_ + ((size_t)(seq*256 + i))*512 + d*256;
  const float* Mside = side ? MEANP_ : MEANH_;
  const float* Xside = side ? XP_ : XH_;
  const float* brow = (wv < 2 ? Mside : Xside) + (size_t)d*262144 + (size_t)b*65536 + (size_t)i*256;
  const float* wp = (wv==0) ? w5 : (wv==1) ? w6 : (wv==2) ? w7 : w8;

  float av[4], bv[4];
  #pragma unroll
  for (int q=0;q<4;q++){ av[q] = arow[lane+64*q]; bv[q] = brow[lane+64*q]; }
  for (int l=0;l<10;l++){
    const float* wrow = wp + l*256;
    float s1=0.f, s2=0.f, s3=0.f;
    #pragma unroll
    for (int q=0;q<4;q++){
      float w = wrow[lane+64*q]; float w2v = w*w;
      s1 += w2v*av[q]*bv[q]; s2 += w2v*av[q]*av[q]; s3 += w2v*bv[q]*bv[q];
    }
    for (int off=32; off; off>>=1){
      s1 += __shfl_xor(s1,off,64); s2 += __shfl_xor(s2,off,64); s3 += __shfl_xor(s3,off,64);
    }
    if (lane == 0) mvrow[22 + wv*10 + l] = s1 / fmaxf(sqrtf(s2)*sqrtf(s3), EPSV);
  }
}

// ---------------------------------------------------------------------------
// Fused head: fc1 (tanh) + fc2
// ---------------------------------------------------------------------------
__global__ __launch_bounds__(512) void k_fc12(const float* __restrict__ HT_,
                                              const float* __restrict__ XM,
                                              const float* __restrict__ W1T,
                                              const float* __restrict__ b1,
                                              const float* __restrict__ W2,
                                              const float* __restrict__ b2,
                                              float* __restrict__ out){
  __shared__ float x[1626];
  __shared__ float xs2[512];
  int b = blockIdx.x, t = threadIdx.x;
  if (t < 256){
    x[t]       = HT_[(b*2+0)*256 + t];
    x[256+t]   = HT_[(b*2+1)*256 + t];
    x[512+t]   = HT_[((4+b)*2+0)*256 + t];
    x[768+t]   = HT_[((4+b)*2+1)*256 + t];
  }
  if (t == 0){ x[1024] = 0.5f; x[1025] = 0.5f; }
  if (t < 300){ x[1026+t] = XM[b*600 + t]; x[1326+t] = XM[b*600 + 300 + t]; }
  __syncthreads();
  float acc = b1[t];
  for (int k=0;k<1626;k++) acc += x[k]*W1T[(size_t)k*512 + t];
  xs2[t] = tanhf(acc);
  __syncthreads();
  if (t < 22){
    float o = b2[t];
    const float* wr = W2 + (size_t)t*512;
    for (int k=0;k<512;k++) o += xs2[k]*wr[k];
    out[b*22 + t] = o;
  }
}

// ---------------------------------------------------------------------------
extern "C" void kernel_launch(void* const* d_in, const int* in_sizes, int n_in,
                              void* d_out, int out_size, void* d_ws, size_t ws_size,
                              hipStream_t stream) {
  const float* left  = (const float*)d_in[0];
  const float* right = (const float*)d_in[1];
  const float* cWihF = (const float*)d_in[2];
  const float* cWhhF = (const float*)d_in[3];
  const float* cbF   = (const float*)d_in[4];
  const float* cWihB = (const float*)d_in[5];
  const float* cWhhB = (const float*)d_in[6];
  const float* cbB   = (const float*)d_in[7];
  const float* aWihF = (const float*)d_in[8];
  const float* aWhhF = (const float*)d_in[9];
  const float* abF   = (const float*)d_in[10];
  const float* aWihB = (const float*)d_in[11];
  const float* aWhhB = (const float*)d_in[12];
  const float* abB   = (const float*)d_in[13];
  const float* w3 = (const float*)d_in[14];
  const float* w4 = (const float*)d_in[15];
  const float* w5 = (const float*)d_in[16];
  const float* w6 = (const float*)d_in[17];
  const float* w7 = (const float*)d_in[18];
  const float* w8 = (const float*)d_in[19];
  const float* fc1W = (const float*)d_in[20];
  const float* fc1b = (const float*)d_in[21];
  const float* fc2W = (const float*)d_in[22];
  const float* fc2b = (const float*)d_in[23];
  float* out = (float*)d_out;
  float* ws = (float*)d_ws;

  // workspace layout (floats)
  float* WT    = ws;                 // 4 * 262144
  float* PREf  = ws + 1048576;       // 2097152
  float* PREb  = ws + 3145728;       // 2097152
  float* HS    = ws + 5242880;       // 1048576
  float* NORM  = ws + 6291456;       // 4096
  float* ATT   = ws + 6295552;       // 524288
  float* RS    = ws + 6819840;       // 2048
  float* RMAX  = ws + 6821888;       // 2048
  float* CS    = ws + 6823936;       // 2048
  float* CMAX  = ws + 6825984;       // 2048
  float* MEANH = ws + 6828032;       // 524288
  float* MEANP = ws + 7352320;       // 524288
  float* XH    = ws + 7876608;       // 524288
  float* XP    = ws + 8400896;       // 524288
  float* WN1   = ws + 8925184;       // 20480
  float* WN2   = ws + 8945664;       // 20480
  float* MM    = ws + 8966144;       // 2621440 scratch
  float* MMR   = ws + 11587584;      // 20480
  float* MMC   = ws + 11608064;      // 20480
  float* MV    = ws + 11628544;      // 126976
  float* HT    = ws + 11755520;      // 4096
  float* XM    = ws + 11759616;      // 2400
  float* W1T   = ws + 11764064;      // 832512

  // MM overlays
  float* HXB  = MM;                   // scans: 8192 floats (8 teams x 1024)
  int*   FLG  = (int*)(MM + 8192);    // scans: 2048 ints
  float* PARTR= MM;                   // pairwise: 81920
  float* PARTC= MM + 81920;           // 81920

  // 1. ctx Whh transposes
  k_transpose2<<<dim3(8,32,2), dim3(32,32), 0, stream>>>(cWhhF, cWhhB, WT, WT + 262144);

  // 2. ctx projections
  k_proj<<<dim3(16,16,4),256,0,stream>>>(left, right, cWihF, cWihB, cbF, cbB, PREf, PREb);

  // 3. ctx scan (4 teams/dir) + hidden aux work
  hipMemsetAsync(FLG, 0, 2048*sizeof(int), stream);
  k_scanaux<<<128,256,0,stream>>>(PREf, PREb, WT, WT+262144, HXB, FLG, HS, nullptr,
                                  1, fc1W, W1T, aWhhF, WT+524288, aWhhB, WT+786432,
                                  left, right, XM);

  // 4. norms
  k_norms<<<11264,256,0,stream>>>(HS, w3, w4, NORM, WN1, WN2);

  // 5. att cosine matrix
  k_att<<<dim3(4,4,8),256,0,stream>>>(HS, NORM, ATT);

  // 6. att reductions
  k_redcomb<<<520,256,0,stream>>>(ATT, RS, RMAX, CS, CMAX);

  // 7. attentive means and maxes
  k_attstat<<<dim3(4,4,16),256,0,stream>>>(ATT, HS, RS, CS, MEANH, XH, MEANP, XP);

  // 8. pairwise mp-match + combine
  k_pmm2<<<dim3(4,4,80),256,0,stream>>>(HS, w3, w4, WN1, WN2, PARTR, PARTC);
  k_pcomb<<<80,256,0,stream>>>(PARTR, PARTC, MMR, MMC);

  // 9. assemble mv
  k_mv<<<2048,256,0,stream>>>(HS, MEANH, MEANP, XH, XP, RS, RMAX, CS, CMAX,
                              MMR, MMC, w5, w6, w7, w8, MV);

  // 10. agg projections
  k_aggproj<<<dim3(16,32,2),256,0,stream>>>(MV, aWihF, aWihB, abF, abB, PREf, PREb);

  // 11. agg scan (no aux)
  hipMemsetAsync(FLG, 0, 2048*sizeof(int), stream);
  k_scanaux<<<128,256,0,stream>>>(PREf, PREb, WT+524288, WT+786432, HXB, FLG, nullptr, HT,
                                  0, fc1W, W1T, aWhhF, WT+524288, aWhhB, WT+786432,
                                  left, right, XM);

  // 12. fused head
  k_fc12<<<4,512,0,stream>>>(HT, XM, W1T, fc1b, fc2W, fc2b, out);
}

// Round 14
// 1356.512 us; speedup vs baseline: 2.8742x; 1.2022x over previous
//
#include <hip/hip_runtime.h>
#include <hip/hip_bf16.h>
#include <math.h>

#define EPSV 1e-8f

__device__ __forceinline__ float dsmall(float d){ return d > EPSV ? d : EPSV; }
__device__ __forceinline__ float sigf(float x){ return 1.f/(1.f+expf(-x)); }

// ---------------------------------------------------------------------------
// Transpose ctx Whh (z selects F/B): W (1024x256) -> WT (256x1024)
// ---------------------------------------------------------------------------
__global__ __launch_bounds__(1024) void k_transpose2(const float* __restrict__ WF,
                                                     const float* __restrict__ WB,
                                                     float* __restrict__ WT0,
                                                     float* __restrict__ WT1){
  const float* W = blockIdx.z ? WB : WF;
  float* WT = blockIdx.z ? WT1 : WT0;
  __shared__ float t[32][33];
  int rb = blockIdx.y*32, cb = blockIdx.x*32;
  int r = rb + threadIdx.y, c = cb + threadIdx.x;
  t[threadIdx.y][threadIdx.x] = W[(size_t)r*256 + c];
  __syncthreads();
  int rr = cb + threadIdx.y, cc = rb + threadIdx.x;
  WT[(size_t)rr*1024 + cc] = t[threadIdx.x][threadIdx.y];
}

// ---------------------------------------------------------------------------
// ctx projections: z in 0..3 (zo=z>>1: left/right; zi=z&1: F/B dir)
// ---------------------------------------------------------------------------
__global__ __launch_bounds__(256) void k_proj(
    const float* __restrict__ left, const float* __restrict__ right,
    const float* __restrict__ WihF, const float* __restrict__ WihB,
    const float* __restrict__ bF, const float* __restrict__ bB,
    float* __restrict__ PREf, float* __restrict__ PREb)
{
  const int z = blockIdx.z, zo = z >> 1, zi = z & 1;
  const float* A = zo ? right : left;
  const float* B = zi ? WihB : WihF;
  const float* bias = zi ? bB : bF;
  float* C = (zi ? PREb : PREf) + (size_t)zo*1048576;
  const int K = 300;

  __shared__ float As[16][68];
  __shared__ float Bs[16][68];
  const int mb = blockIdx.y*64, nb = blockIdx.x*64;
  const int tid = threadIdx.x;
  const int tx = tid & 15, ty = tid >> 4;

  float acc[4][4];
  #pragma unroll
  for (int i=0;i<4;i++)
    #pragma unroll
    for (int j=0;j<4;j++) acc[i][j] = 0.f;

  for (int kt = 0; kt < K; kt += 16) {
    int ka = tid & 15, ma = tid >> 4;
    #pragma unroll
    for (int q=0;q<4;q++){
      int m = ma + q*16;
      float v = 0.f, bvv = 0.f;
      if (kt+ka < K){
        v = A[(size_t)(mb+m)*300 + kt+ka];
        bvv = B[(size_t)(nb+m)*300 + kt+ka];
      }
      As[ka][m] = v; Bs[ka][m] = bvv;
    }
    __syncthreads();
    #pragma unroll
    for (int k=0;k<16;k++){
      float a[4], bv[4];
      #pragma unroll
      for (int i=0;i<4;i++) a[i] = As[k][ty*4+i];
      #pragma unroll
      for (int j=0;j<4;j++) bv[j] = Bs[k][tx*4+j];
      #pragma unroll
      for (int i=0;i<4;i++)
        #pragma unroll
        for (int j=0;j<4;j++) acc[i][j] += a[i]*bv[j];
    }
    __syncthreads();
  }
  #pragma unroll
  for (int i=0;i<4;i++){
    int m = mb + ty*4 + i;
    #pragma unroll
    for (int j=0;j<4;j++){
      int n = nb + tx*4 + j;
      C[(size_t)m*1024 + n] = acc[i][j] + bias[n];
    }
  }
}

// ---------------------------------------------------------------------------
// agg projections: z in 0..1 (F/B)
// ---------------------------------------------------------------------------
__global__ __launch_bounds__(256) void k_aggproj(
    const float* __restrict__ MV_,
    const float* __restrict__ WihF, const float* __restrict__ WihB,
    const float* __restrict__ bF, const float* __restrict__ bB,
    float* __restrict__ PREf, float* __restrict__ PREb)
{
  const int zi = blockIdx.z;
  const float* B = zi ? WihB : WihF;
  const float* bias = zi ? bB : bF;
  float* C = zi ? PREb : PREf;
  const int K = 62;

  __shared__ float As[16][68];
  __shared__ float Bs[16][68];
  const int mb = blockIdx.y*64, nb = blockIdx.x*64;
  const int tid = threadIdx.x;
  const int tx = tid & 15, ty = tid >> 4;

  float acc[4][4];
  #pragma unroll
  for (int i=0;i<4;i++)
    #pragma unroll
    for (int j=0;j<4;j++) acc[i][j] = 0.f;

  for (int kt = 0; kt < K; kt += 16) {
    int ka = tid & 15, ma = tid >> 4;
    #pragma unroll
    for (int q=0;q<4;q++){
      int m = ma + q*16;
      float v = 0.f, bvv = 0.f;
      if (kt+ka < K){
        v = MV_[(size_t)(mb+m)*62 + kt+ka];
        bvv = B[(size_t)(nb+m)*62 + kt+ka];
      }
      As[ka][m] = v; Bs[ka][m] = bvv;
    }
    __syncthreads();
    #pragma unroll
    for (int k=0;k<16;k++){
      float a[4], bv[4];
      #pragma unroll
      for (int i=0;i<4;i++) a[i] = As[k][ty*4+i];
      #pragma unroll
      for (int j=0;j<4;j++) bv[j] = Bs[k][tx*4+j];
      #pragma unroll
      for (int i=0;i<4;i++)
        #pragma unroll
        for (int j=0;j<4;j++) acc[i][j] += a[i]*bv[j];
    }
    __syncthreads();
  }
  #pragma unroll
  for (int i=0;i<4;i++){
    int m = mb + ty*4 + i;
    #pragma unroll
    for (int j=0;j<4;j++){
      int n = nb + tx*4 + j;
      C[(size_t)m*1024 + n] = acc[i][j] + bias[n];
    }
  }
}

// ---------------------------------------------------------------------------
// att cosine matrix: C=A@B^T / dsmall(U[m]*V[n]), z = d*4+b
// ---------------------------------------------------------------------------
__global__ __launch_bounds__(256) void k_att(
    const float* __restrict__ HS_, const float* __restrict__ NORM_,
    float* __restrict__ ATT_)
{
  const int z = blockIdx.z;
  const int d = z >> 2, b = z & 3;
  const float* A = HS_ + d*256 + (size_t)b*131072;
  const float* B = HS_ + 524288 + d*256 + (size_t)b*131072;
  const float* Uv = NORM_ + (size_t)b*512 + d*256;
  const float* Vv = NORM_ + (size_t)(4+b)*512 + d*256;
  float* C = ATT_ + (size_t)z*65536;

  __shared__ float As[16][68];
  __shared__ float Bs[16][68];
  const int mb = blockIdx.y*64, nb = blockIdx.x*64;
  const int tid = threadIdx.x;
  const int tx = tid & 15, ty = tid >> 4;

  float acc[4][4];
  #pragma unroll
  for (int i=0;i<4;i++)
    #pragma unroll
    for (int j=0;j<4;j++) acc[i][j] = 0.f;

  for (int kt = 0; kt < 256; kt += 16) {
    int ka = tid & 15, ma = tid >> 4;
    #pragma unroll
    for (int q=0;q<4;q++){
      int m = ma + q*16;
      As[ka][m] = A[(size_t)(mb+m)*512 + kt+ka];
      Bs[ka][m] = B[(size_t)(nb+m)*512 + kt+ka];
    }
    __syncthreads();
    #pragma unroll
    for (int k=0;k<16;k++){
      float a[4], bv[4];
      #pragma unroll
      for (int i=0;i<4;i++) a[i] = As[k][ty*4+i];
      #pragma unroll
      for (int j=0;j<4;j++) bv[j] = Bs[k][tx*4+j];
      #pragma unroll
      for (int i=0;i<4;i++)
        #pragma unroll
        for (int j=0;j<4;j++) acc[i][j] += a[i]*bv[j];
    }
    __syncthreads();
  }
  #pragma unroll
  for (int i=0;i<4;i++){
    int m = mb + ty*4 + i;
    float um = Uv[m];
    #pragma unroll
    for (int j=0;j<4;j++){
      int n = nb + tx*4 + j;
      C[(size_t)m*256 + n] = acc[i][j] / dsmall(um * Vv[n]);
    }
  }
}

// ---------------------------------------------------------------------------
// Fused attentive stats
// ---------------------------------------------------------------------------
__global__ __launch_bounds__(256) void k_attstat(
    const float* __restrict__ ATT_, const float* __restrict__ HS_,
    const float* __restrict__ RS_, const float* __restrict__ CS_,
    float* __restrict__ MEANH_, float* __restrict__ XH_,
    float* __restrict__ MEANP_, float* __restrict__ XP_)
{
  const int z16 = blockIdx.z;
  const int var = z16 >> 3;
  const int z = z16 & 7;
  const int d = z >> 2, b = z & 3;
  const float* A = ATT_ + (size_t)z*65536;
  const float* B = (var ? HS_ : HS_ + 524288) + d*256 + (size_t)b*131072;
  const float* U = (var ? CS_ : RS_) + z*256;
  float* C1 = (var ? MEANP_ : MEANH_) + (size_t)z*65536;
  float* C2 = (var ? XP_    : XH_   ) + (size_t)z*65536;

  __shared__ float As[16][68];
  __shared__ float Bs[16][68];
  const int mb = blockIdx.y*64, nb = blockIdx.x*64;
  const int tid = threadIdx.x;
  const int tx = tid & 15, ty = tid >> 4;

  float asum[4][4], amax[4][4];
  #pragma unroll
  for (int i=0;i<4;i++)
    #pragma unroll
    for (int j=0;j<4;j++){ asum[i][j]=0.f; amax[i][j]=-INFINITY; }

  for (int kt = 0; kt < 256; kt += 16) {
    if (var == 0) {
      int ka = tid & 15, ma = tid >> 4;
      #pragma unroll
      for (int q=0;q<4;q++)
        As[ka][ma+q*16] = A[(size_t)(mb+ma+q*16)*256 + kt+ka];
    } else {
      int ma = tid & 63, ka = tid >> 6;
      #pragma unroll
      for (int q=0;q<4;q++)
        As[ka+q*4][ma] = A[(size_t)(kt+ka+q*4)*256 + mb+ma];
    }
    {
      int nbi = tid & 63, kb = tid >> 6;
      #pragma unroll
      for (int q=0;q<4;q++)
        Bs[kb+q*4][nbi] = B[(size_t)(kt+kb+q*4)*512 + nb+nbi];
    }
    __syncthreads();
    #pragma unroll
    for (int k=0;k<16;k++){
      float a[4], bv[4];
      #pragma unroll
      for (int i=0;i<4;i++) a[i] = As[k][ty*4+i];
      #pragma unroll
      for (int j=0;j<4;j++) bv[j] = Bs[k][tx*4+j];
      #pragma unroll
      for (int i=0;i<4;i++)
        #pragma unroll
        for (int j=0;j<4;j++){
          float p = a[i]*bv[j];
          asum[i][j] += p;
          amax[i][j] = fmaxf(amax[i][j], p);
        }
    }
    __syncthreads();
  }
  #pragma unroll
  for (int i=0;i<4;i++){
    int m = mb + ty*4 + i;
    float ud = dsmall(U[m]);
    #pragma unroll
    for (int j=0;j<4;j++){
      int n = nb + tx*4 + j;
      C1[(size_t)m*256 + n] = asum[i][j] / ud;
      C2[(size_t)m*256 + n] = amax[i][j];
    }
  }
}

// ---------------------------------------------------------------------------
// Pairwise mp-match, fw+bw in one launch: z in 0..79 (dir = z>=40)
// ---------------------------------------------------------------------------
__global__ __launch_bounds__(256) void k_pmm2(
    const float* __restrict__ HS_,
    const float* __restrict__ w3, const float* __restrict__ w4,
    const float* __restrict__ WN1_, const float* __restrict__ WN2_,
    float* __restrict__ PARTR, float* __restrict__ PARTC)
{
  const int z = blockIdx.z;
  const int dir = z >= 40;
  const int zz = z - dir*40;
  const int bq = zz / 10, l = zz % 10;
  const float* A = HS_ + dir*256 + (size_t)bq*131072;
  const float* B = HS_ + 524288 + dir*256 + (size_t)bq*131072;
  const float* Wv = (dir ? w4 : w3) + l*256;
  const float* U = WN1_ + dir*10240 + bq*2560 + l*256;
  const float* V = WN2_ + dir*10240 + bq*2560 + l*256;

  __shared__ float As[16][68];
  __shared__ float Bs[16][68];
  const int mb = blockIdx.y*64, nb = blockIdx.x*64;
  const int tid = threadIdx.x;
  const int tx = tid & 15, ty = tid >> 4;

  float acc[4][4];
  #pragma unroll
  for (int i=0;i<4;i++)
    #pragma unroll
    for (int j=0;j<4;j++) acc[i][j] = 0.f;

  for (int kt = 0; kt < 256; kt += 16) {
    int ka = tid & 15, ma = tid >> 4;
    float w = Wv[kt+ka]; float w2 = w*w;
    #pragma unroll
    for (int q=0;q<4;q++){
      As[ka][ma+q*16] = A[(size_t)(mb+ma+q*16)*512 + kt+ka] * w2;
      Bs[ka][ma+q*16] = B[(size_t)(nb+ma+q*16)*512 + kt+ka];
    }
    __syncthreads();
    #pragma unroll
    for (int k=0;k<16;k++){
      float a[4], bv[4];
      #pragma unroll
      for (int i=0;i<4;i++) a[i] = As[k][ty*4+i];
      #pragma unroll
      for (int j=0;j<4;j++) bv[j] = Bs[k][tx*4+j];
      #pragma unroll
      for (int i=0;i<4;i++)
        #pragma unroll
        for (int j=0;j<4;j++) acc[i][j] += a[i]*bv[j];
    }
    __syncthreads();
  }
  float um[4], vn[4];
  #pragma unroll
  for (int i=0;i<4;i++) um[i] = U[mb + ty*4 + i];
  #pragma unroll
  for (int j=0;j<4;j++) vn[j] = V[nb + tx*4 + j];
  float c[4][4];
  #pragma unroll
  for (int i=0;i<4;i++)
    #pragma unroll
    for (int j=0;j<4;j++) c[i][j] = acc[i][j] / dsmall(um[i]*vn[j]);

  float rm[4];
  #pragma unroll
  for (int i=0;i<4;i++){
    rm[i] = fmaxf(fmaxf(c[i][0], c[i][1]), fmaxf(c[i][2], c[i][3]));
    rm[i] = fmaxf(rm[i], __shfl_xor(rm[i], 1, 64));
    rm[i] = fmaxf(rm[i], __shfl_xor(rm[i], 2, 64));
    rm[i] = fmaxf(rm[i], __shfl_xor(rm[i], 4, 64));
    rm[i] = fmaxf(rm[i], __shfl_xor(rm[i], 8, 64));
  }
  if ((tid & 15) == 0){
    #pragma unroll
    for (int i=0;i<4;i++)
      PARTR[((size_t)z*4 + blockIdx.x)*256 + mb + ty*4 + i] = rm[i];
  }
  __syncthreads();
  float* colp = &As[0][0];
  #pragma unroll
  for (int j=0;j<4;j++)
    colp[ty*64 + tx*4 + j] = fmaxf(fmaxf(c[0][j], c[1][j]), fmaxf(c[2][j], c[3][j]));
  __syncthreads();
  if (tid < 64){
    float m = colp[tid];
    #pragma unroll
    for (int r=1;r<16;r++) m = fmaxf(m, colp[r*64 + tid]);
    PARTC[((size_t)z*4 + blockIdx.y)*256 + nb + tid] = m;
  }
}

__global__ void k_pcomb(const float* __restrict__ PARTR, const float* __restrict__ PARTC,
                        float* __restrict__ MMRo, float* __restrict__ MMCo){
  int z = blockIdx.x, i = threadIdx.x;
  size_t b0 = (size_t)z*4*256 + i;
  float r = fmaxf(fmaxf(PARTR[b0], PARTR[b0+256]), fmaxf(PARTR[b0+512], PARTR[b0+768]));
  float c = fmaxf(fmaxf(PARTC[b0], PARTC[b0+256]), fmaxf(PARTC[b0+512], PARTC[b0+768]));
  MMRo[(size_t)z*256 + i] = r;
  MMCo[(size_t)z*256 + i] = c;
}

// ---------------------------------------------------------------------------
// LSTM scan v12: 16 teams (8/dir) x 8 WGs, 1 seq per team. bx<128: scan,
// team = bx&15 (teams t, t+8 share XCD t&7; a team's 8 WGs stay on one XCD),
// wg = bx>>4, d = team>>3, sq = team&7. bx>=128: aux work during ctx scan.
// Hbuf: [team][parity][256 h] = 512 floats/team. flg: [team*8+wg]*32 ints.
// ---------------------------------------------------------------------------
__global__ __launch_bounds__(256, 1) void k_scanaux(
    const float* __restrict__ PREf, const float* __restrict__ PREb,
    const float* __restrict__ WTf, const float* __restrict__ WTb,
    float* __restrict__ Hbuf, int* __restrict__ flg,
    float* __restrict__ HSo, float* __restrict__ HTo,
    int do_aux,
    const float* __restrict__ fc1W, float* __restrict__ W1T,
    const float* __restrict__ aWhhF, float* __restrict__ WTaggF,
    const float* __restrict__ aWhhB, float* __restrict__ WTaggB,
    const float* __restrict__ left, const float* __restrict__ right,
    float* __restrict__ XM)
{
  __shared__ float Wl[256][128];     // 128 KB (aux reuses as 32x33 tile)
  __shared__ float hl[256];          // 1 KB
  __shared__ float red[4][4][40];    // 2.5 KB red[kp][cc][gq]

  const int bx = blockIdx.x;
  const int tid = threadIdx.x;

  if (bx >= 128) {
    if (!do_aux) return;
    float (*tl)[33] = (float(*)[33])Wl;
    const int aux = bx - 128;         // 0..63
    for (int u = aux; u < 816 + 512 + 8; u += 64) {
      if (u < 816) {                // fc1W (512x1626) -> W1T (1626x512)
        int tI = u % 16, tJ = u / 16;
        int r0 = tI*32, c0 = tJ*32;
        for (int e = tid; e < 1024; e += 256) {
          int rr = e >> 5, cc = e & 31;
          int c = c0 + cc;
          tl[rr][cc] = (c < 1626) ? fc1W[(size_t)(r0+rr)*1626 + c] : 0.f;
        }
        __syncthreads();
        for (int e = tid; e < 1024; e += 256) {
          int cc = e >> 5, rr = e & 31;
          int c = c0 + cc;
          if (c < 1626) W1T[(size_t)c*512 + r0 + rr] = tl[rr][cc];
        }
        __syncthreads();
      } else if (u < 1328) {        // aWhh (1024x256) -> WTagg (256x1024)
        int u2 = u - 816;
        const float* S = (u2 >= 256) ? aWhhB : aWhhF;
        float* D = (u2 >= 256) ? WTaggB : WTaggF;
        int tile = u2 & 255;
        int r0 = (tile >> 3)*32, c0 = (tile & 7)*32;
        for (int e = tid; e < 1024; e += 256) {
          int rr = e >> 5, cc = e & 31;
          tl[rr][cc] = S[(size_t)(r0+rr)*256 + c0 + cc];
        }
        __syncthreads();
        for (int e = tid; e < 1024; e += 256) {
          int cc = e >> 5, rr = e & 31;
          D[(size_t)(c0+cc)*1024 + r0 + rr] = tl[rr][cc];
        }
        __syncthreads();
      } else {                      // means
        int m = u - 1328;
        int b = m & 3, sideR = m >> 2;
        const float* src = sideR ? right : left;
        for (int ch = tid; ch < 300; ch += 256) {
          float s = 0.f;
          for (int t = 0; t < 256; t++) s += src[((size_t)(b*256+t))*300 + ch];
          XM[b*600 + sideR*300 + ch] = s * (1.f/256.f);
        }
      }
    }
    return;
  }

  // ----------------- scan path -----------------
  const int team = bx & 15;
  const int d  = team >> 3;
  const int sq = team & 7;
  const int wg = bx >> 4;
  const float* PRE = d ? PREb : PREf;
  const float* WT  = d ? WTb  : WTf;
  float* Hb = Hbuf + (size_t)team*512;
  int* fl = flg + team*256;

  const int kc = tid >> 5;   // k-chunk 0..7
  const int gq = tid & 31;
  const int aj = tid & 31;   // activation col (tid<32)

  for (int e = tid; e < 256*128; e += 256) {
    int k = e >> 7, c = e & 127;
    Wl[k][c] = WT[(size_t)k*1024 + (c>>5)*256 + wg*32 + (c&31)];
  }
  if (tid < 256) hl[tid] = 0.f;
  float cst = 0.f;
  __syncthreads();

  for (int tt = 0; tt < 256; ++tt) {
    const int t = d ? 255 - tt : tt;
    const int wp = tt & 1;
    const int sp = (tt + 1) & 1;

    // prefetch PRE (tid<32)
    float pre0=0.f, pre1=0.f, pre2=0.f, pre3=0.f;
    if (tid < 32) {
      const size_t pbase = ((size_t)(sq*256 + t))*1024 + wg*32 + aj;
      pre0 = PRE[pbase];       pre1 = PRE[pbase + 256];
      pre2 = PRE[pbase + 512]; pre3 = PRE[pbase + 768];
    }

    // per-half-wave fetch of remote chunk kc (32 floats = 128B)
    if (tt > 0 && kc != wg) {
      const int* flp = &fl[kc*32];
      while (__hip_atomic_load(flp, __ATOMIC_RELAXED, __HIP_MEMORY_SCOPE_AGENT) < tt)
        __builtin_amdgcn_s_sleep(1);
      float v = __hip_atomic_load(&Hb[sp*256 + kc*32 + gq],
                                  __ATOMIC_RELAXED, __HIP_MEMORY_SCOPE_AGENT);
      hl[kc*32 + gq] = v;
    }

    // gate matmul: acc[cc] over 32 k of chunk kc
    float acc[4] = {0.f, 0.f, 0.f, 0.f};
    #pragma unroll 8
    for (int kk = 0; kk < 32; ++kk) {
      const int k = kc*32 + kk;
      float4 w = *(const float4*)&Wl[k][gq*4];
      float h = hl[k];
      acc[0] += h*w.x; acc[1] += h*w.y; acc[2] += h*w.z; acc[3] += h*w.w;
    }
    #pragma unroll
    for (int c2=0;c2<4;c2++)
      acc[c2] += __shfl_xor(acc[c2], 32, 64);
    if ((tid & 32) == 0) {
      const int kp = kc >> 1;
      #pragma unroll
      for (int c2=0;c2<4;c2++)
        red[kp][c2][gq] = acc[c2];
    }
    __syncthreads();   // B1

    float hreg = 0.f;
    if (tid < 32) {
      float g[4];
      #pragma unroll
      for (int gt=0; gt<4; ++gt) {
        const int c = gt*32 + aj;
        const int gqq = c >> 2, cc = c & 3;
        g[gt] = red[0][cc][gqq] + red[1][cc][gqq] + red[2][cc][gqq] + red[3][cc][gqq];
      }
      g[0] += pre0; g[1] += pre1; g[2] += pre2; g[3] += pre3;
      const float ig = sigf(g[0]), fg = sigf(g[1]), gg = tanhf(g[2]), og = sigf(g[3]);
      cst = fg*cst + ig*gg;
      hreg = og*tanhf(cst);
      hl[wg*32 + aj] = hreg;
      __hip_atomic_store(&Hb[wp*256 + wg*32 + aj], hreg,
                         __ATOMIC_RELAXED, __HIP_MEMORY_SCOPE_AGENT);
    }
    __syncthreads();   // B2: drains Hb stores + hl ds_writes

    if (tid == 0)
      __hip_atomic_store(&fl[wg*32], tt+1, __ATOMIC_RELAXED, __HIP_MEMORY_SCOPE_AGENT);

    if (tid < 32) {
      if (HSo) HSo[((size_t)(sq*256 + t))*512 + d*256 + wg*32 + aj] = hreg;
      if (HTo && tt == 255) HTo[((size_t)(sq*2 + d))*256 + wg*32 + aj] = hreg;
    }
  }
}

// ---------------------------------------------------------------------------
// Norms: bx<1024 -> row L2 norms of HS; else weighted norms
// ---------------------------------------------------------------------------
__global__ __launch_bounds__(256) void k_norms(const float* __restrict__ HS_,
                                               const float* __restrict__ w3, const float* __restrict__ w4,
                                               float* __restrict__ NORM_,
                                               float* __restrict__ WN1_, float* __restrict__ WN2_){
  const int bx = blockIdx.x;
  int lane = threadIdx.x & 63;
  if (bx < 1024) {
    int r = bx*4 + (threadIdx.x >> 6);
    int seq = r >> 9, d = (r >> 8) & 1, i = r & 255;
    const float* row = HS_ + ((size_t)(seq*256 + i))*512 + d*256;
    float s = 0.f;
    #pragma unroll
    for (int q=0;q<4;q++){ float v = row[lane + 64*q]; s += v*v; }
    for (int off=32; off; off>>=1) s += __shfl_xor(s, off, 64);
    if (lane == 0) NORM_[r] = sqrtf(s);
  } else {
    int rid = (bx-1024)*4 + (threadIdx.x >> 6);
    int side = rid / 20480; int rem = rid % 20480;
    int d = rem / 10240; int rem2 = rem % 10240;
    int b = rem2 / 2560; int l = (rem2 / 256) % 10; int i = rem2 & 255;
    int seq = side ? 4+b : b;
    const float* row = HS_ + ((size_t)(seq*256 + i))*512 + d*256;
    const float* w = (d ? w4 : w3) + l*256;
    float s = 0.f;
    #pragma unroll
    for (int q=0;q<4;q++){ float wv = w[lane+64*q]; float v = row[lane+64*q]; s += wv*wv*v*v; }
    for (int off=32; off; off>>=1) s += __shfl_xor(s, off, 64);
    if (lane == 0) (side ? WN2_ : WN1_)[rem] = sqrtf(s);
  }
}

// ---------------------------------------------------------------------------
// Combined att reductions
// ---------------------------------------------------------------------------
__global__ __launch_bounds__(256) void k_redcomb(const float* __restrict__ ATT_,
                                                 float* __restrict__ RS_, float* __restrict__ RMAX_,
                                                 float* __restrict__ CS_, float* __restrict__ CMAX_){
  const int bx = blockIdx.x;
  if (bx < 512) {
    int r = bx*4 + (threadIdx.x >> 6);
    int lane = threadIdx.x & 63;
    const float* row = ATT_ + (size_t)r*256;
    float s = 0.f, m = -INFINITY;
    #pragma unroll
    for (int q=0;q<4;q++){ float v = row[lane + 64*q]; s += v; m = fmaxf(m,v); }
    for (int off=32; off; off>>=1){ s += __shfl_xor(s,off,64); m = fmaxf(m, __shfl_xor(m,off,64)); }
    if (lane == 0){ RS_[r] = s; RMAX_[r] = m; }
  } else {
    int z = bx - 512;
    const float* in = ATT_ + (size_t)z*65536;
    int j = threadIdx.x;
    float s = 0.f, m = -INFINITY;
    for (int r=0;r<256;r++){ float v = in[(size_t)r*256 + j]; s += v; m = fmaxf(m,v); }
    CS_[z*256 + j] = s;
    CMAX_[z*256 + j] = m;
  }
}

// ---------------------------------------------------------------------------
// Assemble mv rows (62 channels)
// ---------------------------------------------------------------------------
__global__ __launch_bounds__(256) void k_mv(
    const float* __restrict__ HS_, const float* __restrict__ MEANH_, const float* __restrict__ MEANP_,
    const float* __restrict__ XH_, const float* __restrict__ XP_,
    const float* __restrict__ RS_, const float* __restrict__ RMAX_,
    const float* __restrict__ CS_, const float* __restrict__ CMAX_,
    const float* __restrict__ MMR_, const float* __restrict__ MMC_,
    const float* __restrict__ w5, const float* __restrict__ w6,
    const float* __restrict__ w7, const float* __restrict__ w8,
    float* __restrict__ MV_)
{
  const int blk = blockIdx.x;
  const int side = blk >> 10, b = (blk >> 8) & 3, i = blk & 255;
  const int wv = threadIdx.x >> 6, lane = threadIdx.x & 63;
  float* mvrow = MV_ + (size_t)blk*62;

  if (threadIdx.x == 0){
    const float* rmax = side ? CMAX_ : RMAX_;
    const float* rsum = side ? CS_   : RS_;
    mvrow[0] = rmax[b*256 + i];
    mvrow[1] = rsum[b*256 + i] * (1.f/256.f);
  }
  if (threadIdx.x < 20){
    int dd = threadIdx.x / 10, l = threadIdx.x % 10;
    const float* mm = side ? MMC_ : MMR_;
    mvrow[2 + dd*10 + l] = mm[dd*10240 + (b*10 + l)*256 + i];
  }
  const int d = wv & 1;
  const int seq = side ? 4+b : b;
  const float* arow = HS_ + ((size_t)(seq*256 + i))*512 + d*256;
  const float* Mside = side ? MEANP_ : MEANH_;
  const float* Xside = side ? XP_ : XH_;
  const float* brow = (wv < 2 ? Mside : Xside) + (size_t)d*262144 + (size_t)b*65536 + (size_t)i*256;
  const float* wp = (wv==0) ? w5 : (wv==1) ? w6 : (wv==2) ? w7 : w8;

  float av[4], bv[4];
  #pragma unroll
  for (int q=0;q<4;q++){ av[q] = arow[lane+64*q]; bv[q] = brow[lane+64*q]; }
  for (int l=0;l<10;l++){
    const float* wrow = wp + l*256;
    float s1=0.f, s2=0.f, s3=0.f;
    #pragma unroll
    for (int q=0;q<4;q++){
      float w = wrow[lane+64*q]; float w2v = w*w;
      s1 += w2v*av[q]*bv[q]; s2 += w2v*av[q]*av[q]; s3 += w2v*bv[q]*bv[q];
    }
    for (int off=32; off; off>>=1){
      s1 += __shfl_xor(s1,off,64); s2 += __shfl_xor(s2,off,64); s3 += __shfl_xor(s3,off,64);
    }
    if (lane == 0) mvrow[22 + wv*10 + l] = s1 / fmaxf(sqrtf(s2)*sqrtf(s3), EPSV);
  }
}

// ---------------------------------------------------------------------------
// Fused head: fc1 (tanh) + fc2
// ---------------------------------------------------------------------------
__global__ __launch_bounds__(512) void k_fc12(const float* __restrict__ HT_,
                                              const float* __restrict__ XM,
                                              const float* __restrict__ W1T,
                                              const float* __restrict__ b1,
                                              const float* __restrict__ W2,
                                              const float* __restrict__ b2,
                                              float* __restrict__ out){
  __shared__ float x[1626];
  __shared__ float xs2[512];
  int b = blockIdx.x, t = threadIdx.x;
  if (t < 256){
    x[t]       = HT_[(b*2+0)*256 + t];
    x[256+t]   = HT_[(b*2+1)*256 + t];
    x[512+t]   = HT_[((4+b)*2+0)*256 + t];
    x[768+t]   = HT_[((4+b)*2+1)*256 + t];
  }
  if (t == 0){ x[1024] = 0.5f; x[1025] = 0.5f; }
  if (t < 300){ x[1026+t] = XM[b*600 + t]; x[1326+t] = XM[b*600 + 300 + t]; }
  __syncthreads();
  float acc = b1[t];
  for (int k=0;k<1626;k++) acc += x[k]*W1T[(size_t)k*512 + t];
  xs2[t] = tanhf(acc);
  __syncthreads();
  if (t < 22){
    float o = b2[t];
    const float* wr = W2 + (size_t)t*512;
    for (int k=0;k<512;k++) o += xs2[k]*wr[k];
    out[b*22 + t] = o;
  }
}

// ---------------------------------------------------------------------------
extern "C" void kernel_launch(void* const* d_in, const int* in_sizes, int n_in,
                              void* d_out, int out_size, void* d_ws, size_t ws_size,
                              hipStream_t stream) {
  const float* left  = (const float*)d_in[0];
  const float* right = (const float*)d_in[1];
  const float* cWihF = (const float*)d_in[2];
  const float* cWhhF = (const float*)d_in[3];
  const float* cbF   = (const float*)d_in[4];
  const float* cWihB = (const float*)d_in[5];
  const float* cWhhB = (const float*)d_in[6];
  const float* cbB   = (const float*)d_in[7];
  const float* aWihF = (const float*)d_in[8];
  const float* aWhhF = (const float*)d_in[9];
  const float* abF   = (const float*)d_in[10];
  const float* aWihB = (const float*)d_in[11];
  const float* aWhhB = (const float*)d_in[12];
  const float* abB   = (const float*)d_in[13];
  const float* w3 = (const float*)d_in[14];
  const float* w4 = (const float*)d_in[15];
  const float* w5 = (const float*)d_in[16];
  const float* w6 = (const float*)d_in[17];
  const float* w7 = (const float*)d_in[18];
  const float* w8 = (const float*)d_in[19];
  const float* fc1W = (const float*)d_in[20];
  const float* fc1b = (const float*)d_in[21];
  const float* fc2W = (const float*)d_in[22];
  const float* fc2b = (const float*)d_in[23];
  float* out = (float*)d_out;
  float* ws = (float*)d_ws;

  // workspace layout (floats)
  float* WT    = ws;                 // 4 * 262144
  float* PREf  = ws + 1048576;       // 2097152
  float* PREb  = ws + 3145728;       // 2097152
  float* HS    = ws + 5242880;       // 1048576
  float* NORM  = ws + 6291456;       // 4096
  float* ATT   = ws + 6295552;       // 524288
  float* RS    = ws + 6819840;       // 2048
  float* RMAX  = ws + 6821888;       // 2048
  float* CS    = ws + 6823936;       // 2048
  float* CMAX  = ws + 6825984;       // 2048
  float* MEANH = ws + 6828032;       // 524288
  float* MEANP = ws + 7352320;       // 524288
  float* XH    = ws + 7876608;       // 524288
  float* XP    = ws + 8400896;       // 524288
  float* WN1   = ws + 8925184;       // 20480
  float* WN2   = ws + 8945664;       // 20480
  float* MM    = ws + 8966144;       // 2621440 scratch
  float* MMR   = ws + 11587584;      // 20480
  float* MMC   = ws + 11608064;      // 20480
  float* MV    = ws + 11628544;      // 126976
  float* HT    = ws + 11755520;      // 4096
  float* XM    = ws + 11759616;      // 2400
  float* W1T   = ws + 11764064;      // 832512

  // MM overlays
  float* HXB  = MM;                   // scans: 8192 floats (16 teams x 512)
  int*   FLG  = (int*)(MM + 8192);    // scans: 4096 ints
  float* PARTR= MM;                   // pairwise: 81920
  float* PARTC= MM + 81920;           // 81920

  // 1. ctx Whh transposes
  k_transpose2<<<dim3(8,32,2), dim3(32,32), 0, stream>>>(cWhhF, cWhhB, WT, WT + 262144);

  // 2. ctx projections
  k_proj<<<dim3(16,16,4),256,0,stream>>>(left, right, cWihF, cWihB, cbF, cbB, PREf, PREb);

  // 3. ctx scan (8 teams/dir, 1 seq/team) + hidden aux work
  hipMemsetAsync(FLG, 0, 4096*sizeof(int), stream);
  k_scanaux<<<192,256,0,stream>>>(PREf, PREb, WT, WT+262144, HXB, FLG, HS, nullptr,
                                  1, fc1W, W1T, aWhhF, WT+524288, aWhhB, WT+786432,
                                  left, right, XM);

  // 4. norms
  k_norms<<<11264,256,0,stream>>>(HS, w3, w4, NORM, WN1, WN2);

  // 5. att cosine matrix
  k_att<<<dim3(4,4,8),256,0,stream>>>(HS, NORM, ATT);

  // 6. att reductions
  k_redcomb<<<520,256,0,stream>>>(ATT, RS, RMAX, CS, CMAX);

  // 7. attentive means and maxes
  k_attstat<<<dim3(4,4,16),256,0,stream>>>(ATT, HS, RS, CS, MEANH, XH, MEANP, XP);

  // 8. pairwise mp-match + combine
  k_pmm2<<<dim3(4,4,80),256,0,stream>>>(HS, w3, w4, WN1, WN2, PARTR, PARTC);
  k_pcomb<<<80,256,0,stream>>>(PARTR, PARTC, MMR, MMC);

  // 9. assemble mv
  k_mv<<<2048,256,0,stream>>>(HS, MEANH, MEANP, XH, XP, RS, RMAX, CS, CMAX,
                              MMR, MMC, w5, w6, w7, w8, MV);

  // 10. agg projections
  k_aggproj<<<dim3(16,32,2),256,0,stream>>>(MV, aWihF, aWihB, abF, abB, PREf, PREb);

  // 11. agg scan (no aux)
  hipMemsetAsync(FLG, 0, 4096*sizeof(int), stream);
  k_scanaux<<<192,256,0,stream>>>(PREf, PREb, WT+524288, WT+786432, HXB, FLG, nullptr, HT,
                                  0, fc1W, W1T, aWhhF, WT+524288, aWhhB, WT+786432,
                                  left, right, XM);

  // 12. fused head
  k_fc12<<<4,512,0,stream>>>(HT, XM, W1T, fc1b, fc2W, fc2b, out);
}